// Round 12
// baseline (1482.684 us; speedup 1.0000x reference)
//
#include <hip/hip_runtime.h>

#define D 300

namespace {

constexpr int kN   = 20000;
constexpr int kNLG = 40000;
constexpr int kE   = 80000;
constexpr int kELG = 200000;
constexpr int kL   = 5;

constexpr int K1P = 320;        // padded feature dim (fp16) = A-row width
constexpr int N1P = 640;
constexpr int K2P = 640;
constexpr int N2P = 384;        // GEMM2 col tiles (3x128)
constexpr int PQH = 320;        // preact row stride (halves)
constexpr int MP_N   = 20096;   // main rows padded (157 tiles)
constexpr int MP_ALL = 60160;   // + 40064 lg rows = 470 tiles
constexpr int MAIN_TILES = 157;
constexpr int RH = 320;         // halves per padded row
constexpr int RQ = 40;          // uint4 per padded row
constexpr int NALL = kN + kNLG; // 60000

typedef __attribute__((ext_vector_type(8))) _Float16 half8;
typedef __attribute__((ext_vector_type(2))) _Float16 half2v;
typedef __attribute__((ext_vector_type(4))) float f32x4;

__device__ inline short f2h(float f) {
  _Float16 h = (_Float16)f;
  return __builtin_bit_cast(short, h);
}

__device__ inline float2 upk(unsigned u) {
  half2v h = __builtin_bit_cast(half2v, u);
  return make_float2((float)h.x, (float)h.y);
}

__device__ inline unsigned pk(float a, float b) {
  half2v h;
  h.x = (_Float16)a;
  h.y = (_Float16)b;
  return __builtin_bit_cast(unsigned, h);
}

__device__ inline void addrow(float* acc, uint4 r) {
  float2 t0 = upk(r.x), t1 = upk(r.y), t2 = upk(r.z), t3 = upk(r.w);
  acc[0] += t0.x; acc[1] += t0.y; acc[2] += t1.x; acc[3] += t1.y;
  acc[4] += t2.x; acc[5] += t2.y; acc[6] += t3.x; acc[7] += t3.y;
}

__device__ inline void unpk8(uint4 r, float* v) {
  float2 t0 = upk(r.x), t1 = upk(r.y), t2 = upk(r.z), t3 = upk(r.w);
  v[0] = t0.x; v[1] = t0.y; v[2] = t1.x; v[3] = t1.y;
  v[4] = t2.x; v[5] = t2.y; v[6] = t3.x; v[7] = t3.y;
}

__device__ inline uint4 pk4(const float* a) {
  uint4 r;
  r.x = pk(a[0], a[1]); r.y = pk(a[2], a[3]);
  r.z = pk(a[4], a[5]); r.w = pk(a[6], a[7]);
  return r;
}

__device__ inline void gload_lds16(const void* g, void* l) {
  __builtin_amdgcn_global_load_lds(
      (const __attribute__((address_space(1))) void*)g,
      (__attribute__((address_space(3))) void*)l, 16, 0, 0);
}

// ---------------- init: stats, ab pad rows, CSR cursors ----------------

__global__ void k_init(float* __restrict__ stats, short* __restrict__ ab,
                       int* __restrict__ m0_cur, int* __restrict__ mL_cur,
                       int* __restrict__ lg_cur) {
  int g = blockIdx.x * blockDim.x + threadIdx.x;
  if (g < kL * 1200) stats[g] = 0.f;
  int np1 = (MP_N - kN) * K1P;
  int np2 = (MP_ALL - MP_N - kNLG) * K1P;
  if (g < np1) ab[(size_t)kN * K1P + g] = 0;
  if (g < np2) ab[(size_t)(MP_N + kNLG) * K1P + g] = 0;
  if (g < kN) { m0_cur[g] = 0; mL_cur[g] = 0; }
  if (g < kNLG) lg_cur[g] = 0;
}

// ---------------- CSR build (merged; also builds combined attr indices) ---------

__global__ void k_hist_all(const int* __restrict__ edge_index,
                           const int* __restrict__ lg_map,
                           const int* __restrict__ lg_ei,
                           const int* __restrict__ eattr,
                           const int* __restrict__ map2,
                           const int* __restrict__ x,
                           int* __restrict__ m0_cur, int* __restrict__ mL_cur,
                           int* __restrict__ lg_cur,
                           int* __restrict__ cam, int* __restrict__ cal) {
  int g = blockIdx.x * blockDim.x + threadIdx.x;
  if (g < kE) {
    atomicAdd(&m0_cur[edge_index[kE + g]], 1);
    cam[g] = eattr[2 * g] * 3 + eattr[2 * g + 1];
    return;
  }
  g -= kE;
  if (g < kNLG) { atomicAdd(&mL_cur[lg_map[kNLG + g]], 1); return; }
  g -= kNLG;
  if (g < kNLG) { atomicAdd(&mL_cur[lg_map[g]], 1); return; }
  g -= kNLG;
  if (g < kELG) {
    atomicAdd(&lg_cur[lg_ei[kELG + g]], 1);
    int a = map2[g];
    cal[g] = x[2 * a] * 3 + x[2 * a + 1];
  }
}

__device__ void scan_one(int* cursor, int* offs, int n) {
  __shared__ int part[256];
  int tid = threadIdx.x;
  int chunk = (n + 255) / 256;
  int s0 = tid * chunk;
  int s1 = min(n, s0 + chunk);
  int sum = 0;
  for (int i = s0; i < s1; ++i) sum += cursor[i];
  part[tid] = sum;
  __syncthreads();
  for (int off = 1; off < 256; off <<= 1) {
    int v = (tid >= off) ? part[tid - off] : 0;
    __syncthreads();
    part[tid] += v;
    __syncthreads();
  }
  int run = (tid == 0) ? 0 : part[tid - 1];
  for (int i = s0; i < s1; ++i) {
    int dv = cursor[i];
    offs[i] = run;
    cursor[i] = run;
    run += dv;
  }
  if (tid == 255) offs[n] = run;
}

__global__ __launch_bounds__(256) void k_scan3(
    int* __restrict__ m0_cur, int* __restrict__ m0_offs,
    int* __restrict__ mL_cur, int* __restrict__ mL_offs,
    int* __restrict__ lg_cur, int* __restrict__ lg_offs) {
  if (blockIdx.x == 0) scan_one(m0_cur, m0_offs, kN);
  else if (blockIdx.x == 1) scan_one(mL_cur, mL_offs, kN);
  else scan_one(lg_cur, lg_offs, kNLG);
}

__global__ void k_fill_all(const int* __restrict__ edge_index,
                           const int* __restrict__ lg_map,
                           const int* __restrict__ lg_ei,
                           int* __restrict__ m0_cur, int* __restrict__ m0_perm,
                           int* __restrict__ mL_cur, int* __restrict__ mL_perm,
                           int* __restrict__ lg_cur, int* __restrict__ lg_perm) {
  int g = blockIdx.x * blockDim.x + threadIdx.x;
  if (g < kE) {
    int pos = atomicAdd(&m0_cur[edge_index[kE + g]], 1);
    m0_perm[pos] = g;
    return;
  }
  g -= kE;
  if (g < kNLG) {
    int pos = atomicAdd(&mL_cur[lg_map[kNLG + g]], 1);
    mL_perm[pos] = g;
    return;
  }
  g -= kNLG;
  if (g < kNLG) {
    int pos = atomicAdd(&mL_cur[lg_map[g]], 1);
    mL_perm[pos] = kNLG + g;
    return;
  }
  g -= kNLG;
  if (g < kELG) {
    int pos = atomicAdd(&lg_cur[lg_ei[kELG + g]], 1);
    lg_perm[pos] = g;
  }
}

// ---------------- precompute: self vectors, combined tables, weights -----------

__global__ void k_selfvec(const float* __restrict__ g1, const float* __restrict__ g2,
                          const float* __restrict__ l1, const float* __restrict__ l2,
                          float* __restrict__ slv) {
  int g = blockIdx.x * blockDim.x + threadIdx.x;
  if (g >= kL * 640) return;
  int l = g / 640, rem = g - l * 640;
  int gr = rem / 320, c = rem - gr * 320;
  float v = 0.f;
  if (c < D) {
    if (gr == 0) v = g1[(size_t)l * 6 * D + 4 * D + c] + g2[(size_t)l * 3 * D + c];
    else         v = l1[(size_t)l * 120 * D + 119 * D + c] + l2[(size_t)l * 3 * D + c];
  }
  slv[g] = v;
}

// combined layer-0 attr tables: tcm[a1*3+a2] = g_emb1[0][a1]+g_emb2[0][a2]  (18 rows)
//                               tcl[a1*3+a2] = lg_emb1[0][a1]+lg_emb2[0][a2] (360 rows)
__global__ void k_comb_tab(const float* __restrict__ g1, const float* __restrict__ g2,
                           const float* __restrict__ l1, const float* __restrict__ l2,
                           short* __restrict__ tcm, short* __restrict__ tcl) {
  int g = blockIdx.x * blockDim.x + threadIdx.x;
  if (g < 18 * RH) {
    int p = g / RH, c = g - p * RH;
    float v = (c < D) ? g1[(size_t)(p / 3) * D + c] + g2[(size_t)(p % 3) * D + c] : 0.f;
    tcm[g] = f2h(v);
    return;
  }
  g -= 18 * RH;
  if (g < 360 * RH) {
    int p = g / RH, c = g - p * RH;
    float v = (c < D) ? l1[(size_t)(p / 3) * D + c] + l2[(size_t)(p % 3) * D + c] : 0.f;
    tcl[g] = f2h(v);
  }
}

__device__ void cvt_w1(const float* W, short* Wt, int g) {
  int per = N1P * K1P;
  int l = g / per, rem = g - l * per;
  int n = rem / K1P, k = rem - n * K1P;
  float v = (n < 2 * D && k < D) ? W[(size_t)l * D * 2 * D + (size_t)k * 2 * D + n] : 0.f;
  Wt[g] = f2h(v);
}

__device__ void cvt_w2(const float* W, short* Wt, int g) {
  int per = N2P * K2P;
  int l = g / per, rem = g - l * per;
  int n = rem / K2P, k = rem - n * K2P;
  float v = (n < D && k < 2 * D) ? W[(size_t)l * 2 * D * D + (size_t)k * D + n] : 0.f;
  Wt[g] = f2h(v);
}

__global__ void k_convert_wt_all(const float* __restrict__ g_w1, const float* __restrict__ g_w2,
                                 const float* __restrict__ lg_w1, const float* __restrict__ lg_w2,
                                 short* __restrict__ g_w1t, short* __restrict__ g_w2t,
                                 short* __restrict__ lg_w1t, short* __restrict__ lg_w2t) {
  int g = blockIdx.x * blockDim.x + threadIdx.x;
  const int s1 = kL * N1P * K1P, s2 = kL * N2P * K2P;
  if (g < s1) { cvt_w1(g_w1, g_w1t, g); return; }
  g -= s1;
  if (g < s2) { cvt_w2(g_w2, g_w2t, g); return; }
  g -= s2;
  if (g < s1) { cvt_w1(lg_w1, lg_w1t, g); return; }
  g -= s1;
  if (g < s2) cvt_w2(lg_w2, lg_w2t, g);
}

// ---------------- embed (merged main+lg, x8 vectorized) ----------------

__global__ void k_embed_all(const int* __restrict__ x, const int* __restrict__ lg_x,
                            const float* __restrict__ t1m, const float* __restrict__ t2m,
                            const float* __restrict__ t1l, const float* __restrict__ t2l,
                            float* __restrict__ outF, uint4* __restrict__ hist) {
  int g = blockIdx.x * blockDim.x + threadIdx.x;
  if (g >= NALL * RQ) return;
  int r = g / RQ, q = g - r * RQ;
  bool m = r < kN;
  int i = m ? r : r - kN;
  const int* ix = (m ? x : lg_x) + 2 * i;
  const float* t1 = (m ? t1m : t1l) + (size_t)ix[0] * D;
  const float* t2 = (m ? t2m : t2l) + (size_t)ix[1] * D;
  int c0 = q * 8;
  float y[8] = {0.f, 0.f, 0.f, 0.f, 0.f, 0.f, 0.f, 0.f};
  if (c0 < D) {
    float4 p0 = *(const float4*)(t1 + c0);
    float4 q0 = *(const float4*)(t2 + c0);
    y[0] = p0.x + q0.x; y[1] = p0.y + q0.y; y[2] = p0.z + q0.z; y[3] = p0.w + q0.w;
    *(float4*)(outF + (size_t)r * D + c0) = make_float4(y[0], y[1], y[2], y[3]);
    if (c0 + 8 <= D) {
      float4 p1 = *(const float4*)(t1 + c0 + 4);
      float4 q1 = *(const float4*)(t2 + c0 + 4);
      y[4] = p1.x + q1.x; y[5] = p1.y + q1.y; y[6] = p1.z + q1.z; y[7] = p1.w + q1.w;
      *(float4*)(outF + (size_t)r * D + c0 + 4) = make_float4(y[4], y[5], y[6], y[7]);
    }
  }
  hist[(size_t)r * RQ + q] = pk4(y);
}

// ---------------- gathers: predicated 8-slot MLP loop ----------------
// Per edge: TWO row loads (bA[ra] + bB[rb]). cnt is wave-uniform -> uniform guards.

#define GATHER_BODY                                                     \
  int p0 = offs[j], p1 = offs[j + 1];                                   \
  for (int pb = p0; pb < p1; pb += 64) {                                \
    int cnt = min(64, p1 - pb);                                         \
    int e_ = permp[pb + ((lane < cnt) ? lane : 0)];                     \
    int ra, rb;                                                         \
    GATHER_IDX                                                          \
    for (int t = 0; t < cnt; t += 8) {                                  \
      uint4 xa[8], xb[8];                                               \
      _Pragma("unroll")                                                 \
      for (int u = 0; u < 8; ++u) {                                     \
        int tt = min(t + u, cnt - 1);                                   \
        int a0 = __shfl(ra, tt), b0 = __shfl(rb, tt);                   \
        xa[u] = bA[(size_t)a0 * RQ + ll];                               \
        xb[u] = bB[(size_t)b0 * RQ + ll];                               \
      }                                                                 \
      int lim = min(8, cnt - t);                                        \
      _Pragma("unroll")                                                 \
      for (int u = 0; u < 8; ++u)                                       \
        if (u < lim) { addrow(acc, xa[u]); addrow(acc, xb[u]); }        \
    }                                                                   \
  }

__global__ void k_gather_all0(
    const uint4* __restrict__ h16, const uint4* __restrict__ e16,
    const int* __restrict__ m_src, const int* __restrict__ lg_src,
    const int* __restrict__ cam, const int* __restrict__ cal,
    const uint4* __restrict__ tcm, const uint4* __restrict__ tcl,
    const float* __restrict__ slvM, const float* __restrict__ slvL,
    const int* __restrict__ m_offs, const int* __restrict__ m_perm,
    const int* __restrict__ l_offs, const int* __restrict__ l_perm,
    uint4* __restrict__ ab) {
  int node = blockIdx.x * 4 + (threadIdx.x >> 6);
  int lane = threadIdx.x & 63;
  if (node >= NALL) return;
  bool act = lane < RQ;
  int ll = act ? lane : 0;
  bool isM = node < kN;
  int j = isM ? node : node - kN;
  const uint4* selfrow = isM ? (h16 + (size_t)node * RQ) : (e16 + (size_t)j * RQ);
  const float* sv = (isM ? slvM : slvL) + ll * 8;
  const int* offs = isM ? m_offs : l_offs;
  const int* permp = isM ? m_perm : l_perm;
  const uint4* bA = isM ? h16 : e16;
  const uint4* bB = isM ? tcm : tcl;
  const int* srcp = isM ? m_src : lg_src;
  const int* catp = isM ? cam : cal;

  float acc[8];
  {
    float vv[8];
    unpk8(selfrow[ll], vv);
#pragma unroll
    for (int i = 0; i < 8; ++i) acc[i] = vv[i] + sv[i];
  }

#define GATHER_IDX ra = srcp[e_]; rb = catp[e_];
  GATHER_BODY
#undef GATHER_IDX

  if (act) ab[(size_t)(isM ? node : MP_N + j) * RQ + ll] = pk4(acc);
}

__global__ void k_gather_allL(
    const uint4* __restrict__ h16, const uint4* __restrict__ e16,
    const int* __restrict__ lg_map, const int* __restrict__ lg_src,
    const int* __restrict__ map2,
    const float* __restrict__ slvM, const float* __restrict__ slvL,
    const int* __restrict__ m_offs, const int* __restrict__ m_perm,
    const int* __restrict__ l_offs, const int* __restrict__ l_perm,
    uint4* __restrict__ ab) {
  int node = blockIdx.x * 4 + (threadIdx.x >> 6);
  int lane = threadIdx.x & 63;
  if (node >= NALL) return;
  bool act = lane < RQ;
  int ll = act ? lane : 0;
  bool isM = node < kN;
  int j = isM ? node : node - kN;
  const uint4* selfrow = isM ? (h16 + (size_t)node * RQ) : (e16 + (size_t)j * RQ);
  const float* sv = (isM ? slvM : slvL) + ll * 8;
  const int* offs = isM ? m_offs : l_offs;
  const int* permp = isM ? m_perm : l_perm;
  const uint4* bA = isM ? h16 : e16;
  const uint4* bB = isM ? e16 : h16;

  float acc[8];
  {
    float vv[8];
    unpk8(selfrow[ll], vv);
#pragma unroll
    for (int i = 0; i < 8; ++i) acc[i] = vv[i] + sv[i];
  }

#define GATHER_IDX                                     \
  if (isM) {                                           \
    ra = lg_map[e_];                                   \
    rb = (e_ < kNLG) ? e_ : e_ - kNLG;                 \
  } else {                                             \
    ra = lg_src[e_];                                   \
    rb = map2[e_];                                     \
  }
  GATHER_BODY
#undef GATHER_IDX

  if (act) ab[(size_t)(isM ? node : MP_N + j) * RQ + ll] = pk4(acc);
}

// ---------------- dual MFMA GEMM (fp16 out; optional fused BN stats) ----------------

template<bool RELU, bool STATS>
__global__ __launch_bounds__(256) void k_mfma_gemm_dual(
    const short* __restrict__ A,
    const short* __restrict__ BtM, const short* __restrict__ BtL,
    const float* __restrict__ biasM, const float* __restrict__ biasL, int biasN,
    short* __restrict__ Cout, int Cstat, int Cwrite, int Cstride, int Kpad,
    int mainLimit, int lgLimit,
    float* __restrict__ statsM, float* __restrict__ statsL) {
  __shared__ __align__(16) short ldsA[128 * 32];
  __shared__ __align__(16) short ldsB[128 * 32];
  __shared__ float sd[256];
  const int tid = threadIdx.x;
  const int lane = tid & 63, w = tid >> 6;
  const bool isMain = (int)blockIdx.y < MAIN_TILES;
  const short* Bt = isMain ? BtM : BtL;
  const float* bias = isMain ? biasM : biasL;
  const int rowLimit = isMain ? mainLimit : lgLimit;
  const int brow = blockIdx.y * 128;
  const int bcol = blockIdx.x * 128;
  const int wr = w >> 1, wc = w & 1;

  if (STATS) sd[tid] = 0.f;

  f32x4 acc[4][4] = {};

  const int sr = tid >> 2;
  const int sc = (tid & 3) * 8;
  char* la = (char*)ldsA + w * 1024;
  char* lb = (char*)ldsB + w * 1024;

  for (int k0 = 0; k0 < Kpad; k0 += 32) {
    __syncthreads();
    const short* gA0 = A + (size_t)(brow + sr) * Kpad + (k0 + sc);
    const short* gB0 = Bt + (size_t)(bcol + sr) * Kpad + (k0 + sc);
    gload_lds16(gA0, la);
    gload_lds16(gA0 + (size_t)64 * Kpad, la + 4096);
    gload_lds16(gB0, lb);
    gload_lds16(gB0 + (size_t)64 * Kpad, lb + 4096);
    __syncthreads();

    const int kq = (lane >> 4) * 16;
    half8 af[4], bf[4];
#pragma unroll
    for (int m = 0; m < 4; ++m) {
      int row = wr * 64 + m * 16 + (lane & 15);
      af[m] = *(const half8*)((const char*)ldsA + row * 64 + kq);
    }
#pragma unroll
    for (int n = 0; n < 4; ++n) {
      int col = wc * 64 + n * 16 + (lane & 15);
      bf[n] = *(const half8*)((const char*)ldsB + col * 64 + kq);
    }
#pragma unroll
    for (int m = 0; m < 4; ++m)
#pragma unroll
      for (int n = 0; n < 4; ++n)
        acc[m][n] = __builtin_amdgcn_mfma_f32_16x16x32_f16(af[m], bf[n], acc[m][n], 0, 0, 0);
  }

  const int r0 = brow + wr * 64;
  const int c0 = bcol + wc * 64;
  float ps[4] = {}, pq[4] = {};
#pragma unroll
  for (int m = 0; m < 4; ++m) {
#pragma unroll
    for (int i = 0; i < 4; ++i) {
      int row = r0 + m * 16 + (lane >> 4) * 4 + i;
      bool rv = row < rowLimit;
#pragma unroll
      for (int n = 0; n < 4; ++n) {
        int col = c0 + n * 16 + (lane & 15);
        float bv = (col < biasN) ? bias[col] : 0.f;
        float v = acc[m][n][i] + bv;
        if (RELU) v = fmaxf(v, 0.f);
        if (rv && col < Cwrite) {
          Cout[(size_t)row * Cstride + col] = f2h(v);
          if (STATS && col < Cstat) { ps[n] += v; pq[n] += v * v; }
        }
      }
    }
  }

  if (STATS) {
#pragma unroll
    for (int n = 0; n < 4; ++n) {
      float s = ps[n], q = pq[n];
      s += __shfl_xor(s, 16); q += __shfl_xor(q, 16);
      s += __shfl_xor(s, 32); q += __shfl_xor(q, 32);
      if ((lane >> 4) == 0) {
        int c = wc * 64 + n * 16 + (lane & 15);
        atomicAdd(&sd[c], s);
        atomicAdd(&sd[128 + c], q);
      }
    }
    __syncthreads();
    float* gs = isMain ? statsM : statsL;
    if (tid < 128) {
      int col = bcol + tid;
      if (col < Cstat) {
        atomicAdd(&gs[col], sd[tid]);
        atomicAdd(&gs[D + col], sd[128 + tid]);
      }
    }
  }
}

// ---------------- BN coef precompute (a = rs*gamma, b = beta - mu*a) -------------

__global__ void k_bn_coef(const float* __restrict__ stats,
                          const float* __restrict__ gM, const float* __restrict__ bM,
                          const float* __restrict__ gL, const float* __restrict__ bL,
                          float* __restrict__ coef) {
  int t = blockIdx.x * blockDim.x + threadIdx.x;
  if (t >= 640) return;
  bool m = t < 320;
  int c = m ? t : t - 320;
  float a = 0.f, b = 0.f;
  if (c < D) {
    const float* s = stats + (m ? 0 : 600);
    float inv_n = m ? (1.f / kN) : (1.f / kNLG);
    float mu = s[c] * inv_n;
    float var = s[D + c] * inv_n - mu * mu;
    a = rsqrtf(var + 1e-5f) * (m ? gM : gL)[c];
    b = (m ? bM : bL)[c] - mu * a;
  }
  int base = m ? 0 : 640;
  coef[base + c] = a;
  coef[base + 320 + c] = b;
}

// ---------------- BN apply (x8 vectorized; reads fp16 preact, coef table) --------

template<bool RELU, bool WRITE_HIST>
__global__ void k_bn_apply_v(const uint4* __restrict__ pre, const float* __restrict__ coef,
                             float* __restrict__ outF, uint4* __restrict__ hist) {
  int g = blockIdx.x * blockDim.x + threadIdx.x;
  if (g >= NALL * RQ) return;
  int r = g / RQ, q = g - r * RQ;
  bool m = r < kN;
  int pr = m ? r : MP_N + (r - kN);
  float v[8], y[8];
  unpk8(pre[(size_t)pr * RQ + q], v);
  const float* cb = coef + (m ? 0 : 640);
  float4 a0 = *(const float4*)(cb + q * 8);
  float4 a1 = *(const float4*)(cb + q * 8 + 4);
  float4 b0 = *(const float4*)(cb + 320 + q * 8);
  float4 b1 = *(const float4*)(cb + 320 + q * 8 + 4);
  y[0] = a0.x * v[0] + b0.x; y[1] = a0.y * v[1] + b0.y;
  y[2] = a0.z * v[2] + b0.z; y[3] = a0.w * v[3] + b0.w;
  y[4] = a1.x * v[4] + b1.x; y[5] = a1.y * v[5] + b1.y;
  y[6] = a1.z * v[6] + b1.z; y[7] = a1.w * v[7] + b1.w;
  if (RELU) {
#pragma unroll
    for (int i = 0; i < 8; ++i) y[i] = fmaxf(y[i], 0.f);
  }
  float* op = outF + (size_t)r * D + q * 8;
  if (q < 37) {
    *(float4*)op = make_float4(y[0], y[1], y[2], y[3]);
    *(float4*)(op + 4) = make_float4(y[4], y[5], y[6], y[7]);
  } else if (q == 37) {
    *(float4*)op = make_float4(y[0], y[1], y[2], y[3]);
  }
  if (WRITE_HIST) hist[(size_t)r * RQ + q] = pk4(y);
}

}  // namespace

extern "C" void kernel_launch(void* const* d_in, const int* in_sizes, int n_in,
                              void* d_out_v, int out_size, void* d_ws, size_t ws_size,
                              hipStream_t stream) {
  const int*   x            = (const int*)d_in[0];
  const int*   edge_index   = (const int*)d_in[1];
  const int*   edge_attr    = (const int*)d_in[2];
  const int*   lg_x         = (const int*)d_in[3];
  const int*   lg_edge_index= (const int*)d_in[4];
  const int*   lg_map       = (const int*)d_in[5];
  const int*   lg_map2      = (const int*)d_in[6];
  const float* node_emb1    = (const float*)d_in[7];
  const float* node_emb2    = (const float*)d_in[8];
  const float* gnn_e_emb1   = (const float*)d_in[9];
  const float* gnn_e_emb2   = (const float*)d_in[10];
  const float* g_emb1       = (const float*)d_in[11];
  const float* g_emb2       = (const float*)d_in[12];
  const float* g_w1         = (const float*)d_in[13];
  const float* g_b1         = (const float*)d_in[14];
  const float* g_w2         = (const float*)d_in[15];
  const float* g_b2         = (const float*)d_in[16];
  const float* g_gamma      = (const float*)d_in[17];
  const float* g_beta       = (const float*)d_in[18];
  const float* lg_emb1      = (const float*)d_in[19];
  const float* lg_emb2      = (const float*)d_in[20];
  const float* lg_w1        = (const float*)d_in[21];
  const float* lg_b1        = (const float*)d_in[22];
  const float* lg_w2        = (const float*)d_in[23];
  const float* lg_b2        = (const float*)d_in[24];
  const float* lg_gamma     = (const float*)d_in[25];
  const float* lg_beta      = (const float*)d_in[26];

  float* out = (float*)d_out_v;
  char*  ws  = (char*)d_ws;

  size_t off = 0;
  auto alloc = [&](size_t bytes) { void* p = ws + off; off = (off + bytes + 255) & ~(size_t)255; return p; };
  short* ab      = (short*)alloc((size_t)MP_ALL * K1P * 2);          // 38.5 MB
  short* hidden  = (short*)alloc((size_t)MP_ALL * N1P * 2);          // 77 MB
  short* pre16   = (short*)alloc((size_t)MP_ALL * PQH * 2);          // 38.5 MB
  short* hist2   = (short*)alloc((size_t)2 * NALL * RH * 2);         // 76.8 MB ping-pong
  short* g_w1t   = (short*)alloc((size_t)kL * N1P * K1P * 2);
  short* g_w2t   = (short*)alloc((size_t)kL * N2P * K2P * 2);
  short* lg_w1t  = (short*)alloc((size_t)kL * N1P * K1P * 2);
  short* lg_w2t  = (short*)alloc((size_t)kL * N2P * K2P * 2);
  float* stats   = (float*)alloc(kL * 1200 * 4);
  float* slv     = (float*)alloc(kL * 640 * 4);
  float* coef    = (float*)alloc(1280 * 4);
  short* tcm     = (short*)alloc(18 * RH * 2);
  short* tcl     = (short*)alloc(360 * RH * 2);
  int* cam     = (int*)alloc(kE * 4);
  int* cal     = (int*)alloc(kELG * 4);
  int* m0_offs = (int*)alloc((kN + 1) * 4);
  int* m0_cur  = (int*)alloc(kN * 4);
  int* m0_perm = (int*)alloc(kE * 4);
  int* mL_offs = (int*)alloc((kN + 1) * 4);
  int* mL_cur  = (int*)alloc(kN * 4);
  int* mL_perm = (int*)alloc(2 * kNLG * 4);
  int* lg_offs = (int*)alloc((kNLG + 1) * 4);
  int* lg_cur  = (int*)alloc(kNLG * 4);
  int* lg_perm = (int*)alloc(kELG * 4);

  auto hptr = [&](int l) { return out + (size_t)l * 60000 * D; };
  auto slot_h = [&](int s) { return hist2 + (size_t)s * NALL * RH; };
  auto slot_e = [&](int s) { return hist2 + (size_t)s * NALL * RH + (size_t)kN * RH; };

  dim3 b(256);

  // ---- prologue ----
  k_init<<<(kNLG + 255) / 256, b, 0, stream>>>(stats, ab, m0_cur, mL_cur, lg_cur);
  {
    int tot = kE + 2 * kNLG + kELG;
    k_hist_all<<<(tot + 255) / 256, b, 0, stream>>>(edge_index, lg_map, lg_edge_index,
                                                    edge_attr, lg_map2, x,
                                                    m0_cur, mL_cur, lg_cur, cam, cal);
    k_scan3<<<3, b, 0, stream>>>(m0_cur, m0_offs, mL_cur, mL_offs, lg_cur, lg_offs);
    k_fill_all<<<(tot + 255) / 256, b, 0, stream>>>(edge_index, lg_map, lg_edge_index,
                                                    m0_cur, m0_perm, mL_cur, mL_perm,
                                                    lg_cur, lg_perm);
  }
  k_selfvec<<<(kL * 640 + 255) / 256, b, 0, stream>>>(g_emb1, g_emb2, lg_emb1, lg_emb2, slv);
  k_comb_tab<<<(378 * RH + 255) / 256, b, 0, stream>>>(g_emb1, g_emb2, lg_emb1, lg_emb2,
                                                       tcm, tcl);
  {
    int tot = 2 * kL * (N1P * K1P + N2P * K2P);
    k_convert_wt_all<<<(tot + 255) / 256, b, 0, stream>>>(g_w1, g_w2, lg_w1, lg_w2,
                                                          g_w1t, g_w2t, lg_w1t, lg_w2t);
  }
  k_embed_all<<<(NALL * RQ + 255) / 256, b, 0, stream>>>(x, lg_x, node_emb1, node_emb2,
                                                         gnn_e_emb1, gnn_e_emb2,
                                                         hptr(0), (uint4*)slot_h(0));

  int cur = 0;
  for (int l = 0; l < kL; ++l) {
    float* slot = stats + (size_t)l * 1200;
    const float* slvM = slv + (size_t)l * 640;
    const float* slvL = slvM + 320;

    if (l == 0)
      k_gather_all0<<<(NALL + 3) / 4, b, 0, stream>>>(
          (const uint4*)slot_h(cur), (const uint4*)slot_e(cur),
          edge_index, lg_edge_index, cam, cal,
          (const uint4*)tcm, (const uint4*)tcl,
          slvM, slvL, m0_offs, m0_perm, lg_offs, lg_perm, (uint4*)ab);
    else
      k_gather_allL<<<(NALL + 3) / 4, b, 0, stream>>>(
          (const uint4*)slot_h(cur), (const uint4*)slot_e(cur),
          lg_map, lg_edge_index, lg_map2,
          slvM, slvL, mL_offs, mL_perm, lg_offs, lg_perm, (uint4*)ab);

    k_mfma_gemm_dual<true, false><<<dim3(N1P / 128, MP_ALL / 128), b, 0, stream>>>(
        ab, g_w1t + (size_t)l * N1P * K1P, lg_w1t + (size_t)l * N1P * K1P,
        g_b1 + (size_t)l * 2 * D, lg_b1 + (size_t)l * 2 * D, 2 * D,
        hidden, 0, N1P, N1P, K1P, MP_ALL, MP_ALL, nullptr, nullptr);

    k_mfma_gemm_dual<false, true><<<dim3(N2P / 128, MP_ALL / 128), b, 0, stream>>>(
        hidden, g_w2t + (size_t)l * N2P * K2P, lg_w2t + (size_t)l * N2P * K2P,
        g_b2 + (size_t)l * D, lg_b2 + (size_t)l * D, D,
        pre16, D, PQH, PQH, K2P, kN, MP_N + kNLG,
        slot, slot + 600);

    k_bn_coef<<<3, b, 0, stream>>>(slot,
                                   g_gamma + (size_t)l * D, g_beta + (size_t)l * D,
                                   lg_gamma + (size_t)l * D, lg_beta + (size_t)l * D, coef);

    int nxt = cur ^ 1;
    if (l < kL - 1)
      k_bn_apply_v<true, true><<<(NALL * RQ + 255) / 256, b, 0, stream>>>(
          (const uint4*)pre16, coef, hptr(l + 1), (uint4*)slot_h(nxt));
    else
      k_bn_apply_v<false, false><<<(NALL * RQ + 255) / 256, b, 0, stream>>>(
          (const uint4*)pre16, coef, hptr(l + 1), (uint4*)slot_h(nxt));
    cur = nxt;
  }
}

// Round 13
// 1397.313 us; speedup vs baseline: 1.0611x; 1.0611x over previous
//
#include <hip/hip_runtime.h>

#define D 300

namespace {

constexpr int kN   = 20000;
constexpr int kNLG = 40000;
constexpr int kE   = 80000;
constexpr int kELG = 200000;
constexpr int kL   = 5;

constexpr int K1P = 320;        // padded feature dim (fp16) = A-row width
constexpr int N1P = 640;
constexpr int K2P = 640;
constexpr int N2P = 384;        // GEMM2 col tiles (3x128)
constexpr int PQH = 320;        // preact row stride (halves)
constexpr int MP_N   = 20096;   // main rows padded (157 tiles)
constexpr int MP_ALL = 60160;   // + 40064 lg rows = 470 tiles
constexpr int MAIN_TILES = 157;
constexpr int NRT = 470;        // row tiles
constexpr int NRP = 59;         // ceil(470/8) padded row-tile groups
constexpr int RH = 320;         // halves per padded row
constexpr int RQ = 40;          // uint4 per padded row
constexpr int NALL = kN + kNLG; // 60000

typedef __attribute__((ext_vector_type(8))) _Float16 half8;
typedef __attribute__((ext_vector_type(2))) _Float16 half2v;
typedef __attribute__((ext_vector_type(4))) float f32x4;

__device__ inline short f2h(float f) {
  _Float16 h = (_Float16)f;
  return __builtin_bit_cast(short, h);
}

__device__ inline float2 upk(unsigned u) {
  half2v h = __builtin_bit_cast(half2v, u);
  return make_float2((float)h.x, (float)h.y);
}

__device__ inline unsigned pk(float a, float b) {
  half2v h;
  h.x = (_Float16)a;
  h.y = (_Float16)b;
  return __builtin_bit_cast(unsigned, h);
}

__device__ inline void addrow(float* acc, uint4 r) {
  float2 t0 = upk(r.x), t1 = upk(r.y), t2 = upk(r.z), t3 = upk(r.w);
  acc[0] += t0.x; acc[1] += t0.y; acc[2] += t1.x; acc[3] += t1.y;
  acc[4] += t2.x; acc[5] += t2.y; acc[6] += t3.x; acc[7] += t3.y;
}

__device__ inline void unpk8(uint4 r, float* v) {
  float2 t0 = upk(r.x), t1 = upk(r.y), t2 = upk(r.z), t3 = upk(r.w);
  v[0] = t0.x; v[1] = t0.y; v[2] = t1.x; v[3] = t1.y;
  v[4] = t2.x; v[5] = t2.y; v[6] = t3.x; v[7] = t3.y;
}

__device__ inline uint4 pk4(const float* a) {
  uint4 r;
  r.x = pk(a[0], a[1]); r.y = pk(a[2], a[3]);
  r.z = pk(a[4], a[5]); r.w = pk(a[6], a[7]);
  return r;
}

__device__ inline void gload_lds16(const void* g, void* l) {
  __builtin_amdgcn_global_load_lds(
      (const __attribute__((address_space(1))) void*)g,
      (__attribute__((address_space(3))) void*)l, 16, 0, 0);
}

// ---------------- init: stats, ab pad rows, CSR cursors ----------------

__global__ void k_init(float* __restrict__ stats, short* __restrict__ ab,
                       int* __restrict__ m0_cur, int* __restrict__ mL_cur,
                       int* __restrict__ lg_cur) {
  int g = blockIdx.x * blockDim.x + threadIdx.x;
  if (g < kL * 1200) stats[g] = 0.f;
  int np1 = (MP_N - kN) * K1P;
  int np2 = (MP_ALL - MP_N - kNLG) * K1P;
  if (g < np1) ab[(size_t)kN * K1P + g] = 0;
  if (g < np2) ab[(size_t)(MP_N + kNLG) * K1P + g] = 0;
  if (g < kN) { m0_cur[g] = 0; mL_cur[g] = 0; }
  if (g < kNLG) lg_cur[g] = 0;
}

// ---------------- CSR build (merged; also builds combined attr indices) ---------

__global__ void k_hist_all(const int* __restrict__ edge_index,
                           const int* __restrict__ lg_map,
                           const int* __restrict__ lg_ei,
                           const int* __restrict__ eattr,
                           const int* __restrict__ map2,
                           const int* __restrict__ x,
                           int* __restrict__ m0_cur, int* __restrict__ mL_cur,
                           int* __restrict__ lg_cur,
                           int* __restrict__ cam, int* __restrict__ cal) {
  int g = blockIdx.x * blockDim.x + threadIdx.x;
  if (g < kE) {
    atomicAdd(&m0_cur[edge_index[kE + g]], 1);
    cam[g] = eattr[2 * g] * 3 + eattr[2 * g + 1];
    return;
  }
  g -= kE;
  if (g < kNLG) { atomicAdd(&mL_cur[lg_map[kNLG + g]], 1); return; }
  g -= kNLG;
  if (g < kNLG) { atomicAdd(&mL_cur[lg_map[g]], 1); return; }
  g -= kNLG;
  if (g < kELG) {
    atomicAdd(&lg_cur[lg_ei[kELG + g]], 1);
    int a = map2[g];
    cal[g] = x[2 * a] * 3 + x[2 * a + 1];
  }
}

__device__ void scan_one(int* cursor, int* offs, int n) {
  __shared__ int part[256];
  int tid = threadIdx.x;
  int chunk = (n + 255) / 256;
  int s0 = tid * chunk;
  int s1 = min(n, s0 + chunk);
  int sum = 0;
  for (int i = s0; i < s1; ++i) sum += cursor[i];
  part[tid] = sum;
  __syncthreads();
  for (int off = 1; off < 256; off <<= 1) {
    int v = (tid >= off) ? part[tid - off] : 0;
    __syncthreads();
    part[tid] += v;
    __syncthreads();
  }
  int run = (tid == 0) ? 0 : part[tid - 1];
  for (int i = s0; i < s1; ++i) {
    int dv = cursor[i];
    offs[i] = run;
    cursor[i] = run;
    run += dv;
  }
  if (tid == 255) offs[n] = run;
}

__global__ __launch_bounds__(256) void k_scan3(
    int* __restrict__ m0_cur, int* __restrict__ m0_offs,
    int* __restrict__ mL_cur, int* __restrict__ mL_offs,
    int* __restrict__ lg_cur, int* __restrict__ lg_offs) {
  if (blockIdx.x == 0) scan_one(m0_cur, m0_offs, kN);
  else if (blockIdx.x == 1) scan_one(mL_cur, mL_offs, kN);
  else scan_one(lg_cur, lg_offs, kNLG);
}

__global__ void k_fill_all(const int* __restrict__ edge_index,
                           const int* __restrict__ lg_map,
                           const int* __restrict__ lg_ei,
                           int* __restrict__ m0_cur, int* __restrict__ m0_perm,
                           int* __restrict__ mL_cur, int* __restrict__ mL_perm,
                           int* __restrict__ lg_cur, int* __restrict__ lg_perm) {
  int g = blockIdx.x * blockDim.x + threadIdx.x;
  if (g < kE) {
    int pos = atomicAdd(&m0_cur[edge_index[kE + g]], 1);
    m0_perm[pos] = g;
    return;
  }
  g -= kE;
  if (g < kNLG) {
    int pos = atomicAdd(&mL_cur[lg_map[kNLG + g]], 1);
    mL_perm[pos] = g;
    return;
  }
  g -= kNLG;
  if (g < kNLG) {
    int pos = atomicAdd(&mL_cur[lg_map[g]], 1);
    mL_perm[pos] = kNLG + g;
    return;
  }
  g -= kNLG;
  if (g < kELG) {
    int pos = atomicAdd(&lg_cur[lg_ei[kELG + g]], 1);
    lg_perm[pos] = g;
  }
}

// ---------------- precompute: self vectors, combined tables, weights -----------

__global__ void k_selfvec(const float* __restrict__ g1, const float* __restrict__ g2,
                          const float* __restrict__ l1, const float* __restrict__ l2,
                          float* __restrict__ slv) {
  int g = blockIdx.x * blockDim.x + threadIdx.x;
  if (g >= kL * 640) return;
  int l = g / 640, rem = g - l * 640;
  int gr = rem / 320, c = rem - gr * 320;
  float v = 0.f;
  if (c < D) {
    if (gr == 0) v = g1[(size_t)l * 6 * D + 4 * D + c] + g2[(size_t)l * 3 * D + c];
    else         v = l1[(size_t)l * 120 * D + 119 * D + c] + l2[(size_t)l * 3 * D + c];
  }
  slv[g] = v;
}

__global__ void k_comb_tab(const float* __restrict__ g1, const float* __restrict__ g2,
                           const float* __restrict__ l1, const float* __restrict__ l2,
                           short* __restrict__ tcm, short* __restrict__ tcl) {
  int g = blockIdx.x * blockDim.x + threadIdx.x;
  if (g < 18 * RH) {
    int p = g / RH, c = g - p * RH;
    float v = (c < D) ? g1[(size_t)(p / 3) * D + c] + g2[(size_t)(p % 3) * D + c] : 0.f;
    tcm[g] = f2h(v);
    return;
  }
  g -= 18 * RH;
  if (g < 360 * RH) {
    int p = g / RH, c = g - p * RH;
    float v = (c < D) ? l1[(size_t)(p / 3) * D + c] + l2[(size_t)(p % 3) * D + c] : 0.f;
    tcl[g] = f2h(v);
  }
}

__device__ void cvt_w1(const float* W, short* Wt, int g) {
  int per = N1P * K1P;
  int l = g / per, rem = g - l * per;
  int n = rem / K1P, k = rem - n * K1P;
  float v = (n < 2 * D && k < D) ? W[(size_t)l * D * 2 * D + (size_t)k * 2 * D + n] : 0.f;
  Wt[g] = f2h(v);
}

__device__ void cvt_w2(const float* W, short* Wt, int g) {
  int per = N2P * K2P;
  int l = g / per, rem = g - l * per;
  int n = rem / K2P, k = rem - n * K2P;
  float v = (n < D && k < 2 * D) ? W[(size_t)l * 2 * D * D + (size_t)k * D + n] : 0.f;
  Wt[g] = f2h(v);
}

__global__ void k_convert_wt_all(const float* __restrict__ g_w1, const float* __restrict__ g_w2,
                                 const float* __restrict__ lg_w1, const float* __restrict__ lg_w2,
                                 short* __restrict__ g_w1t, short* __restrict__ g_w2t,
                                 short* __restrict__ lg_w1t, short* __restrict__ lg_w2t) {
  int g = blockIdx.x * blockDim.x + threadIdx.x;
  const int s1 = kL * N1P * K1P, s2 = kL * N2P * K2P;
  if (g < s1) { cvt_w1(g_w1, g_w1t, g); return; }
  g -= s1;
  if (g < s2) { cvt_w2(g_w2, g_w2t, g); return; }
  g -= s2;
  if (g < s1) { cvt_w1(lg_w1, lg_w1t, g); return; }
  g -= s1;
  if (g < s2) cvt_w2(lg_w2, lg_w2t, g);
}

// ---------------- embed (merged main+lg, x8 vectorized) ----------------

__global__ void k_embed_all(const int* __restrict__ x, const int* __restrict__ lg_x,
                            const float* __restrict__ t1m, const float* __restrict__ t2m,
                            const float* __restrict__ t1l, const float* __restrict__ t2l,
                            float* __restrict__ outF, uint4* __restrict__ hist) {
  int g = blockIdx.x * blockDim.x + threadIdx.x;
  if (g >= NALL * RQ) return;
  int r = g / RQ, q = g - r * RQ;
  bool m = r < kN;
  int i = m ? r : r - kN;
  const int* ix = (m ? x : lg_x) + 2 * i;
  const float* t1 = (m ? t1m : t1l) + (size_t)ix[0] * D;
  const float* t2 = (m ? t2m : t2l) + (size_t)ix[1] * D;
  int c0 = q * 8;
  float y[8] = {0.f, 0.f, 0.f, 0.f, 0.f, 0.f, 0.f, 0.f};
  if (c0 < D) {
    float4 p0 = *(const float4*)(t1 + c0);
    float4 q0 = *(const float4*)(t2 + c0);
    y[0] = p0.x + q0.x; y[1] = p0.y + q0.y; y[2] = p0.z + q0.z; y[3] = p0.w + q0.w;
    *(float4*)(outF + (size_t)r * D + c0) = make_float4(y[0], y[1], y[2], y[3]);
    if (c0 + 8 <= D) {
      float4 p1 = *(const float4*)(t1 + c0 + 4);
      float4 q1 = *(const float4*)(t2 + c0 + 4);
      y[4] = p1.x + q1.x; y[5] = p1.y + q1.y; y[6] = p1.z + q1.z; y[7] = p1.w + q1.w;
      *(float4*)(outF + (size_t)r * D + c0 + 4) = make_float4(y[4], y[5], y[6], y[7]);
    }
  }
  hist[(size_t)r * RQ + q] = pk4(y);
}

// ---------------- gathers: 4-deep unrolled (round-11 proven loop) ----------------

#define GATHER_BODY                                                     \
  int p0 = offs[j], p1 = offs[j + 1];                                   \
  for (int pb = p0; pb < p1; pb += 64) {                                \
    int cnt = min(64, p1 - pb);                                         \
    int e_ = permp[pb + ((lane < cnt) ? lane : 0)];                     \
    int ra, rb;                                                         \
    GATHER_IDX                                                          \
    int t = 0;                                                          \
    for (; t + 3 < cnt; t += 4) {                                       \
      int a0 = __shfl(ra, t),     b0 = __shfl(rb, t);                   \
      int a1 = __shfl(ra, t + 1), b1 = __shfl(rb, t + 1);               \
      int a2 = __shfl(ra, t + 2), b2 = __shfl(rb, t + 2);               \
      int a3 = __shfl(ra, t + 3), b3 = __shfl(rb, t + 3);               \
      uint4 x0 = bA[(size_t)a0 * RQ + ll];                              \
      uint4 y0 = bB[(size_t)b0 * RQ + ll];                              \
      uint4 x1 = bA[(size_t)a1 * RQ + ll];                              \
      uint4 y1 = bB[(size_t)b1 * RQ + ll];                              \
      uint4 x2 = bA[(size_t)a2 * RQ + ll];                              \
      uint4 y2 = bB[(size_t)b2 * RQ + ll];                              \
      uint4 x3 = bA[(size_t)a3 * RQ + ll];                              \
      uint4 y3 = bB[(size_t)b3 * RQ + ll];                              \
      addrow(acc, x0); addrow(acc, y0);                                 \
      addrow(acc, x1); addrow(acc, y1);                                 \
      addrow(acc, x2); addrow(acc, y2);                                 \
      addrow(acc, x3); addrow(acc, y3);                                 \
    }                                                                   \
    for (; t < cnt; ++t) {                                              \
      int a0 = __shfl(ra, t), b0 = __shfl(rb, t);                       \
      uint4 x0 = bA[(size_t)a0 * RQ + ll];                              \
      uint4 y0 = bB[(size_t)b0 * RQ + ll];                              \
      addrow(acc, x0); addrow(acc, y0);                                 \
    }                                                                   \
  }

__global__ void k_gather_all0(
    const uint4* __restrict__ h16, const uint4* __restrict__ e16,
    const int* __restrict__ m_src, const int* __restrict__ lg_src,
    const int* __restrict__ cam, const int* __restrict__ cal,
    const uint4* __restrict__ tcm, const uint4* __restrict__ tcl,
    const float* __restrict__ slvM, const float* __restrict__ slvL,
    const int* __restrict__ m_offs, const int* __restrict__ m_perm,
    const int* __restrict__ l_offs, const int* __restrict__ l_perm,
    uint4* __restrict__ ab) {
  int node = blockIdx.x * 4 + (threadIdx.x >> 6);
  int lane = threadIdx.x & 63;
  if (node >= NALL) return;
  bool act = lane < RQ;
  int ll = act ? lane : 0;
  bool isM = node < kN;
  int j = isM ? node : node - kN;
  const uint4* selfrow = isM ? (h16 + (size_t)node * RQ) : (e16 + (size_t)j * RQ);
  const float* sv = (isM ? slvM : slvL) + ll * 8;
  const int* offs = isM ? m_offs : l_offs;
  const int* permp = isM ? m_perm : l_perm;
  const uint4* bA = isM ? h16 : e16;
  const uint4* bB = isM ? tcm : tcl;
  const int* srcp = isM ? m_src : lg_src;
  const int* catp = isM ? cam : cal;

  float acc[8];
  {
    float vv[8];
    unpk8(selfrow[ll], vv);
#pragma unroll
    for (int i = 0; i < 8; ++i) acc[i] = vv[i] + sv[i];
  }

#define GATHER_IDX ra = srcp[e_]; rb = catp[e_];
  GATHER_BODY
#undef GATHER_IDX

  if (act) ab[(size_t)(isM ? node : MP_N + j) * RQ + ll] = pk4(acc);
}

__global__ void k_gather_allL(
    const uint4* __restrict__ h16, const uint4* __restrict__ e16,
    const int* __restrict__ lg_map, const int* __restrict__ lg_src,
    const int* __restrict__ map2,
    const float* __restrict__ slvM, const float* __restrict__ slvL,
    const int* __restrict__ m_offs, const int* __restrict__ m_perm,
    const int* __restrict__ l_offs, const int* __restrict__ l_perm,
    uint4* __restrict__ ab) {
  int node = blockIdx.x * 4 + (threadIdx.x >> 6);
  int lane = threadIdx.x & 63;
  if (node >= NALL) return;
  bool act = lane < RQ;
  int ll = act ? lane : 0;
  bool isM = node < kN;
  int j = isM ? node : node - kN;
  const uint4* selfrow = isM ? (h16 + (size_t)node * RQ) : (e16 + (size_t)j * RQ);
  const float* sv = (isM ? slvM : slvL) + ll * 8;
  const int* offs = isM ? m_offs : l_offs;
  const int* permp = isM ? m_perm : l_perm;
  const uint4* bA = isM ? h16 : e16;
  const uint4* bB = isM ? e16 : h16;

  float acc[8];
  {
    float vv[8];
    unpk8(selfrow[ll], vv);
#pragma unroll
    for (int i = 0; i < 8; ++i) acc[i] = vv[i] + sv[i];
  }

#define GATHER_IDX                                     \
  if (isM) {                                           \
    ra = lg_map[e_];                                   \
    rb = (e_ < kNLG) ? e_ : e_ - kNLG;                 \
  } else {                                             \
    ra = lg_src[e_];                                   \
    rb = map2[e_];                                     \
  }
  GATHER_BODY
#undef GATHER_IDX

  if (act) ab[(size_t)(isM ? node : MP_N + j) * RQ + ll] = pk4(acc);
}

// ---------------- dual MFMA GEMM ----------------
// 1-D grid, XCD-aware swizzle: all col-tiles of a row-panel land on one XCD.
// 2-phase double-buffered LDS: stage k+1 while computing k; 1 barrier/step.

template<bool RELU, bool STATS>
__global__ __launch_bounds__(256) void k_mfma_gemm_dual(
    const short* __restrict__ A,
    const short* __restrict__ BtM, const short* __restrict__ BtL,
    const float* __restrict__ biasM, const float* __restrict__ biasL, int biasN,
    short* __restrict__ Cout, int Cstat, int Cwrite, int Cstride,
    int Astride, int Kloop, int NC,
    int mainLimit, int lgLimit,
    float* __restrict__ statsM, float* __restrict__ statsL) {
  __shared__ __align__(16) short ldsA[2][128 * 32];
  __shared__ __align__(16) short ldsB[2][128 * 32];
  __shared__ float sd[256];

  // swizzle: bid -> (rtile, c) with rtile ≡ bid (mod 8) so one XCD owns a row-panel
  int bid = blockIdx.x;
  int xcd = bid & 7;
  int t0 = bid >> 3;
  int c = t0 % NC;
  int rr = t0 / NC;
  int rtile = rr * 8 + xcd;
  if (rtile >= NRT) return;

  const int tid = threadIdx.x;
  const int lane = tid & 63, w = tid >> 6;
  const bool isMain = rtile < MAIN_TILES;
  const short* Bt = isMain ? BtM : BtL;
  const float* bias = isMain ? biasM : biasL;
  const int rowLimit = isMain ? mainLimit : lgLimit;
  const int brow = rtile * 128;
  const int bcol = c * 128;
  const int wr = w >> 1, wc = w & 1;

  if (STATS) sd[tid] = 0.f;

  f32x4 acc[4][4] = {};

  const int sr = tid >> 2;
  const int sc = (tid & 3) * 8;

  auto stage = [&](int buf, int k0) {
    char* la = (char*)(&ldsA[buf][0]) + w * 1024;
    char* lb = (char*)(&ldsB[buf][0]) + w * 1024;
    const short* gA0 = A + (size_t)(brow + sr) * Astride + (k0 + sc);
    const short* gB0 = Bt + (size_t)(bcol + sr) * Astride + (k0 + sc);
    gload_lds16(gA0, la);
    gload_lds16(gA0 + (size_t)64 * Astride, la + 4096);
    gload_lds16(gB0, lb);
    gload_lds16(gB0 + (size_t)64 * Astride, lb + 4096);
  };

  const int nt = Kloop / 32;
  stage(0, 0);
  __syncthreads();

  for (int t = 0; t < nt; ++t) {
    int cb = t & 1;
    if (t + 1 < nt) stage(cb ^ 1, (t + 1) * 32);

    const int kq = (lane >> 4) * 16;
    const char* baseA = (const char*)(&ldsA[cb][0]);
    const char* baseB = (const char*)(&ldsB[cb][0]);
    half8 af[4], bf[4];
#pragma unroll
    for (int m = 0; m < 4; ++m) {
      int row = wr * 64 + m * 16 + (lane & 15);
      af[m] = *(const half8*)(baseA + row * 64 + kq);
    }
#pragma unroll
    for (int n = 0; n < 4; ++n) {
      int col = wc * 64 + n * 16 + (lane & 15);
      bf[n] = *(const half8*)(baseB + col * 64 + kq);
    }
#pragma unroll
    for (int m = 0; m < 4; ++m)
#pragma unroll
      for (int n = 0; n < 4; ++n)
        acc[m][n] = __builtin_amdgcn_mfma_f32_16x16x32_f16(af[m], bf[n], acc[m][n], 0, 0, 0);
    __syncthreads();  // drains staged loads (vmcnt 0) + protects buffer reuse
  }

  const int r0 = brow + wr * 64;
  const int c0 = bcol + wc * 64;
  float ps[4] = {}, pq[4] = {};
#pragma unroll
  for (int m = 0; m < 4; ++m) {
#pragma unroll
    for (int i = 0; i < 4; ++i) {
      int row = r0 + m * 16 + (lane >> 4) * 4 + i;
      bool rv = row < rowLimit;
#pragma unroll
      for (int n = 0; n < 4; ++n) {
        int col = c0 + n * 16 + (lane & 15);
        float bv = (col < biasN) ? bias[col] : 0.f;
        float v = acc[m][n][i] + bv;
        if (RELU) v = fmaxf(v, 0.f);
        if (rv && col < Cwrite) {
          Cout[(size_t)row * Cstride + col] = f2h(v);
          if (STATS && col < Cstat) { ps[n] += v; pq[n] += v * v; }
        }
      }
    }
  }

  if (STATS) {
#pragma unroll
    for (int n = 0; n < 4; ++n) {
      float s = ps[n], q = pq[n];
      s += __shfl_xor(s, 16); q += __shfl_xor(q, 16);
      s += __shfl_xor(s, 32); q += __shfl_xor(q, 32);
      if ((lane >> 4) == 0) {
        int cc = wc * 64 + n * 16 + (lane & 15);
        atomicAdd(&sd[cc], s);
        atomicAdd(&sd[128 + cc], q);
      }
    }
    __syncthreads();
    float* gs = isMain ? statsM : statsL;
    if (tid < 128) {
      int col = bcol + tid;
      if (col < Cstat) {
        atomicAdd(&gs[col], sd[tid]);
        atomicAdd(&gs[D + col], sd[128 + tid]);
      }
    }
  }
}

// ---------------- BN coef precompute (a = rs*gamma, b = beta - mu*a) -------------

__global__ void k_bn_coef(const float* __restrict__ stats,
                          const float* __restrict__ gM, const float* __restrict__ bM,
                          const float* __restrict__ gL, const float* __restrict__ bL,
                          float* __restrict__ coef) {
  int t = blockIdx.x * blockDim.x + threadIdx.x;
  if (t >= 640) return;
  bool m = t < 320;
  int c = m ? t : t - 320;
  float a = 0.f, b = 0.f;
  if (c < D) {
    const float* s = stats + (m ? 0 : 600);
    float inv_n = m ? (1.f / kN) : (1.f / kNLG);
    float mu = s[c] * inv_n;
    float var = s[D + c] * inv_n - mu * mu;
    a = rsqrtf(var + 1e-5f) * (m ? gM : gL)[c];
    b = (m ? bM : bL)[c] - mu * a;
  }
  int base = m ? 0 : 640;
  coef[base + c] = a;
  coef[base + 320 + c] = b;
}

// ---------------- BN apply (x8 vectorized; reads fp16 preact, coef table) --------

template<bool RELU, bool WRITE_HIST>
__global__ void k_bn_apply_v(const uint4* __restrict__ pre, const float* __restrict__ coef,
                             float* __restrict__ outF, uint4* __restrict__ hist) {
  int g = blockIdx.x * blockDim.x + threadIdx.x;
  if (g >= NALL * RQ) return;
  int r = g / RQ, q = g - r * RQ;
  bool m = r < kN;
  int pr = m ? r : MP_N + (r - kN);
  float v[8], y[8];
  unpk8(pre[(size_t)pr * RQ + q], v);
  const float* cb = coef + (m ? 0 : 640);
  float4 a0 = *(const float4*)(cb + q * 8);
  float4 a1 = *(const float4*)(cb + q * 8 + 4);
  float4 b0 = *(const float4*)(cb + 320 + q * 8);
  float4 b1 = *(const float4*)(cb + 320 + q * 8 + 4);
  y[0] = a0.x * v[0] + b0.x; y[1] = a0.y * v[1] + b0.y;
  y[2] = a0.z * v[2] + b0.z; y[3] = a0.w * v[3] + b0.w;
  y[4] = a1.x * v[4] + b1.x; y[5] = a1.y * v[5] + b1.y;
  y[6] = a1.z * v[6] + b1.z; y[7] = a1.w * v[7] + b1.w;
  if (RELU) {
#pragma unroll
    for (int i = 0; i < 8; ++i) y[i] = fmaxf(y[i], 0.f);
  }
  float* op = outF + (size_t)r * D + q * 8;
  if (q < 37) {
    *(float4*)op = make_float4(y[0], y[1], y[2], y[3]);
    *(float4*)(op + 4) = make_float4(y[4], y[5], y[6], y[7]);
  } else if (q == 37) {
    *(float4*)op = make_float4(y[0], y[1], y[2], y[3]);
  }
  if (WRITE_HIST) hist[(size_t)r * RQ + q] = pk4(y);
}

}  // namespace

extern "C" void kernel_launch(void* const* d_in, const int* in_sizes, int n_in,
                              void* d_out_v, int out_size, void* d_ws, size_t ws_size,
                              hipStream_t stream) {
  const int*   x            = (const int*)d_in[0];
  const int*   edge_index   = (const int*)d_in[1];
  const int*   edge_attr    = (const int*)d_in[2];
  const int*   lg_x         = (const int*)d_in[3];
  const int*   lg_edge_index= (const int*)d_in[4];
  const int*   lg_map       = (const int*)d_in[5];
  const int*   lg_map2      = (const int*)d_in[6];
  const float* node_emb1    = (const float*)d_in[7];
  const float* node_emb2    = (const float*)d_in[8];
  const float* gnn_e_emb1   = (const float*)d_in[9];
  const float* gnn_e_emb2   = (const float*)d_in[10];
  const float* g_emb1       = (const float*)d_in[11];
  const float* g_emb2       = (const float*)d_in[12];
  const float* g_w1         = (const float*)d_in[13];
  const float* g_b1         = (const float*)d_in[14];
  const float* g_w2         = (const float*)d_in[15];
  const float* g_b2         = (const float*)d_in[16];
  const float* g_gamma      = (const float*)d_in[17];
  const float* g_beta       = (const float*)d_in[18];
  const float* lg_emb1      = (const float*)d_in[19];
  const float* lg_emb2      = (const float*)d_in[20];
  const float* lg_w1        = (const float*)d_in[21];
  const float* lg_b1        = (const float*)d_in[22];
  const float* lg_w2        = (const float*)d_in[23];
  const float* lg_b2        = (const float*)d_in[24];
  const float* lg_gamma     = (const float*)d_in[25];
  const float* lg_beta      = (const float*)d_in[26];

  float* out = (float*)d_out_v;
  char*  ws  = (char*)d_ws;

  size_t off = 0;
  auto alloc = [&](size_t bytes) { void* p = ws + off; off = (off + bytes + 255) & ~(size_t)255; return p; };
  short* ab      = (short*)alloc((size_t)MP_ALL * K1P * 2);          // 38.5 MB
  short* hidden  = (short*)alloc((size_t)MP_ALL * N1P * 2);          // 77 MB
  short* pre16   = (short*)alloc((size_t)MP_ALL * PQH * 2);          // 38.5 MB
  short* hist2   = (short*)alloc((size_t)2 * NALL * RH * 2);         // 76.8 MB ping-pong
  short* g_w1t   = (short*)alloc((size_t)kL * N1P * K1P * 2);
  short* g_w2t   = (short*)alloc((size_t)kL * N2P * K2P * 2);
  short* lg_w1t  = (short*)alloc((size_t)kL * N1P * K1P * 2);
  short* lg_w2t  = (short*)alloc((size_t)kL * N2P * K2P * 2);
  float* stats   = (float*)alloc(kL * 1200 * 4);
  float* slv     = (float*)alloc(kL * 640 * 4);
  float* coef    = (float*)alloc(1280 * 4);
  short* tcm     = (short*)alloc(18 * RH * 2);
  short* tcl     = (short*)alloc(360 * RH * 2);
  int* cam     = (int*)alloc(kE * 4);
  int* cal     = (int*)alloc(kELG * 4);
  int* m0_offs = (int*)alloc((kN + 1) * 4);
  int* m0_cur  = (int*)alloc(kN * 4);
  int* m0_perm = (int*)alloc(kE * 4);
  int* mL_offs = (int*)alloc((kN + 1) * 4);
  int* mL_cur  = (int*)alloc(kN * 4);
  int* mL_perm = (int*)alloc(2 * kNLG * 4);
  int* lg_offs = (int*)alloc((kNLG + 1) * 4);
  int* lg_cur  = (int*)alloc(kNLG * 4);
  int* lg_perm = (int*)alloc(kELG * 4);

  auto hptr = [&](int l) { return out + (size_t)l * 60000 * D; };
  auto slot_h = [&](int s) { return hist2 + (size_t)s * NALL * RH; };
  auto slot_e = [&](int s) { return hist2 + (size_t)s * NALL * RH + (size_t)kN * RH; };

  dim3 b(256);

  // ---- prologue ----
  k_init<<<(kNLG + 255) / 256, b, 0, stream>>>(stats, ab, m0_cur, mL_cur, lg_cur);
  {
    int tot = kE + 2 * kNLG + kELG;
    k_hist_all<<<(tot + 255) / 256, b, 0, stream>>>(edge_index, lg_map, lg_edge_index,
                                                    edge_attr, lg_map2, x,
                                                    m0_cur, mL_cur, lg_cur, cam, cal);
    k_scan3<<<3, b, 0, stream>>>(m0_cur, m0_offs, mL_cur, mL_offs, lg_cur, lg_offs);
    k_fill_all<<<(tot + 255) / 256, b, 0, stream>>>(edge_index, lg_map, lg_edge_index,
                                                    m0_cur, m0_perm, mL_cur, mL_perm,
                                                    lg_cur, lg_perm);
  }
  k_selfvec<<<(kL * 640 + 255) / 256, b, 0, stream>>>(g_emb1, g_emb2, lg_emb1, lg_emb2, slv);
  k_comb_tab<<<(378 * RH + 255) / 256, b, 0, stream>>>(g_emb1, g_emb2, lg_emb1, lg_emb2,
                                                       tcm, tcl);
  {
    int tot = 2 * kL * (N1P * K1P + N2P * K2P);
    k_convert_wt_all<<<(tot + 255) / 256, b, 0, stream>>>(g_w1, g_w2, lg_w1, lg_w2,
                                                          g_w1t, g_w2t, lg_w1t, lg_w2t);
  }
  k_embed_all<<<(NALL * RQ + 255) / 256, b, 0, stream>>>(x, lg_x, node_emb1, node_emb2,
                                                         gnn_e_emb1, gnn_e_emb2,
                                                         hptr(0), (uint4*)slot_h(0));

  int cur = 0;
  for (int l = 0; l < kL; ++l) {
    float* slot = stats + (size_t)l * 1200;
    const float* slvM = slv + (size_t)l * 640;
    const float* slvL = slvM + 320;

    if (l == 0)
      k_gather_all0<<<(NALL + 3) / 4, b, 0, stream>>>(
          (const uint4*)slot_h(cur), (const uint4*)slot_e(cur),
          edge_index, lg_edge_index, cam, cal,
          (const uint4*)tcm, (const uint4*)tcl,
          slvM, slvL, m0_offs, m0_perm, lg_offs, lg_perm, (uint4*)ab);
    else
      k_gather_allL<<<(NALL + 3) / 4, b, 0, stream>>>(
          (const uint4*)slot_h(cur), (const uint4*)slot_e(cur),
          lg_map, lg_edge_index, lg_map2,
          slvM, slvL, mL_offs, mL_perm, lg_offs, lg_perm, (uint4*)ab);

    // GEMM1: A[ab 320-stride], K=320, 5 col-tiles, write 608 hidden cols
    k_mfma_gemm_dual<true, false><<<8 * NRP * 5, b, 0, stream>>>(
        ab, g_w1t + (size_t)l * N1P * K1P, lg_w1t + (size_t)l * N1P * K1P,
        g_b1 + (size_t)l * 2 * D, lg_b1 + (size_t)l * 2 * D, 2 * D,
        hidden, 0, 608, N1P, K1P, K1P, 5, MP_ALL, MP_ALL, nullptr, nullptr);

    // GEMM2: A[hidden 640-stride], K=608 (cols 600..607 are zeros), 3 col-tiles
    k_mfma_gemm_dual<false, true><<<8 * NRP * 3, b, 0, stream>>>(
        hidden, g_w2t + (size_t)l * N2P * K2P, lg_w2t + (size_t)l * N2P * K2P,
        g_b2 + (size_t)l * D, lg_b2 + (size_t)l * D, D,
        pre16, D, PQH, PQH, K2P, 608, 3, kN, MP_N + kNLG,
        slot, slot + 600);

    k_bn_coef<<<3, b, 0, stream>>>(slot,
                                   g_gamma + (size_t)l * D, g_beta + (size_t)l * D,
                                   lg_gamma + (size_t)l * D, lg_beta + (size_t)l * D, coef);

    int nxt = cur ^ 1;
    if (l < kL - 1)
      k_bn_apply_v<true, true><<<(NALL * RQ + 255) / 256, b, 0, stream>>>(
          (const uint4*)pre16, coef, hptr(l + 1), (uint4*)slot_h(nxt));
    else
      k_bn_apply_v<false, false><<<(NALL * RQ + 255) / 256, b, 0, stream>>>(
          (const uint4*)pre16, coef, hptr(l + 1), (uint4*)slot_h(nxt));
    cur = nxt;
  }
}

// Round 14
// 1389.450 us; speedup vs baseline: 1.0671x; 1.0057x over previous
//
#include <hip/hip_runtime.h>

#define D 300

namespace {

constexpr int kN   = 20000;
constexpr int kNLG = 40000;
constexpr int kE   = 80000;
constexpr int kELG = 200000;
constexpr int kL   = 5;

constexpr int K1P = 320;        // padded feature dim (fp16) = A-row width
constexpr int N1P = 640;
constexpr int K2P = 640;
constexpr int N2P = 384;        // GEMM2 col tiles (3x128)
constexpr int PQH = 320;        // preact row stride (halves)
constexpr int MP_N   = 20096;   // main rows padded (157 tiles)
constexpr int MP_ALL = 60160;   // + 40064 lg rows = 470 tiles
constexpr int MAIN_TILES = 157;
constexpr int NRT = 470;        // row tiles
constexpr int NRP = 59;         // ceil(470/8)
constexpr int RH = 320;         // halves per padded row
constexpr int RQ = 40;          // uint4 per padded row
constexpr int NALL = kN + kNLG; // 60000

typedef __attribute__((ext_vector_type(8))) _Float16 half8;
typedef __attribute__((ext_vector_type(2))) _Float16 half2v;
typedef __attribute__((ext_vector_type(4))) float f32x4;

__device__ inline short f2h(float f) {
  _Float16 h = (_Float16)f;
  return __builtin_bit_cast(short, h);
}

__device__ inline float2 upk(unsigned u) {
  half2v h = __builtin_bit_cast(half2v, u);
  return make_float2((float)h.x, (float)h.y);
}

__device__ inline unsigned pk(float a, float b) {
  half2v h;
  h.x = (_Float16)a;
  h.y = (_Float16)b;
  return __builtin_bit_cast(unsigned, h);
}

__device__ inline void addrow(float* acc, uint4 r) {
  float2 t0 = upk(r.x), t1 = upk(r.y), t2 = upk(r.z), t3 = upk(r.w);
  acc[0] += t0.x; acc[1] += t0.y; acc[2] += t1.x; acc[3] += t1.y;
  acc[4] += t2.x; acc[5] += t2.y; acc[6] += t3.x; acc[7] += t3.y;
}

__device__ inline void unpk8(uint4 r, float* v) {
  float2 t0 = upk(r.x), t1 = upk(r.y), t2 = upk(r.z), t3 = upk(r.w);
  v[0] = t0.x; v[1] = t0.y; v[2] = t1.x; v[3] = t1.y;
  v[4] = t2.x; v[5] = t2.y; v[6] = t3.x; v[7] = t3.y;
}

__device__ inline uint4 pk4(const float* a) {
  uint4 r;
  r.x = pk(a[0], a[1]); r.y = pk(a[2], a[3]);
  r.z = pk(a[4], a[5]); r.w = pk(a[6], a[7]);
  return r;
}

__device__ inline void gload_lds16(const void* g, void* l) {
  __builtin_amdgcn_global_load_lds(
      (const __attribute__((address_space(1))) void*)g,
      (__attribute__((address_space(3))) void*)l, 16, 0, 0);
}

// ---------------- init: stats, ab pad rows, CSR cursors ----------------

__global__ void k_init(float* __restrict__ stats, short* __restrict__ ab,
                       int* __restrict__ m0_cur, int* __restrict__ mL_cur,
                       int* __restrict__ lg_cur) {
  int g = blockIdx.x * blockDim.x + threadIdx.x;
  if (g < kL * 1200) stats[g] = 0.f;
  int np1 = (MP_N - kN) * K1P;
  int np2 = (MP_ALL - MP_N - kNLG) * K1P;
  if (g < np1) ab[(size_t)kN * K1P + g] = 0;
  if (g < np2) ab[(size_t)(MP_N + kNLG) * K1P + g] = 0;
  if (g < kN) { m0_cur[g] = 0; mL_cur[g] = 0; }
  if (g < kNLG) lg_cur[g] = 0;
}

// ---------------- CSR build (merged; also builds combined attr indices) ---------

__global__ void k_hist_all(const int* __restrict__ edge_index,
                           const int* __restrict__ lg_map,
                           const int* __restrict__ lg_ei,
                           const int* __restrict__ eattr,
                           const int* __restrict__ map2,
                           const int* __restrict__ x,
                           int* __restrict__ m0_cur, int* __restrict__ mL_cur,
                           int* __restrict__ lg_cur,
                           int* __restrict__ cam, int* __restrict__ cal) {
  int g = blockIdx.x * blockDim.x + threadIdx.x;
  if (g < kE) {
    atomicAdd(&m0_cur[edge_index[kE + g]], 1);
    cam[g] = eattr[2 * g] * 3 + eattr[2 * g + 1];
    return;
  }
  g -= kE;
  if (g < kNLG) { atomicAdd(&mL_cur[lg_map[kNLG + g]], 1); return; }
  g -= kNLG;
  if (g < kNLG) { atomicAdd(&mL_cur[lg_map[g]], 1); return; }
  g -= kNLG;
  if (g < kELG) {
    atomicAdd(&lg_cur[lg_ei[kELG + g]], 1);
    int a = map2[g];
    cal[g] = x[2 * a] * 3 + x[2 * a + 1];
  }
}

__device__ void scan_one(int* cursor, int* offs, int n) {
  __shared__ int part[256];
  int tid = threadIdx.x;
  int chunk = (n + 255) / 256;
  int s0 = tid * chunk;
  int s1 = min(n, s0 + chunk);
  int sum = 0;
  for (int i = s0; i < s1; ++i) sum += cursor[i];
  part[tid] = sum;
  __syncthreads();
  for (int off = 1; off < 256; off <<= 1) {
    int v = (tid >= off) ? part[tid - off] : 0;
    __syncthreads();
    part[tid] += v;
    __syncthreads();
  }
  int run = (tid == 0) ? 0 : part[tid - 1];
  for (int i = s0; i < s1; ++i) {
    int dv = cursor[i];
    offs[i] = run;
    cursor[i] = run;
    run += dv;
  }
  if (tid == 255) offs[n] = run;
}

__global__ __launch_bounds__(256) void k_scan3(
    int* __restrict__ m0_cur, int* __restrict__ m0_offs,
    int* __restrict__ mL_cur, int* __restrict__ mL_offs,
    int* __restrict__ lg_cur, int* __restrict__ lg_offs) {
  if (blockIdx.x == 0) scan_one(m0_cur, m0_offs, kN);
  else if (blockIdx.x == 1) scan_one(mL_cur, mL_offs, kN);
  else scan_one(lg_cur, lg_offs, kNLG);
}

__global__ void k_fill_all(const int* __restrict__ edge_index,
                           const int* __restrict__ lg_map,
                           const int* __restrict__ lg_ei,
                           int* __restrict__ m0_cur, int* __restrict__ m0_perm,
                           int* __restrict__ mL_cur, int* __restrict__ mL_perm,
                           int* __restrict__ lg_cur, int* __restrict__ lg_perm) {
  int g = blockIdx.x * blockDim.x + threadIdx.x;
  if (g < kE) {
    int pos = atomicAdd(&m0_cur[edge_index[kE + g]], 1);
    m0_perm[pos] = g;
    return;
  }
  g -= kE;
  if (g < kNLG) {
    int pos = atomicAdd(&mL_cur[lg_map[kNLG + g]], 1);
    mL_perm[pos] = g;
    return;
  }
  g -= kNLG;
  if (g < kNLG) {
    int pos = atomicAdd(&mL_cur[lg_map[g]], 1);
    mL_perm[pos] = kNLG + g;
    return;
  }
  g -= kNLG;
  if (g < kELG) {
    int pos = atomicAdd(&lg_cur[lg_ei[kELG + g]], 1);
    lg_perm[pos] = g;
  }
}

// ---------------- merged precompute: selfvec + combined tables + weights --------

__device__ void cvt_w1(const float* W, short* Wt, int g) {
  int per = N1P * K1P;
  int l = g / per, rem = g - l * per;
  int n = rem / K1P, k = rem - n * K1P;
  float v = (n < 2 * D && k < D) ? W[(size_t)l * D * 2 * D + (size_t)k * 2 * D + n] : 0.f;
  Wt[g] = f2h(v);
}

__device__ void cvt_w2(const float* W, short* Wt, int g) {
  int per = N2P * K2P;
  int l = g / per, rem = g - l * per;
  int n = rem / K2P, k = rem - n * K2P;
  float v = (n < D && k < 2 * D) ? W[(size_t)l * 2 * D * D + (size_t)k * D + n] : 0.f;
  Wt[g] = f2h(v);
}

__global__ void k_precomp(const float* __restrict__ g1, const float* __restrict__ g2,
                          const float* __restrict__ l1, const float* __restrict__ l2,
                          const float* __restrict__ g_w1, const float* __restrict__ g_w2,
                          const float* __restrict__ lg_w1, const float* __restrict__ lg_w2,
                          float* __restrict__ slv, short* __restrict__ tcm,
                          short* __restrict__ tcl,
                          short* __restrict__ g_w1t, short* __restrict__ g_w2t,
                          short* __restrict__ lg_w1t, short* __restrict__ lg_w2t) {
  int g = blockIdx.x * blockDim.x + threadIdx.x;
  const int s1 = kL * N1P * K1P, s2 = kL * N2P * K2P;
  if (g < s1) { cvt_w1(g_w1, g_w1t, g); return; }
  g -= s1;
  if (g < s2) { cvt_w2(g_w2, g_w2t, g); return; }
  g -= s2;
  if (g < s1) { cvt_w1(lg_w1, lg_w1t, g); return; }
  g -= s1;
  if (g < s2) { cvt_w2(lg_w2, lg_w2t, g); return; }
  g -= s2;
  if (g < kL * 640) {  // self vectors
    int l = g / 640, rem = g - l * 640;
    int gr = rem / 320, c = rem - gr * 320;
    float v = 0.f;
    if (c < D) {
      if (gr == 0) v = g1[(size_t)l * 6 * D + 4 * D + c] + g2[(size_t)l * 3 * D + c];
      else         v = l1[(size_t)l * 120 * D + 119 * D + c] + l2[(size_t)l * 3 * D + c];
    }
    slv[g] = v;
    return;
  }
  g -= kL * 640;
  if (g < 18 * RH) {  // combined main table
    int p = g / RH, c = g - p * RH;
    float v = (c < D) ? g1[(size_t)(p / 3) * D + c] + g2[(size_t)(p % 3) * D + c] : 0.f;
    tcm[g] = f2h(v);
    return;
  }
  g -= 18 * RH;
  if (g < 360 * RH) {  // combined lg table
    int p = g / RH, c = g - p * RH;
    float v = (c < D) ? l1[(size_t)(p / 3) * D + c] + l2[(size_t)(p % 3) * D + c] : 0.f;
    tcl[g] = f2h(v);
  }
}

// ---------------- embed (merged main+lg, x8 vectorized) ----------------

__global__ void k_embed_all(const int* __restrict__ x, const int* __restrict__ lg_x,
                            const float* __restrict__ t1m, const float* __restrict__ t2m,
                            const float* __restrict__ t1l, const float* __restrict__ t2l,
                            float* __restrict__ outF, uint4* __restrict__ hist) {
  int g = blockIdx.x * blockDim.x + threadIdx.x;
  if (g >= NALL * RQ) return;
  int r = g / RQ, q = g - r * RQ;
  bool m = r < kN;
  int i = m ? r : r - kN;
  const int* ix = (m ? x : lg_x) + 2 * i;
  const float* t1 = (m ? t1m : t1l) + (size_t)ix[0] * D;
  const float* t2 = (m ? t2m : t2l) + (size_t)ix[1] * D;
  int c0 = q * 8;
  float y[8] = {0.f, 0.f, 0.f, 0.f, 0.f, 0.f, 0.f, 0.f};
  if (c0 < D) {
    float4 p0 = *(const float4*)(t1 + c0);
    float4 q0 = *(const float4*)(t2 + c0);
    y[0] = p0.x + q0.x; y[1] = p0.y + q0.y; y[2] = p0.z + q0.z; y[3] = p0.w + q0.w;
    *(float4*)(outF + (size_t)r * D + c0) = make_float4(y[0], y[1], y[2], y[3]);
    if (c0 + 8 <= D) {
      float4 p1 = *(const float4*)(t1 + c0 + 4);
      float4 q1 = *(const float4*)(t2 + c0 + 4);
      y[4] = p1.x + q1.x; y[5] = p1.y + q1.y; y[6] = p1.z + q1.z; y[7] = p1.w + q1.w;
      *(float4*)(outF + (size_t)r * D + c0 + 4) = make_float4(y[4], y[5], y[6], y[7]);
    }
  }
  hist[(size_t)r * RQ + q] = pk4(y);
}

// ---------------- gathers: 1 node per 64-thread block, 4-deep unrolled ----------

#define GATHER_BODY                                                     \
  int p0 = offs[j], p1 = offs[j + 1];                                   \
  for (int pb = p0; pb < p1; pb += 64) {                                \
    int cnt = min(64, p1 - pb);                                         \
    int e_ = permp[pb + ((lane < cnt) ? lane : 0)];                     \
    int ra, rb;                                                         \
    GATHER_IDX                                                          \
    int t = 0;                                                          \
    for (; t + 3 < cnt; t += 4) {                                       \
      int a0 = __shfl(ra, t),     b0 = __shfl(rb, t);                   \
      int a1 = __shfl(ra, t + 1), b1 = __shfl(rb, t + 1);               \
      int a2 = __shfl(ra, t + 2), b2 = __shfl(rb, t + 2);               \
      int a3 = __shfl(ra, t + 3), b3 = __shfl(rb, t + 3);               \
      uint4 x0 = bA[(size_t)a0 * RQ + ll];                              \
      uint4 y0 = bB[(size_t)b0 * RQ + ll];                              \
      uint4 x1 = bA[(size_t)a1 * RQ + ll];                              \
      uint4 y1 = bB[(size_t)b1 * RQ + ll];                              \
      uint4 x2 = bA[(size_t)a2 * RQ + ll];                              \
      uint4 y2 = bB[(size_t)b2 * RQ + ll];                              \
      uint4 x3 = bA[(size_t)a3 * RQ + ll];                              \
      uint4 y3 = bB[(size_t)b3 * RQ + ll];                              \
      addrow(acc, x0); addrow(acc, y0);                                 \
      addrow(acc, x1); addrow(acc, y1);                                 \
      addrow(acc, x2); addrow(acc, y2);                                 \
      addrow(acc, x3); addrow(acc, y3);                                 \
    }                                                                   \
    for (; t < cnt; ++t) {                                              \
      int a0 = __shfl(ra, t), b0 = __shfl(rb, t);                       \
      uint4 x0 = bA[(size_t)a0 * RQ + ll];                              \
      uint4 y0 = bB[(size_t)b0 * RQ + ll];                              \
      addrow(acc, x0); addrow(acc, y0);                                 \
    }                                                                   \
  }

__global__ __launch_bounds__(64) void k_gather_all0(
    const uint4* __restrict__ h16, const uint4* __restrict__ e16,
    const int* __restrict__ m_src, const int* __restrict__ lg_src,
    const int* __restrict__ cam, const int* __restrict__ cal,
    const uint4* __restrict__ tcm, const uint4* __restrict__ tcl,
    const float* __restrict__ slvM, const float* __restrict__ slvL,
    const int* __restrict__ m_offs, const int* __restrict__ m_perm,
    const int* __restrict__ l_offs, const int* __restrict__ l_perm,
    uint4* __restrict__ ab) {
  int node = blockIdx.x;
  int lane = threadIdx.x;
  bool act = lane < RQ;
  int ll = act ? lane : 0;
  bool isM = node < kN;
  int j = isM ? node : node - kN;
  const uint4* selfrow = isM ? (h16 + (size_t)node * RQ) : (e16 + (size_t)j * RQ);
  const float* sv = (isM ? slvM : slvL) + ll * 8;
  const int* offs = isM ? m_offs : l_offs;
  const int* permp = isM ? m_perm : l_perm;
  const uint4* bA = isM ? h16 : e16;
  const uint4* bB = isM ? tcm : tcl;
  const int* srcp = isM ? m_src : lg_src;
  const int* catp = isM ? cam : cal;

  float acc[8];
  {
    float vv[8];
    unpk8(selfrow[ll], vv);
#pragma unroll
    for (int i = 0; i < 8; ++i) acc[i] = vv[i] + sv[i];
  }

#define GATHER_IDX ra = srcp[e_]; rb = catp[e_];
  GATHER_BODY
#undef GATHER_IDX

  if (act) ab[(size_t)(isM ? node : MP_N + j) * RQ + ll] = pk4(acc);
}

__global__ __launch_bounds__(64) void k_gather_allL(
    const uint4* __restrict__ h16, const uint4* __restrict__ e16,
    const int* __restrict__ lg_map, const int* __restrict__ lg_src,
    const int* __restrict__ map2,
    const float* __restrict__ slvM, const float* __restrict__ slvL,
    const int* __restrict__ m_offs, const int* __restrict__ m_perm,
    const int* __restrict__ l_offs, const int* __restrict__ l_perm,
    uint4* __restrict__ ab) {
  int node = blockIdx.x;
  int lane = threadIdx.x;
  bool act = lane < RQ;
  int ll = act ? lane : 0;
  bool isM = node < kN;
  int j = isM ? node : node - kN;
  const uint4* selfrow = isM ? (h16 + (size_t)node * RQ) : (e16 + (size_t)j * RQ);
  const float* sv = (isM ? slvM : slvL) + ll * 8;
  const int* offs = isM ? m_offs : l_offs;
  const int* permp = isM ? m_perm : l_perm;
  const uint4* bA = isM ? h16 : e16;
  const uint4* bB = isM ? e16 : h16;

  float acc[8];
  {
    float vv[8];
    unpk8(selfrow[ll], vv);
#pragma unroll
    for (int i = 0; i < 8; ++i) acc[i] = vv[i] + sv[i];
  }

#define GATHER_IDX                                     \
  if (isM) {                                           \
    ra = lg_map[e_];                                   \
    rb = (e_ < kNLG) ? e_ : e_ - kNLG;                 \
  } else {                                             \
    ra = lg_src[e_];                                   \
    rb = map2[e_];                                     \
  }
  GATHER_BODY
#undef GATHER_IDX

  if (act) ab[(size_t)(isM ? node : MP_N + j) * RQ + ll] = pk4(acc);
}

// ---------------- dual MFMA GEMM ----------------
// 1-D grid, XCD-aware swizzle; 2-phase double-buffered LDS.

template<bool RELU, bool STATS>
__global__ __launch_bounds__(256) void k_mfma_gemm_dual(
    const short* __restrict__ A,
    const short* __restrict__ BtM, const short* __restrict__ BtL,
    const float* __restrict__ biasM, const float* __restrict__ biasL, int biasN,
    short* __restrict__ Cout, int Cstat, int Cwrite, int Cstride,
    int Astride, int Kloop, int NC,
    int mainLimit, int lgLimit,
    float* __restrict__ statsM, float* __restrict__ statsL) {
  __shared__ __align__(16) short ldsA[2][128 * 32];
  __shared__ __align__(16) short ldsB[2][128 * 32];
  __shared__ float sd[256];

  int bid = blockIdx.x;
  int xcd = bid & 7;
  int t0 = bid >> 3;
  int c = t0 % NC;
  int rr = t0 / NC;
  int rtile = rr * 8 + xcd;
  if (rtile >= NRT) return;

  const int tid = threadIdx.x;
  const int lane = tid & 63, w = tid >> 6;
  const bool isMain = rtile < MAIN_TILES;
  const short* Bt = isMain ? BtM : BtL;
  const float* bias = isMain ? biasM : biasL;
  const int rowLimit = isMain ? mainLimit : lgLimit;
  const int brow = rtile * 128;
  const int bcol = c * 128;
  const int wr = w >> 1, wc = w & 1;

  if (STATS) sd[tid] = 0.f;

  f32x4 acc[4][4] = {};

  const int sr = tid >> 2;
  const int sc = (tid & 3) * 8;

  auto stage = [&](int buf, int k0) {
    char* la = (char*)(&ldsA[buf][0]) + w * 1024;
    char* lb = (char*)(&ldsB[buf][0]) + w * 1024;
    const short* gA0 = A + (size_t)(brow + sr) * Astride + (k0 + sc);
    const short* gB0 = Bt + (size_t)(bcol + sr) * Astride + (k0 + sc);
    gload_lds16(gA0, la);
    gload_lds16(gA0 + (size_t)64 * Astride, la + 4096);
    gload_lds16(gB0, lb);
    gload_lds16(gB0 + (size_t)64 * Astride, lb + 4096);
  };

  const int nt = Kloop / 32;
  stage(0, 0);
  __syncthreads();

  for (int t = 0; t < nt; ++t) {
    int cb = t & 1;
    if (t + 1 < nt) stage(cb ^ 1, (t + 1) * 32);

    const int kq = (lane >> 4) * 16;
    const char* baseA = (const char*)(&ldsA[cb][0]);
    const char* baseB = (const char*)(&ldsB[cb][0]);
    half8 af[4], bf[4];
#pragma unroll
    for (int m = 0; m < 4; ++m) {
      int row = wr * 64 + m * 16 + (lane & 15);
      af[m] = *(const half8*)(baseA + row * 64 + kq);
    }
#pragma unroll
    for (int n = 0; n < 4; ++n) {
      int col = wc * 64 + n * 16 + (lane & 15);
      bf[n] = *(const half8*)(baseB + col * 64 + kq);
    }
#pragma unroll
    for (int m = 0; m < 4; ++m)
#pragma unroll
      for (int n = 0; n < 4; ++n)
        acc[m][n] = __builtin_amdgcn_mfma_f32_16x16x32_f16(af[m], bf[n], acc[m][n], 0, 0, 0);
    __syncthreads();
  }

  const int r0 = brow + wr * 64;
  const int c0 = bcol + wc * 64;
  float ps[4] = {}, pq[4] = {};
#pragma unroll
  for (int m = 0; m < 4; ++m) {
#pragma unroll
    for (int i = 0; i < 4; ++i) {
      int row = r0 + m * 16 + (lane >> 4) * 4 + i;
      bool rv = row < rowLimit;
#pragma unroll
      for (int n = 0; n < 4; ++n) {
        int col = c0 + n * 16 + (lane & 15);
        float bv = (col < biasN) ? bias[col] : 0.f;
        float v = acc[m][n][i] + bv;
        if (RELU) v = fmaxf(v, 0.f);
        if (rv && col < Cwrite) {
          Cout[(size_t)row * Cstride + col] = f2h(v);
          if (STATS && col < Cstat) { ps[n] += v; pq[n] += v * v; }
        }
      }
    }
  }

  if (STATS) {
#pragma unroll
    for (int n = 0; n < 4; ++n) {
      float s = ps[n], q = pq[n];
      s += __shfl_xor(s, 16); q += __shfl_xor(q, 16);
      s += __shfl_xor(s, 32); q += __shfl_xor(q, 32);
      if ((lane >> 4) == 0) {
        int cc = wc * 64 + n * 16 + (lane & 15);
        atomicAdd(&sd[cc], s);
        atomicAdd(&sd[128 + cc], q);
      }
    }
    __syncthreads();
    float* gs = isMain ? statsM : statsL;
    if (tid < 128) {
      int col = bcol + tid;
      if (col < Cstat) {
        atomicAdd(&gs[col], sd[tid]);
        atomicAdd(&gs[D + col], sd[128 + tid]);
      }
    }
  }
}

// ---------------- BN coef precompute ----------------

__global__ void k_bn_coef(const float* __restrict__ stats,
                          const float* __restrict__ gM, const float* __restrict__ bM,
                          const float* __restrict__ gL, const float* __restrict__ bL,
                          float* __restrict__ coef) {
  int t = blockIdx.x * blockDim.x + threadIdx.x;
  if (t >= 640) return;
  bool m = t < 320;
  int c = m ? t : t - 320;
  float a = 0.f, b = 0.f;
  if (c < D) {
    const float* s = stats + (m ? 0 : 600);
    float inv_n = m ? (1.f / kN) : (1.f / kNLG);
    float mu = s[c] * inv_n;
    float var = s[D + c] * inv_n - mu * mu;
    a = rsqrtf(var + 1e-5f) * (m ? gM : gL)[c];
    b = (m ? bM : bL)[c] - mu * a;
  }
  int base = m ? 0 : 640;
  coef[base + c] = a;
  coef[base + 320 + c] = b;
}

// ---------------- BN apply (x8 vectorized) ----------------

template<bool RELU, bool WRITE_HIST>
__global__ void k_bn_apply_v(const uint4* __restrict__ pre, const float* __restrict__ coef,
                             float* __restrict__ outF, uint4* __restrict__ hist) {
  int g = blockIdx.x * blockDim.x + threadIdx.x;
  if (g >= NALL * RQ) return;
  int r = g / RQ, q = g - r * RQ;
  bool m = r < kN;
  int pr = m ? r : MP_N + (r - kN);
  float v[8], y[8];
  unpk8(pre[(size_t)pr * RQ + q], v);
  const float* cb = coef + (m ? 0 : 640);
  float4 a0 = *(const float4*)(cb + q * 8);
  float4 a1 = *(const float4*)(cb + q * 8 + 4);
  float4 b0 = *(const float4*)(cb + 320 + q * 8);
  float4 b1 = *(const float4*)(cb + 320 + q * 8 + 4);
  y[0] = a0.x * v[0] + b0.x; y[1] = a0.y * v[1] + b0.y;
  y[2] = a0.z * v[2] + b0.z; y[3] = a0.w * v[3] + b0.w;
  y[4] = a1.x * v[4] + b1.x; y[5] = a1.y * v[5] + b1.y;
  y[6] = a1.z * v[6] + b1.z; y[7] = a1.w * v[7] + b1.w;
  if (RELU) {
#pragma unroll
    for (int i = 0; i < 8; ++i) y[i] = fmaxf(y[i], 0.f);
  }
  float* op = outF + (size_t)r * D + q * 8;
  if (q < 37) {
    *(float4*)op = make_float4(y[0], y[1], y[2], y[3]);
    *(float4*)(op + 4) = make_float4(y[4], y[5], y[6], y[7]);
  } else if (q == 37) {
    *(float4*)op = make_float4(y[0], y[1], y[2], y[3]);
  }
  if (WRITE_HIST) hist[(size_t)r * RQ + q] = pk4(y);
}

}  // namespace

extern "C" void kernel_launch(void* const* d_in, const int* in_sizes, int n_in,
                              void* d_out_v, int out_size, void* d_ws, size_t ws_size,
                              hipStream_t stream) {
  const int*   x            = (const int*)d_in[0];
  const int*   edge_index   = (const int*)d_in[1];
  const int*   edge_attr    = (const int*)d_in[2];
  const int*   lg_x         = (const int*)d_in[3];
  const int*   lg_edge_index= (const int*)d_in[4];
  const int*   lg_map       = (const int*)d_in[5];
  const int*   lg_map2      = (const int*)d_in[6];
  const float* node_emb1    = (const float*)d_in[7];
  const float* node_emb2    = (const float*)d_in[8];
  const float* gnn_e_emb1   = (const float*)d_in[9];
  const float* gnn_e_emb2   = (const float*)d_in[10];
  const float* g_emb1       = (const float*)d_in[11];
  const float* g_emb2       = (const float*)d_in[12];
  const float* g_w1         = (const float*)d_in[13];
  const float* g_b1         = (const float*)d_in[14];
  const float* g_w2         = (const float*)d_in[15];
  const float* g_b2         = (const float*)d_in[16];
  const float* g_gamma      = (const float*)d_in[17];
  const float* g_beta       = (const float*)d_in[18];
  const float* lg_emb1      = (const float*)d_in[19];
  const float* lg_emb2      = (const float*)d_in[20];
  const float* lg_w1        = (const float*)d_in[21];
  const float* lg_b1        = (const float*)d_in[22];
  const float* lg_w2        = (const float*)d_in[23];
  const float* lg_b2        = (const float*)d_in[24];
  const float* lg_gamma     = (const float*)d_in[25];
  const float* lg_beta      = (const float*)d_in[26];

  float* out = (float*)d_out_v;
  char*  ws  = (char*)d_ws;

  size_t off = 0;
  auto alloc = [&](size_t bytes) { void* p = ws + off; off = (off + bytes + 255) & ~(size_t)255; return p; };
  short* ab      = (short*)alloc((size_t)MP_ALL * K1P * 2);
  short* hidden  = (short*)alloc((size_t)MP_ALL * N1P * 2);
  short* pre16   = (short*)alloc((size_t)MP_ALL * PQH * 2);
  short* hist2   = (short*)alloc((size_t)2 * NALL * RH * 2);
  short* g_w1t   = (short*)alloc((size_t)kL * N1P * K1P * 2);
  short* g_w2t   = (short*)alloc((size_t)kL * N2P * K2P * 2);
  short* lg_w1t  = (short*)alloc((size_t)kL * N1P * K1P * 2);
  short* lg_w2t  = (short*)alloc((size_t)kL * N2P * K2P * 2);
  float* stats   = (float*)alloc(kL * 1200 * 4);
  float* slv     = (float*)alloc(kL * 640 * 4);
  float* coef    = (float*)alloc(1280 * 4);
  short* tcm     = (short*)alloc(18 * RH * 2);
  short* tcl     = (short*)alloc(360 * RH * 2);
  int* cam     = (int*)alloc(kE * 4);
  int* cal     = (int*)alloc(kELG * 4);
  int* m0_offs = (int*)alloc((kN + 1) * 4);
  int* m0_cur  = (int*)alloc(kN * 4);
  int* m0_perm = (int*)alloc(kE * 4);
  int* mL_offs = (int*)alloc((kN + 1) * 4);
  int* mL_cur  = (int*)alloc(kN * 4);
  int* mL_perm = (int*)alloc(2 * kNLG * 4);
  int* lg_offs = (int*)alloc((kNLG + 1) * 4);
  int* lg_cur  = (int*)alloc(kNLG * 4);
  int* lg_perm = (int*)alloc(kELG * 4);

  auto hptr = [&](int l) { return out + (size_t)l * 60000 * D; };
  auto slot_h = [&](int s) { return hist2 + (size_t)s * NALL * RH; };
  auto slot_e = [&](int s) { return hist2 + (size_t)s * NALL * RH + (size_t)kN * RH; };

  dim3 b(256);

  // ---- prologue (6 dispatches) ----
  k_init<<<(kNLG + 255) / 256, b, 0, stream>>>(stats, ab, m0_cur, mL_cur, lg_cur);
  {
    int tot = kE + 2 * kNLG + kELG;
    k_hist_all<<<(tot + 255) / 256, b, 0, stream>>>(edge_index, lg_map, lg_edge_index,
                                                    edge_attr, lg_map2, x,
                                                    m0_cur, mL_cur, lg_cur, cam, cal);
    k_scan3<<<3, b, 0, stream>>>(m0_cur, m0_offs, mL_cur, mL_offs, lg_cur, lg_offs);
    k_fill_all<<<(tot + 255) / 256, b, 0, stream>>>(edge_index, lg_map, lg_edge_index,
                                                    m0_cur, m0_perm, mL_cur, mL_perm,
                                                    lg_cur, lg_perm);
  }
  {
    int tot = 2 * kL * (N1P * K1P + N2P * K2P) + kL * 640 + 378 * RH;
    k_precomp<<<(tot + 255) / 256, b, 0, stream>>>(g_emb1, g_emb2, lg_emb1, lg_emb2,
                                                   g_w1, g_w2, lg_w1, lg_w2,
                                                   slv, tcm, tcl,
                                                   g_w1t, g_w2t, lg_w1t, lg_w2t);
  }
  k_embed_all<<<(NALL * RQ + 255) / 256, b, 0, stream>>>(x, lg_x, node_emb1, node_emb2,
                                                         gnn_e_emb1, gnn_e_emb2,
                                                         hptr(0), (uint4*)slot_h(0));

  int cur = 0;
  for (int l = 0; l < kL; ++l) {
    float* slot = stats + (size_t)l * 1200;
    const float* slvM = slv + (size_t)l * 640;
    const float* slvL = slvM + 320;

    if (l == 0)
      k_gather_all0<<<NALL, 64, 0, stream>>>(
          (const uint4*)slot_h(cur), (const uint4*)slot_e(cur),
          edge_index, lg_edge_index, cam, cal,
          (const uint4*)tcm, (const uint4*)tcl,
          slvM, slvL, m0_offs, m0_perm, lg_offs, lg_perm, (uint4*)ab);
    else
      k_gather_allL<<<NALL, 64, 0, stream>>>(
          (const uint4*)slot_h(cur), (const uint4*)slot_e(cur),
          lg_map, lg_edge_index, lg_map2,
          slvM, slvL, mL_offs, mL_perm, lg_offs, lg_perm, (uint4*)ab);

    k_mfma_gemm_dual<true, false><<<8 * NRP * 5, b, 0, stream>>>(
        ab, g_w1t + (size_t)l * N1P * K1P, lg_w1t + (size_t)l * N1P * K1P,
        g_b1 + (size_t)l * 2 * D, lg_b1 + (size_t)l * 2 * D, 2 * D,
        hidden, 0, 608, N1P, K1P, K1P, 5, MP_ALL, MP_ALL, nullptr, nullptr);

    k_mfma_gemm_dual<false, true><<<8 * NRP * 3, b, 0, stream>>>(
        hidden, g_w2t + (size_t)l * N2P * K2P, lg_w2t + (size_t)l * N2P * K2P,
        g_b2 + (size_t)l * D, lg_b2 + (size_t)l * D, D,
        pre16, D, PQH, PQH, K2P, 608, 3, kN, MP_N + kNLG,
        slot, slot + 600);

    k_bn_coef<<<3, b, 0, stream>>>(slot,
                                   g_gamma + (size_t)l * D, g_beta + (size_t)l * D,
                                   lg_gamma + (size_t)l * D, lg_beta + (size_t)l * D, coef);

    int nxt = cur ^ 1;
    if (l < kL - 1)
      k_bn_apply_v<true, true><<<(NALL * RQ + 255) / 256, b, 0, stream>>>(
          (const uint4*)pre16, coef, hptr(l + 1), (uint4*)slot_h(nxt));
    else
      k_bn_apply_v<false, false><<<(NALL * RQ + 255) / 256, b, 0, stream>>>(
          (const uint4*)pre16, coef, hptr(l + 1), (uint4*)slot_h(nxt));
    cur = nxt;
  }
}

// Round 15
// 1343.884 us; speedup vs baseline: 1.1033x; 1.0339x over previous
//
#include <hip/hip_runtime.h>

#define D 300

namespace {

constexpr int kN   = 20000;
constexpr int kNLG = 40000;
constexpr int kE   = 80000;
constexpr int kELG = 200000;
constexpr int kL   = 5;

constexpr int K1P = 320;
constexpr int N1P = 640;
constexpr int K2P = 640;
constexpr int N2P = 384;
constexpr int PQH = 320;        // preact row stride (halves)
constexpr int MP_N   = 20096;
constexpr int MP_ALL = 60160;
constexpr int MAIN_TILES = 157;
constexpr int NRT = 470;
constexpr int NRP = 59;
constexpr int RH = 320;
constexpr int RQ = 40;
constexpr int NALL = kN + kNLG;

typedef __attribute__((ext_vector_type(8))) _Float16 half8;
typedef __attribute__((ext_vector_type(2))) _Float16 half2v;
typedef __attribute__((ext_vector_type(4))) float f32x4;

__device__ inline short f2h(float f) {
  _Float16 h = (_Float16)f;
  return __builtin_bit_cast(short, h);
}

__device__ inline float2 upk(unsigned u) {
  half2v h = __builtin_bit_cast(half2v, u);
  return make_float2((float)h.x, (float)h.y);
}

__device__ inline unsigned pk(float a, float b) {
  half2v h;
  h.x = (_Float16)a;
  h.y = (_Float16)b;
  return __builtin_bit_cast(unsigned, h);
}

__device__ inline void addrow(float* acc, uint4 r) {
  float2 t0 = upk(r.x), t1 = upk(r.y), t2 = upk(r.z), t3 = upk(r.w);
  acc[0] += t0.x; acc[1] += t0.y; acc[2] += t1.x; acc[3] += t1.y;
  acc[4] += t2.x; acc[5] += t2.y; acc[6] += t3.x; acc[7] += t3.y;
}

__device__ inline void unpk8(uint4 r, float* v) {
  float2 t0 = upk(r.x), t1 = upk(r.y), t2 = upk(r.z), t3 = upk(r.w);
  v[0] = t0.x; v[1] = t0.y; v[2] = t1.x; v[3] = t1.y;
  v[4] = t2.x; v[5] = t2.y; v[6] = t3.x; v[7] = t3.y;
}

__device__ inline uint4 pk4(const float* a) {
  uint4 r;
  r.x = pk(a[0], a[1]); r.y = pk(a[2], a[3]);
  r.z = pk(a[4], a[5]); r.w = pk(a[6], a[7]);
  return r;
}

__device__ inline void gload_lds16(const void* g, void* l) {
  __builtin_amdgcn_global_load_lds(
      (const __attribute__((address_space(1))) void*)g,
      (__attribute__((address_space(3))) void*)l, 16, 0, 0);
}

// ---------------- init ----------------

__global__ void k_init(float* __restrict__ stats, short* __restrict__ ab,
                       int* __restrict__ m0_cur, int* __restrict__ mL_cur,
                       int* __restrict__ lg_cur) {
  int g = blockIdx.x * blockDim.x + threadIdx.x;
  if (g < kL * 1200) stats[g] = 0.f;
  int np1 = (MP_N - kN) * K1P;
  int np2 = (MP_ALL - MP_N - kNLG) * K1P;
  if (g < np1) ab[(size_t)kN * K1P + g] = 0;
  if (g < np2) ab[(size_t)(MP_N + kNLG) * K1P + g] = 0;
  if (g < kN) { m0_cur[g] = 0; mL_cur[g] = 0; }
  if (g < kNLG) lg_cur[g] = 0;
}

// ---------------- CSR build ----------------

__global__ void k_hist_all(const int* __restrict__ edge_index,
                           const int* __restrict__ lg_map,
                           const int* __restrict__ lg_ei,
                           const int* __restrict__ eattr,
                           const int* __restrict__ map2,
                           const int* __restrict__ x,
                           int* __restrict__ m0_cur, int* __restrict__ mL_cur,
                           int* __restrict__ lg_cur,
                           int* __restrict__ cam, int* __restrict__ cal) {
  int g = blockIdx.x * blockDim.x + threadIdx.x;
  if (g < kE) {
    atomicAdd(&m0_cur[edge_index[kE + g]], 1);
    cam[g] = eattr[2 * g] * 3 + eattr[2 * g + 1];
    return;
  }
  g -= kE;
  if (g < kNLG) { atomicAdd(&mL_cur[lg_map[kNLG + g]], 1); return; }
  g -= kNLG;
  if (g < kNLG) { atomicAdd(&mL_cur[lg_map[g]], 1); return; }
  g -= kNLG;
  if (g < kELG) {
    atomicAdd(&lg_cur[lg_ei[kELG + g]], 1);
    int a = map2[g];
    cal[g] = x[2 * a] * 3 + x[2 * a + 1];
  }
}

__device__ void scan_one(int* cursor, int* offs, int n) {
  __shared__ int part[256];
  int tid = threadIdx.x;
  int chunk = (n + 255) / 256;
  int s0 = tid * chunk;
  int s1 = min(n, s0 + chunk);
  int sum = 0;
  for (int i = s0; i < s1; ++i) sum += cursor[i];
  part[tid] = sum;
  __syncthreads();
  for (int off = 1; off < 256; off <<= 1) {
    int v = (tid >= off) ? part[tid - off] : 0;
    __syncthreads();
    part[tid] += v;
    __syncthreads();
  }
  int run = (tid == 0) ? 0 : part[tid - 1];
  for (int i = s0; i < s1; ++i) {
    int dv = cursor[i];
    offs[i] = run;
    cursor[i] = run;
    run += dv;
  }
  if (tid == 255) offs[n] = run;
}

__global__ __launch_bounds__(256) void k_scan3(
    int* __restrict__ m0_cur, int* __restrict__ m0_offs,
    int* __restrict__ mL_cur, int* __restrict__ mL_offs,
    int* __restrict__ lg_cur, int* __restrict__ lg_offs) {
  if (blockIdx.x == 0) scan_one(m0_cur, m0_offs, kN);
  else if (blockIdx.x == 1) scan_one(mL_cur, mL_offs, kN);
  else scan_one(lg_cur, lg_offs, kNLG);
}

__global__ void k_fill_all(const int* __restrict__ edge_index,
                           const int* __restrict__ lg_map,
                           const int* __restrict__ lg_ei,
                           int* __restrict__ m0_cur, int* __restrict__ m0_perm,
                           int* __restrict__ mL_cur, int* __restrict__ mL_perm,
                           int* __restrict__ lg_cur, int* __restrict__ lg_perm) {
  int g = blockIdx.x * blockDim.x + threadIdx.x;
  if (g < kE) {
    int pos = atomicAdd(&m0_cur[edge_index[kE + g]], 1);
    m0_perm[pos] = g;
    return;
  }
  g -= kE;
  if (g < kNLG) {
    int pos = atomicAdd(&mL_cur[lg_map[kNLG + g]], 1);
    mL_perm[pos] = g;
    return;
  }
  g -= kNLG;
  if (g < kNLG) {
    int pos = atomicAdd(&mL_cur[lg_map[g]], 1);
    mL_perm[pos] = kNLG + g;
    return;
  }
  g -= kNLG;
  if (g < kELG) {
    int pos = atomicAdd(&lg_cur[lg_ei[kELG + g]], 1);
    lg_perm[pos] = g;
  }
}

// ---------------- merged precompute ----------------

__device__ void cvt_w1(const float* W, short* Wt, int g) {
  int per = N1P * K1P;
  int l = g / per, rem = g - l * per;
  int n = rem / K1P, k = rem - n * K1P;
  float v = (n < 2 * D && k < D) ? W[(size_t)l * D * 2 * D + (size_t)k * 2 * D + n] : 0.f;
  Wt[g] = f2h(v);
}

__device__ void cvt_w2(const float* W, short* Wt, int g) {
  int per = N2P * K2P;
  int l = g / per, rem = g - l * per;
  int n = rem / K2P, k = rem - n * K2P;
  float v = (n < D && k < 2 * D) ? W[(size_t)l * 2 * D * D + (size_t)k * D + n] : 0.f;
  Wt[g] = f2h(v);
}

__global__ void k_precomp(const float* __restrict__ g1, const float* __restrict__ g2,
                          const float* __restrict__ l1, const float* __restrict__ l2,
                          const float* __restrict__ g_w1, const float* __restrict__ g_w2,
                          const float* __restrict__ lg_w1, const float* __restrict__ lg_w2,
                          float* __restrict__ slv, short* __restrict__ tcm,
                          short* __restrict__ tcl,
                          short* __restrict__ g_w1t, short* __restrict__ g_w2t,
                          short* __restrict__ lg_w1t, short* __restrict__ lg_w2t) {
  int g = blockIdx.x * blockDim.x + threadIdx.x;
  const int s1 = kL * N1P * K1P, s2 = kL * N2P * K2P;
  if (g < s1) { cvt_w1(g_w1, g_w1t, g); return; }
  g -= s1;
  if (g < s2) { cvt_w2(g_w2, g_w2t, g); return; }
  g -= s2;
  if (g < s1) { cvt_w1(lg_w1, lg_w1t, g); return; }
  g -= s1;
  if (g < s2) { cvt_w2(lg_w2, lg_w2t, g); return; }
  g -= s2;
  if (g < kL * 640) {
    int l = g / 640, rem = g - l * 640;
    int gr = rem / 320, c = rem - gr * 320;
    float v = 0.f;
    if (c < D) {
      if (gr == 0) v = g1[(size_t)l * 6 * D + 4 * D + c] + g2[(size_t)l * 3 * D + c];
      else         v = l1[(size_t)l * 120 * D + 119 * D + c] + l2[(size_t)l * 3 * D + c];
    }
    slv[g] = v;
    return;
  }
  g -= kL * 640;
  if (g < 18 * RH) {
    int p = g / RH, c = g - p * RH;
    float v = (c < D) ? g1[(size_t)(p / 3) * D + c] + g2[(size_t)(p % 3) * D + c] : 0.f;
    tcm[g] = f2h(v);
    return;
  }
  g -= 18 * RH;
  if (g < 360 * RH) {
    int p = g / RH, c = g - p * RH;
    float v = (c < D) ? l1[(size_t)(p / 3) * D + c] + l2[(size_t)(p % 3) * D + c] : 0.f;
    tcl[g] = f2h(v);
  }
}

// ---------------- embed ----------------

__global__ void k_embed_all(const int* __restrict__ x, const int* __restrict__ lg_x,
                            const float* __restrict__ t1m, const float* __restrict__ t2m,
                            const float* __restrict__ t1l, const float* __restrict__ t2l,
                            float* __restrict__ outF, uint4* __restrict__ hist) {
  int g = blockIdx.x * blockDim.x + threadIdx.x;
  if (g >= NALL * RQ) return;
  int r = g / RQ, q = g - r * RQ;
  bool m = r < kN;
  int i = m ? r : r - kN;
  const int* ix = (m ? x : lg_x) + 2 * i;
  const float* t1 = (m ? t1m : t1l) + (size_t)ix[0] * D;
  const float* t2 = (m ? t2m : t2l) + (size_t)ix[1] * D;
  int c0 = q * 8;
  float y[8] = {0.f, 0.f, 0.f, 0.f, 0.f, 0.f, 0.f, 0.f};
  if (c0 < D) {
    float4 p0 = *(const float4*)(t1 + c0);
    float4 q0 = *(const float4*)(t2 + c0);
    y[0] = p0.x + q0.x; y[1] = p0.y + q0.y; y[2] = p0.z + q0.z; y[3] = p0.w + q0.w;
    *(float4*)(outF + (size_t)r * D + c0) = make_float4(y[0], y[1], y[2], y[3]);
    if (c0 + 8 <= D) {
      float4 p1 = *(const float4*)(t1 + c0 + 4);
      float4 q1 = *(const float4*)(t2 + c0 + 4);
      y[4] = p1.x + q1.x; y[5] = p1.y + q1.y; y[6] = p1.z + q1.z; y[7] = p1.w + q1.w;
      *(float4*)(outF + (size_t)r * D + c0 + 4) = make_float4(y[4], y[5], y[6], y[7]);
    }
  }
  hist[(size_t)r * RQ + q] = pk4(y);
}

// ---------------- gather, layer 0 (reads embed fp16 history) ----------------

__global__ __launch_bounds__(64) void k_gather_all0(
    const uint4* __restrict__ h16, const uint4* __restrict__ e16,
    const int* __restrict__ m_src, const int* __restrict__ lg_src,
    const int* __restrict__ cam, const int* __restrict__ cal,
    const uint4* __restrict__ tcm, const uint4* __restrict__ tcl,
    const float* __restrict__ slvM, const float* __restrict__ slvL,
    const int* __restrict__ m_offs, const int* __restrict__ m_perm,
    const int* __restrict__ l_offs, const int* __restrict__ l_perm,
    uint4* __restrict__ ab) {
  int node = blockIdx.x;
  int lane = threadIdx.x;
  bool act = lane < RQ;
  int ll = act ? lane : 0;
  bool isM = node < kN;
  int j = isM ? node : node - kN;
  const uint4* selfrow = isM ? (h16 + (size_t)node * RQ) : (e16 + (size_t)j * RQ);
  const float* sv = (isM ? slvM : slvL) + ll * 8;
  const int* offs = isM ? m_offs : l_offs;
  const int* permp = isM ? m_perm : l_perm;
  const uint4* bA = isM ? h16 : e16;
  const uint4* bB = isM ? tcm : tcl;
  const int* srcp = isM ? m_src : lg_src;
  const int* catp = isM ? cam : cal;

  float acc[8];
  {
    float vv[8];
    unpk8(selfrow[ll], vv);
#pragma unroll
    for (int i = 0; i < 8; ++i) acc[i] = vv[i] + sv[i];
  }

  int p0 = offs[j], p1 = offs[j + 1];
  for (int pb = p0; pb < p1; pb += 64) {
    int cnt = min(64, p1 - pb);
    int e_ = permp[pb + ((lane < cnt) ? lane : 0)];
    int ra = srcp[e_], rb = catp[e_];
    int t = 0;
    for (; t + 3 < cnt; t += 4) {
      int a0 = __shfl(ra, t),     b0 = __shfl(rb, t);
      int a1 = __shfl(ra, t + 1), b1 = __shfl(rb, t + 1);
      int a2 = __shfl(ra, t + 2), b2 = __shfl(rb, t + 2);
      int a3 = __shfl(ra, t + 3), b3 = __shfl(rb, t + 3);
      uint4 x0 = bA[(size_t)a0 * RQ + ll];
      uint4 y0 = bB[(size_t)b0 * RQ + ll];
      uint4 x1 = bA[(size_t)a1 * RQ + ll];
      uint4 y1 = bB[(size_t)b1 * RQ + ll];
      uint4 x2 = bA[(size_t)a2 * RQ + ll];
      uint4 y2 = bB[(size_t)b2 * RQ + ll];
      uint4 x3 = bA[(size_t)a3 * RQ + ll];
      uint4 y3 = bB[(size_t)b3 * RQ + ll];
      addrow(acc, x0); addrow(acc, y0);
      addrow(acc, x1); addrow(acc, y1);
      addrow(acc, x2); addrow(acc, y2);
      addrow(acc, x3); addrow(acc, y3);
    }
    for (; t < cnt; ++t) {
      int a0 = __shfl(ra, t), b0 = __shfl(rb, t);
      uint4 x0 = bA[(size_t)a0 * RQ + ll];
      uint4 y0 = bB[(size_t)b0 * RQ + ll];
      addrow(acc, x0); addrow(acc, y0);
    }
  }
  if (act) ab[(size_t)(isM ? node : MP_N + j) * RQ + ll] = pk4(acc);
}

// ---------------- gather + fused BN (layers 1..4) ----------------
// Reads raw fp16 preact of layer l-1 + coef table; applies relu(a*v+b) per row;
// writes this layer's fp32 d_out self-row + fp16 GEMM-A row.

__global__ __launch_bounds__(64) void k_gather_bnL(
    const uint4* __restrict__ pre, const float* __restrict__ coef,
    const int* __restrict__ lg_map, const int* __restrict__ lg_src,
    const int* __restrict__ map2,
    const float* __restrict__ slvM, const float* __restrict__ slvL,
    const int* __restrict__ m_offs, const int* __restrict__ m_perm,
    const int* __restrict__ l_offs, const int* __restrict__ l_perm,
    float* __restrict__ outF, uint4* __restrict__ ab) {
  int node = blockIdx.x;
  int lane = threadIdx.x;
  bool act = lane < RQ;
  int ll = act ? lane : 0;
  bool isM = node < kN;
  int j = isM ? node : node - kN;

  // BN affine coefs for this lane's 8 columns, both regions (8 x float4 loads)
  float aM[8], bM[8], aL[8], bL[8];
  {
    float4 t;
    t = *(const float4*)(coef + ll * 8);            aM[0]=t.x; aM[1]=t.y; aM[2]=t.z; aM[3]=t.w;
    t = *(const float4*)(coef + ll * 8 + 4);        aM[4]=t.x; aM[5]=t.y; aM[6]=t.z; aM[7]=t.w;
    t = *(const float4*)(coef + 320 + ll * 8);      bM[0]=t.x; bM[1]=t.y; bM[2]=t.z; bM[3]=t.w;
    t = *(const float4*)(coef + 320 + ll * 8 + 4);  bM[4]=t.x; bM[5]=t.y; bM[6]=t.z; bM[7]=t.w;
    t = *(const float4*)(coef + 640 + ll * 8);      aL[0]=t.x; aL[1]=t.y; aL[2]=t.z; aL[3]=t.w;
    t = *(const float4*)(coef + 640 + ll * 8 + 4);  aL[4]=t.x; aL[5]=t.y; aL[6]=t.z; aL[7]=t.w;
    t = *(const float4*)(coef + 960 + ll * 8);      bL[0]=t.x; bL[1]=t.y; bL[2]=t.z; bL[3]=t.w;
    t = *(const float4*)(coef + 960 + ll * 8 + 4);  bL[4]=t.x; bL[5]=t.y; bL[6]=t.z; bL[7]=t.w;
  }

  const float* sv = (isM ? slvM : slvL) + ll * 8;
  const int* offs = isM ? m_offs : l_offs;
  const int* permp = isM ? m_perm : l_perm;

  float acc[8];
  {
    int selfIdx = isM ? node : MP_N + j;
    float vv[8], y[8];
    unpk8(pre[(size_t)selfIdx * RQ + ll], vv);
#pragma unroll
    for (int i = 0; i < 8; ++i) {
      float a = isM ? aM[i] : aL[i];
      float b = isM ? bM[i] : bL[i];
      y[i] = fmaxf(a * vv[i] + b, 0.f);
      acc[i] = y[i] + sv[i];
    }
    if (act) {
      float* op = outF + (size_t)node * D + ll * 8;  // rows are 1200B -> 16B aligned
      if (ll < 37) {
        *(float4*)op = make_float4(y[0], y[1], y[2], y[3]);
        *(float4*)(op + 4) = make_float4(y[4], y[5], y[6], y[7]);
      } else if (ll == 37) {
        *(float4*)op = make_float4(y[0], y[1], y[2], y[3]);  // cols 296..299
      }
    }
  }

  int p0 = offs[j], p1 = offs[j + 1];
  for (int pb = p0; pb < p1; pb += 64) {
    int cnt = min(64, p1 - pb);
    int e_ = permp[pb + ((lane < cnt) ? lane : 0)];
    int rh, re;  // main-region row, lg-region row (unified pre16 indices)
    if (isM) {
      rh = lg_map[e_];
      re = MP_N + ((e_ < kNLG) ? e_ : e_ - kNLG);
    } else {
      rh = map2[e_];
      re = MP_N + lg_src[e_];
    }
    int t = 0;
    for (; t + 1 < cnt; t += 2) {
      int h0 = __shfl(rh, t),     e0 = __shfl(re, t);
      int h1 = __shfl(rh, t + 1), e1 = __shfl(re, t + 1);
      uint4 xh0 = pre[(size_t)h0 * RQ + ll];
      uint4 xe0 = pre[(size_t)e0 * RQ + ll];
      uint4 xh1 = pre[(size_t)h1 * RQ + ll];
      uint4 xe1 = pre[(size_t)e1 * RQ + ll];
      float v[8];
      unpk8(xh0, v);
#pragma unroll
      for (int i = 0; i < 8; ++i) acc[i] += fmaxf(aM[i] * v[i] + bM[i], 0.f);
      unpk8(xe0, v);
#pragma unroll
      for (int i = 0; i < 8; ++i) acc[i] += fmaxf(aL[i] * v[i] + bL[i], 0.f);
      unpk8(xh1, v);
#pragma unroll
      for (int i = 0; i < 8; ++i) acc[i] += fmaxf(aM[i] * v[i] + bM[i], 0.f);
      unpk8(xe1, v);
#pragma unroll
      for (int i = 0; i < 8; ++i) acc[i] += fmaxf(aL[i] * v[i] + bL[i], 0.f);
    }
    if (t < cnt) {
      int h0 = __shfl(rh, t), e0 = __shfl(re, t);
      uint4 xh0 = pre[(size_t)h0 * RQ + ll];
      uint4 xe0 = pre[(size_t)e0 * RQ + ll];
      float v[8];
      unpk8(xh0, v);
#pragma unroll
      for (int i = 0; i < 8; ++i) acc[i] += fmaxf(aM[i] * v[i] + bM[i], 0.f);
      unpk8(xe0, v);
#pragma unroll
      for (int i = 0; i < 8; ++i) acc[i] += fmaxf(aL[i] * v[i] + bL[i], 0.f);
    }
  }
  if (act) ab[(size_t)(isM ? node : MP_N + j) * RQ + ll] = pk4(acc);
}

// ---------------- dual MFMA GEMM (round-13 proven config) ----------------

template<bool RELU, bool STATS>
__global__ __launch_bounds__(256) void k_mfma_gemm_dual(
    const short* __restrict__ A,
    const short* __restrict__ BtM, const short* __restrict__ BtL,
    const float* __restrict__ biasM, const float* __restrict__ biasL, int biasN,
    short* __restrict__ Cout, int Cstat, int Cwrite, int Cstride,
    int Astride, int Kloop, int NC,
    int mainLimit, int lgLimit,
    float* __restrict__ statsM, float* __restrict__ statsL) {
  __shared__ __align__(16) short ldsA[2][128 * 32];
  __shared__ __align__(16) short ldsB[2][128 * 32];
  __shared__ float sd[256];

  int bid = blockIdx.x;
  int xcd = bid & 7;
  int t0 = bid >> 3;
  int c = t0 % NC;
  int rr = t0 / NC;
  int rtile = rr * 8 + xcd;
  if (rtile >= NRT) return;

  const int tid = threadIdx.x;
  const int lane = tid & 63, w = tid >> 6;
  const bool isMain = rtile < MAIN_TILES;
  const short* Bt = isMain ? BtM : BtL;
  const float* bias = isMain ? biasM : biasL;
  const int rowLimit = isMain ? mainLimit : lgLimit;
  const int brow = rtile * 128;
  const int bcol = c * 128;
  const int wr = w >> 1, wc = w & 1;

  if (STATS) sd[tid] = 0.f;

  f32x4 acc[4][4] = {};

  const int sr = tid >> 2;
  const int sc = (tid & 3) * 8;

  auto stage = [&](int buf, int k0) {
    char* la = (char*)(&ldsA[buf][0]) + w * 1024;
    char* lb = (char*)(&ldsB[buf][0]) + w * 1024;
    const short* gA0 = A + (size_t)(brow + sr) * Astride + (k0 + sc);
    const short* gB0 = Bt + (size_t)(bcol + sr) * Astride + (k0 + sc);
    gload_lds16(gA0, la);
    gload_lds16(gA0 + (size_t)64 * Astride, la + 4096);
    gload_lds16(gB0, lb);
    gload_lds16(gB0 + (size_t)64 * Astride, lb + 4096);
  };

  const int nt = Kloop / 32;
  stage(0, 0);
  __syncthreads();

  for (int t = 0; t < nt; ++t) {
    int cb = t & 1;
    if (t + 1 < nt) stage(cb ^ 1, (t + 1) * 32);

    const int kq = (lane >> 4) * 16;
    const char* baseA = (const char*)(&ldsA[cb][0]);
    const char* baseB = (const char*)(&ldsB[cb][0]);
    half8 af[4], bf[4];
#pragma unroll
    for (int m = 0; m < 4; ++m) {
      int row = wr * 64 + m * 16 + (lane & 15);
      af[m] = *(const half8*)(baseA + row * 64 + kq);
    }
#pragma unroll
    for (int n = 0; n < 4; ++n) {
      int col = wc * 64 + n * 16 + (lane & 15);
      bf[n] = *(const half8*)(baseB + col * 64 + kq);
    }
#pragma unroll
    for (int m = 0; m < 4; ++m)
#pragma unroll
      for (int n = 0; n < 4; ++n)
        acc[m][n] = __builtin_amdgcn_mfma_f32_16x16x32_f16(af[m], bf[n], acc[m][n], 0, 0, 0);
    __syncthreads();
  }

  const int r0 = brow + wr * 64;
  const int c0 = bcol + wc * 64;
  float ps[4] = {}, pq[4] = {};
#pragma unroll
  for (int m = 0; m < 4; ++m) {
#pragma unroll
    for (int i = 0; i < 4; ++i) {
      int row = r0 + m * 16 + (lane >> 4) * 4 + i;
      bool rv = row < rowLimit;
#pragma unroll
      for (int n = 0; n < 4; ++n) {
        int col = c0 + n * 16 + (lane & 15);
        float bv = (col < biasN) ? bias[col] : 0.f;
        float v = acc[m][n][i] + bv;
        if (RELU) v = fmaxf(v, 0.f);
        if (rv && col < Cwrite) {
          Cout[(size_t)row * Cstride + col] = f2h(v);
          if (STATS && col < Cstat) { ps[n] += v; pq[n] += v * v; }
        }
      }
    }
  }

  if (STATS) {
#pragma unroll
    for (int n = 0; n < 4; ++n) {
      float s = ps[n], q = pq[n];
      s += __shfl_xor(s, 16); q += __shfl_xor(q, 16);
      s += __shfl_xor(s, 32); q += __shfl_xor(q, 32);
      if ((lane >> 4) == 0) {
        int cc = wc * 64 + n * 16 + (lane & 15);
        atomicAdd(&sd[cc], s);
        atomicAdd(&sd[128 + cc], q);
      }
    }
    __syncthreads();
    float* gs = isMain ? statsM : statsL;
    if (tid < 128) {
      int col = bcol + tid;
      if (col < Cstat) {
        atomicAdd(&gs[col], sd[tid]);
        atomicAdd(&gs[D + col], sd[128 + tid]);
      }
    }
  }
}

// ---------------- BN coef precompute ----------------

__global__ void k_bn_coef(const float* __restrict__ stats,
                          const float* __restrict__ gM, const float* __restrict__ bM,
                          const float* __restrict__ gL, const float* __restrict__ bL,
                          float* __restrict__ coef) {
  int t = blockIdx.x * blockDim.x + threadIdx.x;
  if (t >= 640) return;
  bool m = t < 320;
  int c = m ? t : t - 320;
  float a = 0.f, b = 0.f;
  if (c < D) {
    const float* s = stats + (m ? 0 : 600);
    float inv_n = m ? (1.f / kN) : (1.f / kNLG);
    float mu = s[c] * inv_n;
    float var = s[D + c] * inv_n - mu * mu;
    a = rsqrtf(var + 1e-5f) * (m ? gM : gL)[c];
    b = (m ? bM : bL)[c] - mu * a;
  }
  int base = m ? 0 : 640;
  coef[base + c] = a;
  coef[base + 320 + c] = b;
}

// ---------------- final-layer BN apply (no relu, no hist) ----------------

__global__ void k_bn_final(const uint4* __restrict__ pre, const float* __restrict__ coef,
                           float* __restrict__ outF) {
  int g = blockIdx.x * blockDim.x + threadIdx.x;
  if (g >= NALL * RQ) return;
  int r = g / RQ, q = g - r * RQ;
  bool m = r < kN;
  int pr = m ? r : MP_N + (r - kN);
  float v[8], y[8];
  unpk8(pre[(size_t)pr * RQ + q], v);
  const float* cb = coef + (m ? 0 : 640);
  float4 a0 = *(const float4*)(cb + q * 8);
  float4 a1 = *(const float4*)(cb + q * 8 + 4);
  float4 b0 = *(const float4*)(cb + 320 + q * 8);
  float4 b1 = *(const float4*)(cb + 320 + q * 8 + 4);
  y[0] = a0.x * v[0] + b0.x; y[1] = a0.y * v[1] + b0.y;
  y[2] = a0.z * v[2] + b0.z; y[3] = a0.w * v[3] + b0.w;
  y[4] = a1.x * v[4] + b1.x; y[5] = a1.y * v[5] + b1.y;
  y[6] = a1.z * v[6] + b1.z; y[7] = a1.w * v[7] + b1.w;
  float* op = outF + (size_t)r * D + q * 8;
  if (q < 37) {
    *(float4*)op = make_float4(y[0], y[1], y[2], y[3]);
    *(float4*)(op + 4) = make_float4(y[4], y[5], y[6], y[7]);
  } else if (q == 37) {
    *(float4*)op = make_float4(y[0], y[1], y[2], y[3]);
  }
}

}  // namespace

extern "C" void kernel_launch(void* const* d_in, const int* in_sizes, int n_in,
                              void* d_out_v, int out_size, void* d_ws, size_t ws_size,
                              hipStream_t stream) {
  const int*   x            = (const int*)d_in[0];
  const int*   edge_index   = (const int*)d_in[1];
  const int*   edge_attr    = (const int*)d_in[2];
  const int*   lg_x         = (const int*)d_in[3];
  const int*   lg_edge_index= (const int*)d_in[4];
  const int*   lg_map       = (const int*)d_in[5];
  const int*   lg_map2      = (const int*)d_in[6];
  const float* node_emb1    = (const float*)d_in[7];
  const float* node_emb2    = (const float*)d_in[8];
  const float* gnn_e_emb1   = (const float*)d_in[9];
  const float* gnn_e_emb2   = (const float*)d_in[10];
  const float* g_emb1       = (const float*)d_in[11];
  const float* g_emb2       = (const float*)d_in[12];
  const float* g_w1         = (const float*)d_in[13];
  const float* g_b1         = (const float*)d_in[14];
  const float* g_w2         = (const float*)d_in[15];
  const float* g_b2         = (const float*)d_in[16];
  const float* g_gamma      = (const float*)d_in[17];
  const float* g_beta       = (const float*)d_in[18];
  const float* lg_emb1      = (const float*)d_in[19];
  const float* lg_emb2      = (const float*)d_in[20];
  const float* lg_w1        = (const float*)d_in[21];
  const float* lg_b1        = (const float*)d_in[22];
  const float* lg_w2        = (const float*)d_in[23];
  const float* lg_b2        = (const float*)d_in[24];
  const float* lg_gamma     = (const float*)d_in[25];
  const float* lg_beta      = (const float*)d_in[26];

  float* out = (float*)d_out_v;
  char*  ws  = (char*)d_ws;

  size_t off = 0;
  auto alloc = [&](size_t bytes) { void* p = ws + off; off = (off + bytes + 255) & ~(size_t)255; return p; };
  short* ab      = (short*)alloc((size_t)MP_ALL * K1P * 2);           // 38.5 MB
  short* hidden  = (short*)alloc((size_t)MP_ALL * N1P * 2);           // 77 MB
  short* pre2    = (short*)alloc((size_t)2 * MP_ALL * PQH * 2);       // 77 MB ping-pong
  short* hist    = (short*)alloc((size_t)NALL * RH * 2);              // 38.4 MB (layer 0)
  short* g_w1t   = (short*)alloc((size_t)kL * N1P * K1P * 2);
  short* g_w2t   = (short*)alloc((size_t)kL * N2P * K2P * 2);
  short* lg_w1t  = (short*)alloc((size_t)kL * N1P * K1P * 2);
  short* lg_w2t  = (short*)alloc((size_t)kL * N2P * K2P * 2);
  float* stats   = (float*)alloc((kL * 1200 + 64) * 4);
  float* slv     = (float*)alloc(kL * 640 * 4);
  float* coef    = (float*)alloc(1280 * 4);
  short* tcm     = (short*)alloc(18 * RH * 2);
  short* tcl     = (short*)alloc(360 * RH * 2);
  int* cam     = (int*)alloc(kE * 4);
  int* cal     = (int*)alloc(kELG * 4);
  int* m0_offs = (int*)alloc((kN + 1) * 4);
  int* m0_cur  = (int*)alloc(kN * 4);
  int* m0_perm = (int*)alloc(kE * 4);
  int* mL_offs = (int*)alloc((kN + 1) * 4);
  int* mL_cur  = (int*)alloc(kN * 4);
  int* mL_perm = (int*)alloc(2 * kNLG * 4);
  int* lg_offs = (int*)alloc((kNLG + 1) * 4);
  int* lg_cur  = (int*)alloc(kNLG * 4);
  int* lg_perm = (int*)alloc(kELG * 4);

  auto hptr = [&](int l) { return out + (size_t)l * 60000 * D; };
  auto prep = [&](int s) { return pre2 + (size_t)s * MP_ALL * PQH; };

  dim3 b(256);

  // ---- prologue (6 dispatches) ----
  k_init<<<(kNLG + 255) / 256, b, 0, stream>>>(stats, ab, m0_cur, mL_cur, lg_cur);
  {
    int tot = kE + 2 * kNLG + kELG;
    k_hist_all<<<(tot + 255) / 256, b, 0, stream>>>(edge_index, lg_map, lg_edge_index,
                                                    edge_attr, lg_map2, x,
                                                    m0_cur, mL_cur, lg_cur, cam, cal);
    k_scan3<<<3, b, 0, stream>>>(m0_cur, m0_offs, mL_cur, mL_offs, lg_cur, lg_offs);
    k_fill_all<<<(tot + 255) / 256, b, 0, stream>>>(edge_index, lg_map, lg_edge_index,
                                                    m0_cur, m0_perm, mL_cur, mL_perm,
                                                    lg_cur, lg_perm);
  }
  {
    int tot = 2 * kL * (N1P * K1P + N2P * K2P) + kL * 640 + 378 * RH;
    k_precomp<<<(tot + 255) / 256, b, 0, stream>>>(g_emb1, g_emb2, lg_emb1, lg_emb2,
                                                   g_w1, g_w2, lg_w1, lg_w2,
                                                   slv, tcm, tcl,
                                                   g_w1t, g_w2t, lg_w1t, lg_w2t);
  }
  k_embed_all<<<(NALL * RQ + 255) / 256, b, 0, stream>>>(x, lg_x, node_emb1, node_emb2,
                                                         gnn_e_emb1, gnn_e_emb2,
                                                         hptr(0), (uint4*)hist);

  int cur = 0;
  for (int l = 0; l < kL; ++l) {
    float* slot = stats + (size_t)l * 1200;
    const float* slvM = slv + (size_t)l * 640;
    const float* slvL = slvM + 320;

    if (l == 0)
      k_gather_all0<<<NALL, 64, 0, stream>>>(
          (const uint4*)hist, (const uint4*)(hist + (size_t)kN * RH),
          edge_index, lg_edge_index, cam, cal,
          (const uint4*)tcm, (const uint4*)tcl,
          slvM, slvL, m0_offs, m0_perm, lg_offs, lg_perm, (uint4*)ab);
    else
      k_gather_bnL<<<NALL, 64, 0, stream>>>(
          (const uint4*)prep(cur), coef, lg_map, lg_edge_index, lg_map2,
          slvM, slvL, mL_offs, mL_perm, lg_offs, lg_perm,
          hptr(l), (uint4*)ab);

    k_mfma_gemm_dual<true, false><<<8 * NRP * 5, b, 0, stream>>>(
        ab, g_w1t + (size_t)l * N1P * K1P, lg_w1t + (size_t)l * N1P * K1P,
        g_b1 + (size_t)l * 2 * D, lg_b1 + (size_t)l * 2 * D, 2 * D,
        hidden, 0, 608, N1P, K1P, K1P, 5, MP_ALL, MP_ALL, nullptr, nullptr);

    int nxt = cur ^ 1;
    k_mfma_gemm_dual<false, true><<<8 * NRP * 3, b, 0, stream>>>(
        hidden, g_w2t + (size_t)l * N2P * K2P, lg_w2t + (size_t)l * N2P * K2P,
        g_b2 + (size_t)l * D, lg_b2 + (size_t)l * D, D,
        prep(nxt), D, PQH, PQH, K2P, 608, 3, kN, MP_N + kNLG,
        slot, slot + 600);

    k_bn_coef<<<3, b, 0, stream>>>(slot,
                                   g_gamma + (size_t)l * D, g_beta + (size_t)l * D,
                                   lg_gamma + (size_t)l * D, lg_beta + (size_t)l * D, coef);
    cur = nxt;
  }

  // final layer output (h_list[5], e_list[5]) — BN only, no relu
  k_bn_final<<<(NALL * RQ + 255) / 256, b, 0, stream>>>(
      (const uint4*)prep(cur), coef, hptr(kL));
}

// Round 16
// 1321.147 us; speedup vs baseline: 1.1223x; 1.0172x over previous
//
#include <hip/hip_runtime.h>

#define D 300

namespace {

constexpr int kN   = 20000;
constexpr int kNLG = 40000;
constexpr int kE   = 80000;
constexpr int kELG = 200000;
constexpr int kL   = 5;

constexpr int K1P = 320;
constexpr int N1P = 640;
constexpr int K2P = 640;
constexpr int N2P = 384;
constexpr int PQH = 320;
constexpr int MP_N   = 20096;
constexpr int MP_ALL = 60160;
constexpr int MAIN_TILES = 157;
constexpr int NRT = 470;
constexpr int NRP = 59;
constexpr int RH = 320;
constexpr int RQ = 40;
constexpr int NALL = kN + kNLG;
// stats layout per layer: [sumM 320][sumsqM 320][sumL 320][sumsqL 320]
constexpr int STL = 1280;

typedef __attribute__((ext_vector_type(8))) _Float16 half8;
typedef __attribute__((ext_vector_type(2))) _Float16 half2v;
typedef __attribute__((ext_vector_type(4))) float f32x4;

__device__ inline short f2h(float f) {
  _Float16 h = (_Float16)f;
  return __builtin_bit_cast(short, h);
}

__device__ inline float2 upk(unsigned u) {
  half2v h = __builtin_bit_cast(half2v, u);
  return make_float2((float)h.x, (float)h.y);
}

__device__ inline unsigned pk(float a, float b) {
  half2v h;
  h.x = (_Float16)a;
  h.y = (_Float16)b;
  return __builtin_bit_cast(unsigned, h);
}

__device__ inline void addrow(float* acc, uint4 r) {
  float2 t0 = upk(r.x), t1 = upk(r.y), t2 = upk(r.z), t3 = upk(r.w);
  acc[0] += t0.x; acc[1] += t0.y; acc[2] += t1.x; acc[3] += t1.y;
  acc[4] += t2.x; acc[5] += t2.y; acc[6] += t3.x; acc[7] += t3.y;
}

__device__ inline void unpk8(uint4 r, float* v) {
  float2 t0 = upk(r.x), t1 = upk(r.y), t2 = upk(r.z), t3 = upk(r.w);
  v[0] = t0.x; v[1] = t0.y; v[2] = t1.x; v[3] = t1.y;
  v[4] = t2.x; v[5] = t2.y; v[6] = t3.x; v[7] = t3.y;
}

__device__ inline uint4 pk4(const float* a) {
  uint4 r;
  r.x = pk(a[0], a[1]); r.y = pk(a[2], a[3]);
  r.z = pk(a[4], a[5]); r.w = pk(a[6], a[7]);
  return r;
}

__device__ inline void gload_lds16(const void* g, void* l) {
  __builtin_amdgcn_global_load_lds(
      (const __attribute__((address_space(1))) void*)g,
      (__attribute__((address_space(3))) void*)l, 16, 0, 0);
}

// BN coefs for 8 consecutive cols starting at c0=q*8, one stat region.
// sb: [sum 320][sumsq 320]; gb: [gamma 320][beta 320]; pads are zeros -> a=b=0.
__device__ inline void bn_coef8(const float* sb, const float* gb, int q,
                                float inv_n, float* a, float* b) {
  float4 s0 = *(const float4*)(sb + q * 8);
  float4 s1 = *(const float4*)(sb + q * 8 + 4);
  float4 q0 = *(const float4*)(sb + 320 + q * 8);
  float4 q1 = *(const float4*)(sb + 320 + q * 8 + 4);
  float4 g0 = *(const float4*)(gb + q * 8);
  float4 g1 = *(const float4*)(gb + q * 8 + 4);
  float4 e0 = *(const float4*)(gb + 320 + q * 8);
  float4 e1 = *(const float4*)(gb + 320 + q * 8 + 4);
  float su[8] = {s0.x, s0.y, s0.z, s0.w, s1.x, s1.y, s1.z, s1.w};
  float sq[8] = {q0.x, q0.y, q0.z, q0.w, q1.x, q1.y, q1.z, q1.w};
  float ga[8] = {g0.x, g0.y, g0.z, g0.w, g1.x, g1.y, g1.z, g1.w};
  float be[8] = {e0.x, e0.y, e0.z, e0.w, e1.x, e1.y, e1.z, e1.w};
#pragma unroll
  for (int i = 0; i < 8; ++i) {
    float mu = su[i] * inv_n;
    float var = sq[i] * inv_n - mu * mu;
    a[i] = rsqrtf(var + 1e-5f) * ga[i];
    b[i] = be[i] - mu * a[i];
  }
}

// ---------------- init ----------------

__global__ void k_init(float* __restrict__ stats, short* __restrict__ ab,
                       int* __restrict__ m0_cur, int* __restrict__ mL_cur,
                       int* __restrict__ lg_cur) {
  int g = blockIdx.x * blockDim.x + threadIdx.x;
  if (g < kL * STL) stats[g] = 0.f;
  int np1 = (MP_N - kN) * K1P;
  int np2 = (MP_ALL - MP_N - kNLG) * K1P;
  if (g < np1) ab[(size_t)kN * K1P + g] = 0;
  if (g < np2) ab[(size_t)(MP_N + kNLG) * K1P + g] = 0;
  if (g < kN) { m0_cur[g] = 0; mL_cur[g] = 0; }
  if (g < kNLG) lg_cur[g] = 0;
}

// ---------------- CSR build ----------------

__global__ void k_hist_all(const int* __restrict__ edge_index,
                           const int* __restrict__ lg_map,
                           const int* __restrict__ lg_ei,
                           int* __restrict__ m0_cur, int* __restrict__ mL_cur,
                           int* __restrict__ lg_cur) {
  int g = blockIdx.x * blockDim.x + threadIdx.x;
  if (g < kE) { atomicAdd(&m0_cur[edge_index[kE + g]], 1); return; }
  g -= kE;
  if (g < kNLG) { atomicAdd(&mL_cur[lg_map[kNLG + g]], 1); return; }
  g -= kNLG;
  if (g < kNLG) { atomicAdd(&mL_cur[lg_map[g]], 1); return; }
  g -= kNLG;
  if (g < kELG) atomicAdd(&lg_cur[lg_ei[kELG + g]], 1);
}

__device__ void scan_one(int* cursor, int* offs, int n) {
  __shared__ int part[256];
  int tid = threadIdx.x;
  int chunk = (n + 255) / 256;
  int s0 = tid * chunk;
  int s1 = min(n, s0 + chunk);
  int sum = 0;
  for (int i = s0; i < s1; ++i) sum += cursor[i];
  part[tid] = sum;
  __syncthreads();
  for (int off = 1; off < 256; off <<= 1) {
    int v = (tid >= off) ? part[tid - off] : 0;
    __syncthreads();
    part[tid] += v;
    __syncthreads();
  }
  int run = (tid == 0) ? 0 : part[tid - 1];
  for (int i = s0; i < s1; ++i) {
    int dv = cursor[i];
    offs[i] = run;
    cursor[i] = run;
    run += dv;
  }
  if (tid == 255) offs[n] = run;
}

__global__ __launch_bounds__(256) void k_scan3(
    int* __restrict__ m0_cur, int* __restrict__ m0_offs,
    int* __restrict__ mL_cur, int* __restrict__ mL_offs,
    int* __restrict__ lg_cur, int* __restrict__ lg_offs) {
  if (blockIdx.x == 0) scan_one(m0_cur, m0_offs, kN);
  else if (blockIdx.x == 1) scan_one(mL_cur, mL_offs, kN);
  else scan_one(lg_cur, lg_offs, kNLG);
}

// fill CSR with final per-slot row pairs (no indirection left in gathers)
__global__ void k_fill_all(const int* __restrict__ edge_index,
                           const int* __restrict__ lg_map,
                           const int* __restrict__ lg_ei,
                           const int* __restrict__ eattr,
                           const int* __restrict__ map2,
                           const int* __restrict__ x,
                           int* __restrict__ m0_cur, int2* __restrict__ r0m,
                           int* __restrict__ mL_cur, int2* __restrict__ rLm,
                           int* __restrict__ lg_cur, int2* __restrict__ r0l,
                           int2* __restrict__ rLl) {
  int g = blockIdx.x * blockDim.x + threadIdx.x;
  if (g < kE) {
    int pos = atomicAdd(&m0_cur[edge_index[kE + g]], 1);
    r0m[pos] = make_int2(edge_index[g], eattr[2 * g] * 3 + eattr[2 * g + 1]);
    return;
  }
  g -= kE;
  if (g < kNLG) {
    int pos = atomicAdd(&mL_cur[lg_map[kNLG + g]], 1);
    rLm[pos] = make_int2(lg_map[g], MP_N + g);
    return;
  }
  g -= kNLG;
  if (g < kNLG) {
    int pos = atomicAdd(&mL_cur[lg_map[g]], 1);
    rLm[pos] = make_int2(lg_map[kNLG + g], MP_N + g);
    return;
  }
  g -= kNLG;
  if (g < kELG) {
    int pos = atomicAdd(&lg_cur[lg_ei[kELG + g]], 1);
    int a = map2[g];
    r0l[pos] = make_int2(lg_ei[g], x[2 * a] * 3 + x[2 * a + 1]);
    rLl[pos] = make_int2(a, MP_N + lg_ei[g]);
  }
}

// ---------------- merged precompute ----------------

__device__ void cvt_w1(const float* W, short* Wt, int g) {
  int per = N1P * K1P;
  int l = g / per, rem = g - l * per;
  int n = rem / K1P, k = rem - n * K1P;
  float v = (n < 2 * D && k < D) ? W[(size_t)l * D * 2 * D + (size_t)k * 2 * D + n] : 0.f;
  Wt[g] = f2h(v);
}

__device__ void cvt_w2(const float* W, short* Wt, int g) {
  int per = N2P * K2P;
  int l = g / per, rem = g - l * per;
  int n = rem / K2P, k = rem - n * K2P;
  float v = (n < D && k < 2 * D) ? W[(size_t)l * 2 * D * D + (size_t)k * D + n] : 0.f;
  Wt[g] = f2h(v);
}

__global__ void k_precomp(const float* __restrict__ g1, const float* __restrict__ g2,
                          const float* __restrict__ l1, const float* __restrict__ l2,
                          const float* __restrict__ g_w1, const float* __restrict__ g_w2,
                          const float* __restrict__ lg_w1, const float* __restrict__ lg_w2,
                          const float* __restrict__ g_gamma, const float* __restrict__ g_beta,
                          const float* __restrict__ lg_gamma, const float* __restrict__ lg_beta,
                          float* __restrict__ slv, short* __restrict__ tcm,
                          short* __restrict__ tcl, float* __restrict__ gbp,
                          short* __restrict__ g_w1t, short* __restrict__ g_w2t,
                          short* __restrict__ lg_w1t, short* __restrict__ lg_w2t) {
  int g = blockIdx.x * blockDim.x + threadIdx.x;
  const int s1 = kL * N1P * K1P, s2 = kL * N2P * K2P;
  if (g < s1) { cvt_w1(g_w1, g_w1t, g); return; }
  g -= s1;
  if (g < s2) { cvt_w2(g_w2, g_w2t, g); return; }
  g -= s2;
  if (g < s1) { cvt_w1(lg_w1, lg_w1t, g); return; }
  g -= s1;
  if (g < s2) { cvt_w2(lg_w2, lg_w2t, g); return; }
  g -= s2;
  if (g < kL * 640) {
    int l = g / 640, rem = g - l * 640;
    int gr = rem / 320, c = rem - gr * 320;
    float v = 0.f;
    if (c < D) {
      if (gr == 0) v = g1[(size_t)l * 6 * D + 4 * D + c] + g2[(size_t)l * 3 * D + c];
      else         v = l1[(size_t)l * 120 * D + 119 * D + c] + l2[(size_t)l * 3 * D + c];
    }
    slv[g] = v;
    return;
  }
  g -= kL * 640;
  if (g < 18 * RH) {
    int p = g / RH, c = g - p * RH;
    float v = (c < D) ? g1[(size_t)(p / 3) * D + c] + g2[(size_t)(p % 3) * D + c] : 0.f;
    tcm[g] = f2h(v);
    return;
  }
  g -= 18 * RH;
  if (g < 360 * RH) {
    int p = g / RH, c = g - p * RH;
    float v = (c < D) ? l1[(size_t)(p / 3) * D + c] + l2[(size_t)(p % 3) * D + c] : 0.f;
    tcl[g] = f2h(v);
    return;
  }
  g -= 360 * RH;
  if (g < kL * STL) {  // padded gamma/beta: per layer [gM 320][bM 320][gL 320][bL 320]
    int l = g / STL, rem = g - l * STL;
    int seg = rem / 320, c = rem - seg * 320;
    float v = 0.f;
    if (c < D) {
      const float* src = (seg == 0) ? g_gamma : (seg == 1) ? g_beta
                       : (seg == 2) ? lg_gamma : lg_beta;
      v = src[(size_t)l * D + c];
    }
    gbp[g] = v;
  }
}

// ---------------- embed ----------------

__global__ void k_embed_all(const int* __restrict__ x, const int* __restrict__ lg_x,
                            const float* __restrict__ t1m, const float* __restrict__ t2m,
                            const float* __restrict__ t1l, const float* __restrict__ t2l,
                            float* __restrict__ outF, uint4* __restrict__ hist) {
  int g = blockIdx.x * blockDim.x + threadIdx.x;
  if (g >= NALL * RQ) return;
  int r = g / RQ, q = g - r * RQ;
  bool m = r < kN;
  int i = m ? r : r - kN;
  const int* ix = (m ? x : lg_x) + 2 * i;
  const float* t1 = (m ? t1m : t1l) + (size_t)ix[0] * D;
  const float* t2 = (m ? t2m : t2l) + (size_t)ix[1] * D;
  int c0 = q * 8;
  float y[8] = {0.f, 0.f, 0.f, 0.f, 0.f, 0.f, 0.f, 0.f};
  if (c0 < D) {
    float4 p0 = *(const float4*)(t1 + c0);
    float4 q0 = *(const float4*)(t2 + c0);
    y[0] = p0.x + q0.x; y[1] = p0.y + q0.y; y[2] = p0.z + q0.z; y[3] = p0.w + q0.w;
    *(float4*)(outF + (size_t)r * D + c0) = make_float4(y[0], y[1], y[2], y[3]);
    if (c0 + 8 <= D) {
      float4 p1 = *(const float4*)(t1 + c0 + 4);
      float4 q1 = *(const float4*)(t2 + c0 + 4);
      y[4] = p1.x + q1.x; y[5] = p1.y + q1.y; y[6] = p1.z + q1.z; y[7] = p1.w + q1.w;
      *(float4*)(outF + (size_t)r * D + c0 + 4) = make_float4(y[4], y[5], y[6], y[7]);
    }
  }
  hist[(size_t)r * RQ + q] = pk4(y);
}

// ---------------- gather, layer 0 ----------------

__global__ __launch_bounds__(64) void k_gather_all0(
    const uint4* __restrict__ h16, const uint4* __restrict__ e16,
    const int2* __restrict__ r0m, const int2* __restrict__ r0l,
    const uint4* __restrict__ tcm, const uint4* __restrict__ tcl,
    const float* __restrict__ slvM, const float* __restrict__ slvL,
    const int* __restrict__ m_offs, const int* __restrict__ l_offs,
    uint4* __restrict__ ab) {
  int node = blockIdx.x;
  int lane = threadIdx.x;
  bool act = lane < RQ;
  int ll = act ? lane : 0;
  bool isM = node < kN;
  int j = isM ? node : node - kN;
  const uint4* selfrow = isM ? (h16 + (size_t)node * RQ) : (e16 + (size_t)j * RQ);
  const float* sv = (isM ? slvM : slvL) + ll * 8;
  const int* offs = isM ? m_offs : l_offs;
  const int2* rows = isM ? r0m : r0l;
  const uint4* bA = isM ? h16 : e16;
  const uint4* bB = isM ? tcm : tcl;

  float acc[8];
  {
    float vv[8];
    unpk8(selfrow[ll], vv);
#pragma unroll
    for (int i = 0; i < 8; ++i) acc[i] = vv[i] + sv[i];
  }

  int p0 = offs[j], p1 = offs[j + 1];
  for (int pb = p0; pb < p1; pb += 64) {
    int cnt = min(64, p1 - pb);
    int2 rr_ = rows[pb + ((lane < cnt) ? lane : 0)];
    int ra = rr_.x, rb = rr_.y;
    int t = 0;
    for (; t + 3 < cnt; t += 4) {
      int a0 = __shfl(ra, t),     b0 = __shfl(rb, t);
      int a1 = __shfl(ra, t + 1), b1 = __shfl(rb, t + 1);
      int a2 = __shfl(ra, t + 2), b2 = __shfl(rb, t + 2);
      int a3 = __shfl(ra, t + 3), b3 = __shfl(rb, t + 3);
      uint4 x0 = bA[(size_t)a0 * RQ + ll];
      uint4 y0 = bB[(size_t)b0 * RQ + ll];
      uint4 x1 = bA[(size_t)a1 * RQ + ll];
      uint4 y1 = bB[(size_t)b1 * RQ + ll];
      uint4 x2 = bA[(size_t)a2 * RQ + ll];
      uint4 y2 = bB[(size_t)b2 * RQ + ll];
      uint4 x3 = bA[(size_t)a3 * RQ + ll];
      uint4 y3 = bB[(size_t)b3 * RQ + ll];
      addrow(acc, x0); addrow(acc, y0);
      addrow(acc, x1); addrow(acc, y1);
      addrow(acc, x2); addrow(acc, y2);
      addrow(acc, x3); addrow(acc, y3);
    }
    for (; t < cnt; ++t) {
      int a0 = __shfl(ra, t), b0 = __shfl(rb, t);
      uint4 x0 = bA[(size_t)a0 * RQ + ll];
      uint4 y0 = bB[(size_t)b0 * RQ + ll];
      addrow(acc, x0); addrow(acc, y0);
    }
  }
  if (act) ab[(size_t)(isM ? node : MP_N + j) * RQ + ll] = pk4(acc);
}

// ---------------- gather + fused BN (layers 1..4) ----------------
// Row pairs are global pre16 indices; BN coefs computed per-wave from raw stats.

__global__ __launch_bounds__(64) void k_gather_bnL(
    const uint4* __restrict__ pre,
    const float* __restrict__ stp,   // prev-layer stats [1280]
    const float* __restrict__ gbp,   // prev-layer padded gamma/beta [1280]
    const int2* __restrict__ rLm, const int2* __restrict__ rLl,
    const float* __restrict__ slvM, const float* __restrict__ slvL,
    const int* __restrict__ m_offs, const int* __restrict__ l_offs,
    float* __restrict__ outF, uint4* __restrict__ ab) {
  int node = blockIdx.x;
  int lane = threadIdx.x;
  bool act = lane < RQ;
  int ll = act ? lane : 0;
  bool isM = node < kN;
  int j = isM ? node : node - kN;

  float aM[8], bM[8], aL[8], bL[8];
  bn_coef8(stp, gbp, ll, 1.f / kN, aM, bM);
  bn_coef8(stp + 640, gbp + 640, ll, 1.f / kNLG, aL, bL);

  const float* sv = (isM ? slvM : slvL) + ll * 8;
  const int* offs = isM ? m_offs : l_offs;
  const int2* rows = isM ? rLm : rLl;

  float acc[8];
  {
    int selfIdx = isM ? node : MP_N + j;
    float vv[8], y[8];
    unpk8(pre[(size_t)selfIdx * RQ + ll], vv);
#pragma unroll
    for (int i = 0; i < 8; ++i) {
      float a = isM ? aM[i] : aL[i];
      float b = isM ? bM[i] : bL[i];
      y[i] = fmaxf(a * vv[i] + b, 0.f);
      acc[i] = y[i] + sv[i];
    }
    if (act) {
      float* op = outF + (size_t)node * D + ll * 8;
      if (ll < 37) {
        *(float4*)op = make_float4(y[0], y[1], y[2], y[3]);
        *(float4*)(op + 4) = make_float4(y[4], y[5], y[6], y[7]);
      } else if (ll == 37) {
        *(float4*)op = make_float4(y[0], y[1], y[2], y[3]);
      }
    }
  }

  int p0 = offs[j], p1 = offs[j + 1];
  for (int pb = p0; pb < p1; pb += 64) {
    int cnt = min(64, p1 - pb);
    int2 rr_ = rows[pb + ((lane < cnt) ? lane : 0)];
    int rh = rr_.x, re = rr_.y;
    int t = 0;
    for (; t + 1 < cnt; t += 2) {
      int h0 = __shfl(rh, t),     e0 = __shfl(re, t);
      int h1 = __shfl(rh, t + 1), e1 = __shfl(re, t + 1);
      uint4 xh0 = pre[(size_t)h0 * RQ + ll];
      uint4 xe0 = pre[(size_t)e0 * RQ + ll];
      uint4 xh1 = pre[(size_t)h1 * RQ + ll];
      uint4 xe1 = pre[(size_t)e1 * RQ + ll];
      float v[8];
      unpk8(xh0, v);
#pragma unroll
      for (int i = 0; i < 8; ++i) acc[i] += fmaxf(aM[i] * v[i] + bM[i], 0.f);
      unpk8(xe0, v);
#pragma unroll
      for (int i = 0; i < 8; ++i) acc[i] += fmaxf(aL[i] * v[i] + bL[i], 0.f);
      unpk8(xh1, v);
#pragma unroll
      for (int i = 0; i < 8; ++i) acc[i] += fmaxf(aM[i] * v[i] + bM[i], 0.f);
      unpk8(xe1, v);
#pragma unroll
      for (int i = 0; i < 8; ++i) acc[i] += fmaxf(aL[i] * v[i] + bL[i], 0.f);
    }
    if (t < cnt) {
      int h0 = __shfl(rh, t), e0 = __shfl(re, t);
      uint4 xh0 = pre[(size_t)h0 * RQ + ll];
      uint4 xe0 = pre[(size_t)e0 * RQ + ll];
      float v[8];
      unpk8(xh0, v);
#pragma unroll
      for (int i = 0; i < 8; ++i) acc[i] += fmaxf(aM[i] * v[i] + bM[i], 0.f);
      unpk8(xe0, v);
#pragma unroll
      for (int i = 0; i < 8; ++i) acc[i] += fmaxf(aL[i] * v[i] + bL[i], 0.f);
    }
  }
  if (act) ab[(size_t)(isM ? node : MP_N + j) * RQ + ll] = pk4(acc);
}

// ---------------- dual MFMA GEMM ----------------

template<bool RELU, bool STATS>
__global__ __launch_bounds__(256) void k_mfma_gemm_dual(
    const short* __restrict__ A,
    const short* __restrict__ BtM, const short* __restrict__ BtL,
    const float* __restrict__ biasM, const float* __restrict__ biasL, int biasN,
    short* __restrict__ Cout, int Cstat, int Cwrite, int Cstride,
    int Astride, int Kloop, int NC,
    int mainLimit, int lgLimit,
    float* __restrict__ statsM, float* __restrict__ statsL) {
  __shared__ __align__(16) short ldsA[2][128 * 32];
  __shared__ __align__(16) short ldsB[2][128 * 32];
  __shared__ float sd[256];

  int bid = blockIdx.x;
  int xcd = bid & 7;
  int t0 = bid >> 3;
  int c = t0 % NC;
  int rr = t0 / NC;
  int rtile = rr * 8 + xcd;
  if (rtile >= NRT) return;

  const int tid = threadIdx.x;
  const int lane = tid & 63, w = tid >> 6;
  const bool isMain = rtile < MAIN_TILES;
  const short* Bt = isMain ? BtM : BtL;
  const float* bias = isMain ? biasM : biasL;
  const int rowLimit = isMain ? mainLimit : lgLimit;
  const int brow = rtile * 128;
  const int bcol = c * 128;
  const int wr = w >> 1, wc = w & 1;

  if (STATS) sd[tid] = 0.f;

  f32x4 acc[4][4] = {};

  const int sr = tid >> 2;
  const int sc = (tid & 3) * 8;

  auto stage = [&](int buf, int k0) {
    char* la = (char*)(&ldsA[buf][0]) + w * 1024;
    char* lb = (char*)(&ldsB[buf][0]) + w * 1024;
    const short* gA0 = A + (size_t)(brow + sr) * Astride + (k0 + sc);
    const short* gB0 = Bt + (size_t)(bcol + sr) * Astride + (k0 + sc);
    gload_lds16(gA0, la);
    gload_lds16(gA0 + (size_t)64 * Astride, la + 4096);
    gload_lds16(gB0, lb);
    gload_lds16(gB0 + (size_t)64 * Astride, lb + 4096);
  };

  const int nt = Kloop / 32;
  stage(0, 0);
  __syncthreads();

  for (int t = 0; t < nt; ++t) {
    int cb = t & 1;
    if (t + 1 < nt) stage(cb ^ 1, (t + 1) * 32);

    const int kq = (lane >> 4) * 16;
    const char* baseA = (const char*)(&ldsA[cb][0]);
    const char* baseB = (const char*)(&ldsB[cb][0]);
    half8 af[4], bf[4];
#pragma unroll
    for (int m = 0; m < 4; ++m) {
      int row = wr * 64 + m * 16 + (lane & 15);
      af[m] = *(const half8*)(baseA + row * 64 + kq);
    }
#pragma unroll
    for (int n = 0; n < 4; ++n) {
      int col = wc * 64 + n * 16 + (lane & 15);
      bf[n] = *(const half8*)(baseB + col * 64 + kq);
    }
#pragma unroll
    for (int m = 0; m < 4; ++m)
#pragma unroll
      for (int n = 0; n < 4; ++n)
        acc[m][n] = __builtin_amdgcn_mfma_f32_16x16x32_f16(af[m], bf[n], acc[m][n], 0, 0, 0);
    __syncthreads();
  }

  const int r0 = brow + wr * 64;
  const int c0 = bcol + wc * 64;
  float ps[4] = {}, pq[4] = {};
#pragma unroll
  for (int m = 0; m < 4; ++m) {
#pragma unroll
    for (int i = 0; i < 4; ++i) {
      int row = r0 + m * 16 + (lane >> 4) * 4 + i;
      bool rv = row < rowLimit;
#pragma unroll
      for (int n = 0; n < 4; ++n) {
        int col = c0 + n * 16 + (lane & 15);
        float bv = (col < biasN) ? bias[col] : 0.f;
        float v = acc[m][n][i] + bv;
        if (RELU) v = fmaxf(v, 0.f);
        if (rv && col < Cwrite) {
          Cout[(size_t)row * Cstride + col] = f2h(v);
          if (STATS && col < Cstat) { ps[n] += v; pq[n] += v * v; }
        }
      }
    }
  }

  if (STATS) {
#pragma unroll
    for (int n = 0; n < 4; ++n) {
      float s = ps[n], q = pq[n];
      s += __shfl_xor(s, 16); q += __shfl_xor(q, 16);
      s += __shfl_xor(s, 32); q += __shfl_xor(q, 32);
      if ((lane >> 4) == 0) {
        int cc = wc * 64 + n * 16 + (lane & 15);
        atomicAdd(&sd[cc], s);
        atomicAdd(&sd[128 + cc], q);
      }
    }
    __syncthreads();
    float* gs = isMain ? statsM : statsL;
    if (tid < 128) {
      int col = bcol + tid;
      if (col < Cstat) {
        atomicAdd(&gs[col], sd[tid]);
        atomicAdd(&gs[320 + col], sd[128 + tid]);
      }
    }
  }
}

// ---------------- final-layer BN apply (coef fused, no relu) ----------------

__global__ void k_bn_final(const uint4* __restrict__ pre,
                           const float* __restrict__ stp, const float* __restrict__ gbp,
                           float* __restrict__ outF) {
  int g = blockIdx.x * blockDim.x + threadIdx.x;
  if (g >= NALL * RQ) return;
  int r = g / RQ, q = g - r * RQ;
  bool m = r < kN;
  int pr = m ? r : MP_N + (r - kN);
  float a[8], b[8];
  bn_coef8(stp + (m ? 0 : 640), gbp + (m ? 0 : 640), q,
           m ? (1.f / kN) : (1.f / kNLG), a, b);
  float v[8], y[8];
  unpk8(pre[(size_t)pr * RQ + q], v);
#pragma unroll
  for (int i = 0; i < 8; ++i) y[i] = a[i] * v[i] + b[i];
  float* op = outF + (size_t)r * D + q * 8;
  if (q < 37) {
    *(float4*)op = make_float4(y[0], y[1], y[2], y[3]);
    *(float4*)(op + 4) = make_float4(y[4], y[5], y[6], y[7]);
  } else if (q == 37) {
    *(float4*)op = make_float4(y[0], y[1], y[2], y[3]);
  }
}

}  // namespace

extern "C" void kernel_launch(void* const* d_in, const int* in_sizes, int n_in,
                              void* d_out_v, int out_size, void* d_ws, size_t ws_size,
                              hipStream_t stream) {
  const int*   x            = (const int*)d_in[0];
  const int*   edge_index   = (const int*)d_in[1];
  const int*   edge_attr    = (const int*)d_in[2];
  const int*   lg_x         = (const int*)d_in[3];
  const int*   lg_edge_index= (const int*)d_in[4];
  const int*   lg_map       = (const int*)d_in[5];
  const int*   lg_map2      = (const int*)d_in[6];
  const float* node_emb1    = (const float*)d_in[7];
  const float* node_emb2    = (const float*)d_in[8];
  const float* gnn_e_emb1   = (const float*)d_in[9];
  const float* gnn_e_emb2   = (const float*)d_in[10];
  const float* g_emb1       = (const float*)d_in[11];
  const float* g_emb2       = (const float*)d_in[12];
  const float* g_w1         = (const float*)d_in[13];
  const float* g_b1         = (const float*)d_in[14];
  const float* g_w2         = (const float*)d_in[15];
  const float* g_b2         = (const float*)d_in[16];
  const float* g_gamma      = (const float*)d_in[17];
  const float* g_beta       = (const float*)d_in[18];
  const float* lg_emb1      = (const float*)d_in[19];
  const float* lg_emb2      = (const float*)d_in[20];
  const float* lg_w1        = (const float*)d_in[21];
  const float* lg_b1        = (const float*)d_in[22];
  const float* lg_w2        = (const float*)d_in[23];
  const float* lg_b2        = (const float*)d_in[24];
  const float* lg_gamma     = (const float*)d_in[25];
  const float* lg_beta      = (const float*)d_in[26];

  float* out = (float*)d_out_v;
  char*  ws  = (char*)d_ws;

  size_t off = 0;
  auto alloc = [&](size_t bytes) { void* p = ws + off; off = (off + bytes + 255) & ~(size_t)255; return p; };
  short* ab      = (short*)alloc((size_t)MP_ALL * K1P * 2);
  short* hidden  = (short*)alloc((size_t)MP_ALL * N1P * 2);
  short* pre2    = (short*)alloc((size_t)2 * MP_ALL * PQH * 2);
  short* hist    = (short*)alloc((size_t)NALL * RH * 2);
  short* g_w1t   = (short*)alloc((size_t)kL * N1P * K1P * 2);
  short* g_w2t   = (short*)alloc((size_t)kL * N2P * K2P * 2);
  short* lg_w1t  = (short*)alloc((size_t)kL * N1P * K1P * 2);
  short* lg_w2t  = (short*)alloc((size_t)kL * N2P * K2P * 2);
  float* stats   = (float*)alloc(kL * STL * 4);
  float* gbp     = (float*)alloc(kL * STL * 4);
  float* slv     = (float*)alloc(kL * 640 * 4);
  short* tcm     = (short*)alloc(18 * RH * 2);
  short* tcl     = (short*)alloc(360 * RH * 2);
  int2* r0m    = (int2*)alloc((size_t)kE * 8);
  int2* r0l    = (int2*)alloc((size_t)kELG * 8);
  int2* rLm    = (int2*)alloc((size_t)2 * kNLG * 8);
  int2* rLl    = (int2*)alloc((size_t)kELG * 8);
  int* m0_offs = (int*)alloc((kN + 1) * 4);
  int* m0_cur  = (int*)alloc(kN * 4);
  int* mL_offs = (int*)alloc((kN + 1) * 4);
  int* mL_cur  = (int*)alloc(kN * 4);
  int* lg_offs = (int*)alloc((kNLG + 1) * 4);
  int* lg_cur  = (int*)alloc(kNLG * 4);

  auto hptr = [&](int l) { return out + (size_t)l * 60000 * D; };
  auto prep = [&](int s) { return pre2 + (size_t)s * MP_ALL * PQH; };

  dim3 b(256);

  // ---- prologue (5 dispatches) ----
  k_init<<<(kNLG + 255) / 256, b, 0, stream>>>(stats, ab, m0_cur, mL_cur, lg_cur);
  {
    int tot = kE + 2 * kNLG + kELG;
    k_hist_all<<<(tot + 255) / 256, b, 0, stream>>>(edge_index, lg_map, lg_edge_index,
                                                    m0_cur, mL_cur, lg_cur);
    k_scan3<<<3, b, 0, stream>>>(m0_cur, m0_offs, mL_cur, mL_offs, lg_cur, lg_offs);
    k_fill_all<<<(tot + 255) / 256, b, 0, stream>>>(edge_index, lg_map, lg_edge_index,
                                                    edge_attr, lg_map2, x,
                                                    m0_cur, r0m, mL_cur, rLm,
                                                    lg_cur, r0l, rLl);
  }
  {
    int tot = 2 * kL * (N1P * K1P + N2P * K2P) + kL * 640 + 378 * RH + kL * STL;
    k_precomp<<<(tot + 255) / 256, b, 0, stream>>>(g_emb1, g_emb2, lg_emb1, lg_emb2,
                                                   g_w1, g_w2, lg_w1, lg_w2,
                                                   g_gamma, g_beta, lg_gamma, lg_beta,
                                                   slv, tcm, tcl, gbp,
                                                   g_w1t, g_w2t, lg_w1t, lg_w2t);
  }
  k_embed_all<<<(NALL * RQ + 255) / 256, b, 0, stream>>>(x, lg_x, node_emb1, node_emb2,
                                                         gnn_e_emb1, gnn_e_emb2,
                                                         hptr(0), (uint4*)hist);

  int cur = 0;
  for (int l = 0; l < kL; ++l) {
    float* slot = stats + (size_t)l * STL;
    const float* slvM = slv + (size_t)l * 640;
    const float* slvL = slvM + 320;

    if (l == 0)
      k_gather_all0<<<NALL, 64, 0, stream>>>(
          (const uint4*)hist, (const uint4*)(hist + (size_t)kN * RH),
          r0m, r0l, (const uint4*)tcm, (const uint4*)tcl,
          slvM, slvL, m0_offs, lg_offs, (uint4*)ab);
    else
      k_gather_bnL<<<NALL, 64, 0, stream>>>(
          (const uint4*)prep(cur),
          stats + (size_t)(l - 1) * STL, gbp + (size_t)(l - 1) * STL,
          rLm, rLl, slvM, slvL, mL_offs, lg_offs,
          hptr(l), (uint4*)ab);

    k_mfma_gemm_dual<true, false><<<8 * NRP * 5, b, 0, stream>>>(
        ab, g_w1t + (size_t)l * N1P * K1P, lg_w1t + (size_t)l * N1P * K1P,
        g_b1 + (size_t)l * 2 * D, lg_b1 + (size_t)l * 2 * D, 2 * D,
        hidden, 0, 608, N1P, K1P, K1P, 5, MP_ALL, MP_ALL, nullptr, nullptr);

    int nxt = cur ^ 1;
    k_mfma_gemm_dual<false, true><<<8 * NRP * 3, b, 0, stream>>>(
        hidden, g_w2t + (size_t)l * N2P * K2P, lg_w2t + (size_t)l * N2P * K2P,
        g_b2 + (size_t)l * D, lg_b2 + (size_t)l * D, D,
        prep(nxt), D, PQH, PQH, K2P, 608, 3, kN, MP_N + kNLG,
        slot, slot + 640);
    cur = nxt;
  }

  // final layer output (h_list[5], e_list[5]) — BN only, no relu
  k_bn_final<<<(NALL * RQ + 255) / 256, b, 0, stream>>>(
      (const uint4*)prep(cur),
      stats + (size_t)(kL - 1) * STL, gbp + (size_t)(kL - 1) * STL, hptr(kL));
}

// Round 17
// 1314.078 us; speedup vs baseline: 1.1283x; 1.0054x over previous
//
#include <hip/hip_runtime.h>

#define D 300

namespace {

constexpr int kN   = 20000;
constexpr int kNLG = 40000;
constexpr int kE   = 80000;
constexpr int kELG = 200000;
constexpr int kL   = 5;

constexpr int K1P = 320;
constexpr int N1P = 640;
constexpr int K2P = 640;
constexpr int N2P = 384;
constexpr int PQH = 320;
constexpr int MP_N   = 20096;
constexpr int MP_ALL = 60160;
constexpr int MAIN_TILES = 157;
constexpr int NRT = 470;
constexpr int NRP = 59;
constexpr int RH = 320;
constexpr int RQ = 40;
constexpr int RQR = 38;     // read-active uint4 lanes (cols 0..303)
constexpr int NALL = kN + kNLG;
constexpr int STL = 1280;

typedef __attribute__((ext_vector_type(8))) _Float16 half8;
typedef __attribute__((ext_vector_type(2))) _Float16 half2v;
typedef __attribute__((ext_vector_type(4))) float f32x4;

__device__ inline short f2h(float f) {
  _Float16 h = (_Float16)f;
  return __builtin_bit_cast(short, h);
}

__device__ inline float2 upk(unsigned u) {
  half2v h = __builtin_bit_cast(half2v, u);
  return make_float2((float)h.x, (float)h.y);
}

__device__ inline unsigned pk(float a, float b) {
  half2v h;
  h.x = (_Float16)a;
  h.y = (_Float16)b;
  return __builtin_bit_cast(unsigned, h);
}

__device__ inline void addrow(float* acc, uint4 r) {
  float2 t0 = upk(r.x), t1 = upk(r.y), t2 = upk(r.z), t3 = upk(r.w);
  acc[0] += t0.x; acc[1] += t0.y; acc[2] += t1.x; acc[3] += t1.y;
  acc[4] += t2.x; acc[5] += t2.y; acc[6] += t3.x; acc[7] += t3.y;
}

__device__ inline void unpk8(uint4 r, float* v) {
  float2 t0 = upk(r.x), t1 = upk(r.y), t2 = upk(r.z), t3 = upk(r.w);
  v[0] = t0.x; v[1] = t0.y; v[2] = t1.x; v[3] = t1.y;
  v[4] = t2.x; v[5] = t2.y; v[6] = t3.x; v[7] = t3.y;
}

__device__ inline uint4 pk4(const float* a) {
  uint4 r;
  r.x = pk(a[0], a[1]); r.y = pk(a[2], a[3]);
  r.z = pk(a[4], a[5]); r.w = pk(a[6], a[7]);
  return r;
}

__device__ inline void gload_lds16(const void* g, void* l) {
  __builtin_amdgcn_global_load_lds(
      (const __attribute__((address_space(1))) void*)g,
      (__attribute__((address_space(3))) void*)l, 16, 0, 0);
}

__device__ inline void bn_coef8(const float* sb, const float* gb, int q,
                                float inv_n, float* a, float* b) {
  float4 s0 = *(const float4*)(sb + q * 8);
  float4 s1 = *(const float4*)(sb + q * 8 + 4);
  float4 q0 = *(const float4*)(sb + 320 + q * 8);
  float4 q1 = *(const float4*)(sb + 320 + q * 8 + 4);
  float4 g0 = *(const float4*)(gb + q * 8);
  float4 g1 = *(const float4*)(gb + q * 8 + 4);
  float4 e0 = *(const float4*)(gb + 320 + q * 8);
  float4 e1 = *(const float4*)(gb + 320 + q * 8 + 4);
  float su[8] = {s0.x, s0.y, s0.z, s0.w, s1.x, s1.y, s1.z, s1.w};
  float sq[8] = {q0.x, q0.y, q0.z, q0.w, q1.x, q1.y, q1.z, q1.w};
  float ga[8] = {g0.x, g0.y, g0.z, g0.w, g1.x, g1.y, g1.z, g1.w};
  float be[8] = {e0.x, e0.y, e0.z, e0.w, e1.x, e1.y, e1.z, e1.w};
#pragma unroll
  for (int i = 0; i < 8; ++i) {
    float mu = su[i] * inv_n;
    float var = sq[i] * inv_n - mu * mu;
    a[i] = rsqrtf(var + 1e-5f) * ga[i];
    b[i] = be[i] - mu * a[i];
  }
}

// ---------------- init ----------------

__global__ void k_init(float* __restrict__ stats, short* __restrict__ ab,
                       int* __restrict__ m0_cur, int* __restrict__ mL_cur,
                       int* __restrict__ lg_cur) {
  int g = blockIdx.x * blockDim.x + threadIdx.x;
  if (g < kL * STL) stats[g] = 0.f;
  int np1 = (MP_N - kN) * K1P;
  int np2 = (MP_ALL - MP_N - kNLG) * K1P;
  if (g < np1) ab[(size_t)kN * K1P + g] = 0;
  if (g < np2) ab[(size_t)(MP_N + kNLG) * K1P + g] = 0;
  if (g < kN) { m0_cur[g] = 0; mL_cur[g] = 0; }
  if (g < kNLG) lg_cur[g] = 0;
}

// ---------------- CSR build ----------------

__global__ void k_hist_all(const int* __restrict__ edge_index,
                           const int* __restrict__ lg_map,
                           const int* __restrict__ lg_ei,
                           int* __restrict__ m0_cur, int* __restrict__ mL_cur,
                           int* __restrict__ lg_cur) {
  int g = blockIdx.x * blockDim.x + threadIdx.x;
  if (g < kE) { atomicAdd(&m0_cur[edge_index[kE + g]], 1); return; }
  g -= kE;
  if (g < kNLG) { atomicAdd(&mL_cur[lg_map[kNLG + g]], 1); return; }
  g -= kNLG;
  if (g < kNLG) { atomicAdd(&mL_cur[lg_map[g]], 1); return; }
  g -= kNLG;
  if (g < kELG) atomicAdd(&lg_cur[lg_ei[kELG + g]], 1);
}

__device__ void scan_one(int* cursor, int* offs, int n) {
  __shared__ int part[256];
  int tid = threadIdx.x;
  int chunk = (n + 255) / 256;
  int s0 = tid * chunk;
  int s1 = min(n, s0 + chunk);
  int sum = 0;
  for (int i = s0; i < s1; ++i) sum += cursor[i];
  part[tid] = sum;
  __syncthreads();
  for (int off = 1; off < 256; off <<= 1) {
    int v = (tid >= off) ? part[tid - off] : 0;
    __syncthreads();
    part[tid] += v;
    __syncthreads();
  }
  int run = (tid == 0) ? 0 : part[tid - 1];
  for (int i = s0; i < s1; ++i) {
    int dv = cursor[i];
    offs[i] = run;
    cursor[i] = run;
    run += dv;
  }
  if (tid == 255) offs[n] = run;
}

__global__ __launch_bounds__(256) void k_scan3(
    int* __restrict__ m0_cur, int* __restrict__ m0_offs,
    int* __restrict__ mL_cur, int* __restrict__ mL_offs,
    int* __restrict__ lg_cur, int* __restrict__ lg_offs) {
  if (blockIdx.x == 0) scan_one(m0_cur, m0_offs, kN);
  else if (blockIdx.x == 1) scan_one(mL_cur, mL_offs, kN);
  else scan_one(lg_cur, lg_offs, kNLG);
}

__global__ void k_fill_all(const int* __restrict__ edge_index,
                           const int* __restrict__ lg_map,
                           const int* __restrict__ lg_ei,
                           const int* __restrict__ eattr,
                           const int* __restrict__ map2,
                           const int* __restrict__ x,
                           int* __restrict__ m0_cur, int2* __restrict__ r0m,
                           int* __restrict__ mL_cur, int2* __restrict__ rLm,
                           int* __restrict__ lg_cur, int2* __restrict__ r0l,
                           int2* __restrict__ rLl) {
  int g = blockIdx.x * blockDim.x + threadIdx.x;
  if (g < kE) {
    int pos = atomicAdd(&m0_cur[edge_index[kE + g]], 1);
    r0m[pos] = make_int2(edge_index[g], eattr[2 * g] * 3 + eattr[2 * g + 1]);
    return;
  }
  g -= kE;
  if (g < kNLG) {
    int pos = atomicAdd(&mL_cur[lg_map[kNLG + g]], 1);
    rLm[pos] = make_int2(lg_map[g], MP_N + g);
    return;
  }
  g -= kNLG;
  if (g < kNLG) {
    int pos = atomicAdd(&mL_cur[lg_map[g]], 1);
    rLm[pos] = make_int2(lg_map[kNLG + g], MP_N + g);
    return;
  }
  g -= kNLG;
  if (g < kELG) {
    int pos = atomicAdd(&lg_cur[lg_ei[kELG + g]], 1);
    int a = map2[g];
    r0l[pos] = make_int2(lg_ei[g], x[2 * a] * 3 + x[2 * a + 1]);
    rLl[pos] = make_int2(a, MP_N + lg_ei[g]);
  }
}

// ---------------- merged precompute ----------------

__device__ void cvt_w1(const float* W, short* Wt, int g) {
  int per = N1P * K1P;
  int l = g / per, rem = g - l * per;
  int n = rem / K1P, k = rem - n * K1P;
  float v = (n < 2 * D && k < D) ? W[(size_t)l * D * 2 * D + (size_t)k * 2 * D + n] : 0.f;
  Wt[g] = f2h(v);
}

__device__ void cvt_w2(const float* W, short* Wt, int g) {
  int per = N2P * K2P;
  int l = g / per, rem = g - l * per;
  int n = rem / K2P, k = rem - n * K2P;
  float v = (n < D && k < 2 * D) ? W[(size_t)l * 2 * D * D + (size_t)k * D + n] : 0.f;
  Wt[g] = f2h(v);
}

__global__ void k_precomp(const float* __restrict__ g1, const float* __restrict__ g2,
                          const float* __restrict__ l1, const float* __restrict__ l2,
                          const float* __restrict__ g_w1, const float* __restrict__ g_w2,
                          const float* __restrict__ lg_w1, const float* __restrict__ lg_w2,
                          const float* __restrict__ g_gamma, const float* __restrict__ g_beta,
                          const float* __restrict__ lg_gamma, const float* __restrict__ lg_beta,
                          float* __restrict__ slv, short* __restrict__ tcm,
                          short* __restrict__ tcl, float* __restrict__ gbp,
                          short* __restrict__ g_w1t, short* __restrict__ g_w2t,
                          short* __restrict__ lg_w1t, short* __restrict__ lg_w2t) {
  int g = blockIdx.x * blockDim.x + threadIdx.x;
  const int s1 = kL * N1P * K1P, s2 = kL * N2P * K2P;
  if (g < s1) { cvt_w1(g_w1, g_w1t, g); return; }
  g -= s1;
  if (g < s2) { cvt_w2(g_w2, g_w2t, g); return; }
  g -= s2;
  if (g < s1) { cvt_w1(lg_w1, lg_w1t, g); return; }
  g -= s1;
  if (g < s2) { cvt_w2(lg_w2, lg_w2t, g); return; }
  g -= s2;
  if (g < kL * 640) {
    int l = g / 640, rem = g - l * 640;
    int gr = rem / 320, c = rem - gr * 320;
    float v = 0.f;
    if (c < D) {
      if (gr == 0) v = g1[(size_t)l * 6 * D + 4 * D + c] + g2[(size_t)l * 3 * D + c];
      else         v = l1[(size_t)l * 120 * D + 119 * D + c] + l2[(size_t)l * 3 * D + c];
    }
    slv[g] = v;
    return;
  }
  g -= kL * 640;
  if (g < 18 * RH) {
    int p = g / RH, c = g - p * RH;
    float v = (c < D) ? g1[(size_t)(p / 3) * D + c] + g2[(size_t)(p % 3) * D + c] : 0.f;
    tcm[g] = f2h(v);
    return;
  }
  g -= 18 * RH;
  if (g < 360 * RH) {
    int p = g / RH, c = g - p * RH;
    float v = (c < D) ? l1[(size_t)(p / 3) * D + c] + l2[(size_t)(p % 3) * D + c] : 0.f;
    tcl[g] = f2h(v);
    return;
  }
  g -= 360 * RH;
  if (g < kL * STL) {
    int l = g / STL, rem = g - l * STL;
    int seg = rem / 320, c = rem - seg * 320;
    float v = 0.f;
    if (c < D) {
      const float* src = (seg == 0) ? g_gamma : (seg == 1) ? g_beta
                       : (seg == 2) ? lg_gamma : lg_beta;
      v = src[(size_t)l * D + c];
    }
    gbp[g] = v;
  }
}

// ---------------- embed ----------------

__global__ void k_embed_all(const int* __restrict__ x, const int* __restrict__ lg_x,
                            const float* __restrict__ t1m, const float* __restrict__ t2m,
                            const float* __restrict__ t1l, const float* __restrict__ t2l,
                            float* __restrict__ outF, uint4* __restrict__ hist) {
  int g = blockIdx.x * blockDim.x + threadIdx.x;
  if (g >= NALL * RQ) return;
  int r = g / RQ, q = g - r * RQ;
  bool m = r < kN;
  int i = m ? r : r - kN;
  const int* ix = (m ? x : lg_x) + 2 * i;
  const float* t1 = (m ? t1m : t1l) + (size_t)ix[0] * D;
  const float* t2 = (m ? t2m : t2l) + (size_t)ix[1] * D;
  int c0 = q * 8;
  float y[8] = {0.f, 0.f, 0.f, 0.f, 0.f, 0.f, 0.f, 0.f};
  if (c0 < D) {
    float4 p0 = *(const float4*)(t1 + c0);
    float4 q0 = *(const float4*)(t2 + c0);
    y[0] = p0.x + q0.x; y[1] = p0.y + q0.y; y[2] = p0.z + q0.z; y[3] = p0.w + q0.w;
    *(float4*)(outF + (size_t)r * D + c0) = make_float4(y[0], y[1], y[2], y[3]);
    if (c0 + 8 <= D) {
      float4 p1 = *(const float4*)(t1 + c0 + 4);
      float4 q1 = *(const float4*)(t2 + c0 + 4);
      y[4] = p1.x + q1.x; y[5] = p1.y + q1.y; y[6] = p1.z + q1.z; y[7] = p1.w + q1.w;
      *(float4*)(outF + (size_t)r * D + c0 + 4) = make_float4(y[4], y[5], y[6], y[7]);
    }
  }
  hist[(size_t)r * RQ + q] = pk4(y);
}

// ---------------- gather, layer 0 (38-lane reads) ----------------

__global__ __launch_bounds__(64) void k_gather_all0(
    const uint4* __restrict__ h16, const uint4* __restrict__ e16,
    const int2* __restrict__ r0m, const int2* __restrict__ r0l,
    const uint4* __restrict__ tcm, const uint4* __restrict__ tcl,
    const float* __restrict__ slvM, const float* __restrict__ slvL,
    const int* __restrict__ m_offs, const int* __restrict__ l_offs,
    uint4* __restrict__ ab) {
  int node = blockIdx.x;
  int lane = threadIdx.x;
  int ll = (lane < RQR) ? lane : 0;
  bool isM = node < kN;
  int j = isM ? node : node - kN;
  const uint4* selfrow = isM ? (h16 + (size_t)node * RQ) : (e16 + (size_t)j * RQ);
  uint4 selfq = selfrow[ll];
  const float* sv = (isM ? slvM : slvL) + ll * 8;
  const int* offs = isM ? m_offs : l_offs;
  const int2* rows = isM ? r0m : r0l;
  const uint4* bA = isM ? h16 : e16;
  const uint4* bB = isM ? tcm : tcl;

  float acc[8];
  {
    float vv[8];
    unpk8(selfq, vv);
#pragma unroll
    for (int i = 0; i < 8; ++i) acc[i] = vv[i] + sv[i];
  }

  int p0 = offs[j], p1 = offs[j + 1];
  for (int pb = p0; pb < p1; pb += 64) {
    int cnt = min(64, p1 - pb);
    int2 rr_ = rows[pb + ((lane < cnt) ? lane : 0)];
    int ra = rr_.x, rb = rr_.y;
    int t = 0;
    for (; t + 3 < cnt; t += 4) {
      int a0 = __shfl(ra, t),     b0 = __shfl(rb, t);
      int a1 = __shfl(ra, t + 1), b1 = __shfl(rb, t + 1);
      int a2 = __shfl(ra, t + 2), b2 = __shfl(rb, t + 2);
      int a3 = __shfl(ra, t + 3), b3 = __shfl(rb, t + 3);
      uint4 x0 = bA[(size_t)a0 * RQ + ll];
      uint4 y0 = bB[(size_t)b0 * RQ + ll];
      uint4 x1 = bA[(size_t)a1 * RQ + ll];
      uint4 y1 = bB[(size_t)b1 * RQ + ll];
      uint4 x2 = bA[(size_t)a2 * RQ + ll];
      uint4 y2 = bB[(size_t)b2 * RQ + ll];
      uint4 x3 = bA[(size_t)a3 * RQ + ll];
      uint4 y3 = bB[(size_t)b3 * RQ + ll];
      addrow(acc, x0); addrow(acc, y0);
      addrow(acc, x1); addrow(acc, y1);
      addrow(acc, x2); addrow(acc, y2);
      addrow(acc, x3); addrow(acc, y3);
    }
    for (; t < cnt; ++t) {
      int a0 = __shfl(ra, t), b0 = __shfl(rb, t);
      uint4 x0 = bA[(size_t)a0 * RQ + ll];
      uint4 y0 = bB[(size_t)b0 * RQ + ll];
      addrow(acc, x0); addrow(acc, y0);
    }
  }
  if (lane < RQ)
    ab[(size_t)(isM ? node : MP_N + j) * RQ + lane] =
        (lane < RQR) ? pk4(acc) : make_uint4(0, 0, 0, 0);
}

// ---------------- gather + fused BN (layers 1..4; 38-lane reads) ----------------

__global__ __launch_bounds__(64) void k_gather_bnL(
    const uint4* __restrict__ pre,
    const float* __restrict__ stp, const float* __restrict__ gbp,
    const int2* __restrict__ rLm, const int2* __restrict__ rLl,
    const float* __restrict__ slvM, const float* __restrict__ slvL,
    const int* __restrict__ m_offs, const int* __restrict__ l_offs,
    float* __restrict__ outF, uint4* __restrict__ ab) {
  int node = blockIdx.x;
  int lane = threadIdx.x;
  int ll = (lane < RQR) ? lane : 0;
  bool isM = node < kN;
  int j = isM ? node : node - kN;

  int selfIdx = isM ? node : MP_N + j;
  uint4 selfq = pre[(size_t)selfIdx * RQ + ll];   // issue before coef math

  float aM[8], bM[8], aL[8], bL[8];
  bn_coef8(stp, gbp, ll, 1.f / kN, aM, bM);
  bn_coef8(stp + 640, gbp + 640, ll, 1.f / kNLG, aL, bL);

  const float* sv = (isM ? slvM : slvL) + ll * 8;
  const int* offs = isM ? m_offs : l_offs;
  const int2* rows = isM ? rLm : rLl;

  float acc[8];
  {
    float vv[8], y[8];
    unpk8(selfq, vv);
#pragma unroll
    for (int i = 0; i < 8; ++i) {
      float a = isM ? aM[i] : aL[i];
      float b = isM ? bM[i] : bL[i];
      y[i] = fmaxf(a * vv[i] + b, 0.f);
      acc[i] = y[i] + sv[i];
    }
    if (lane < 37) {
      float* op = outF + (size_t)node * D + lane * 8;
      *(float4*)op = make_float4(y[0], y[1], y[2], y[3]);
      *(float4*)(op + 4) = make_float4(y[4], y[5], y[6], y[7]);
    } else if (lane == 37) {
      float* op = outF + (size_t)node * D + 296;
      *(float4*)op = make_float4(y[0], y[1], y[2], y[3]);
    }
  }

  int p0 = offs[j], p1 = offs[j + 1];
  for (int pb = p0; pb < p1; pb += 64) {
    int cnt = min(64, p1 - pb);
    int2 rr_ = rows[pb + ((lane < cnt) ? lane : 0)];
    int rh = rr_.x, re = rr_.y;
    int t = 0;
    for (; t + 1 < cnt; t += 2) {
      int h0 = __shfl(rh, t),     e0 = __shfl(re, t);
      int h1 = __shfl(rh, t + 1), e1 = __shfl(re, t + 1);
      uint4 xh0 = pre[(size_t)h0 * RQ + ll];
      uint4 xe0 = pre[(size_t)e0 * RQ + ll];
      uint4 xh1 = pre[(size_t)h1 * RQ + ll];
      uint4 xe1 = pre[(size_t)e1 * RQ + ll];
      float v[8];
      unpk8(xh0, v);
#pragma unroll
      for (int i = 0; i < 8; ++i) acc[i] += fmaxf(aM[i] * v[i] + bM[i], 0.f);
      unpk8(xe0, v);
#pragma unroll
      for (int i = 0; i < 8; ++i) acc[i] += fmaxf(aL[i] * v[i] + bL[i], 0.f);
      unpk8(xh1, v);
#pragma unroll
      for (int i = 0; i < 8; ++i) acc[i] += fmaxf(aM[i] * v[i] + bM[i], 0.f);
      unpk8(xe1, v);
#pragma unroll
      for (int i = 0; i < 8; ++i) acc[i] += fmaxf(aL[i] * v[i] + bL[i], 0.f);
    }
    if (t < cnt) {
      int h0 = __shfl(rh, t), e0 = __shfl(re, t);
      uint4 xh0 = pre[(size_t)h0 * RQ + ll];
      uint4 xe0 = pre[(size_t)e0 * RQ + ll];
      float v[8];
      unpk8(xh0, v);
#pragma unroll
      for (int i = 0; i < 8; ++i) acc[i] += fmaxf(aM[i] * v[i] + bM[i], 0.f);
      unpk8(xe0, v);
#pragma unroll
      for (int i = 0; i < 8; ++i) acc[i] += fmaxf(aL[i] * v[i] + bL[i], 0.f);
    }
  }
  if (lane < RQ)
    ab[(size_t)(isM ? node : MP_N + j) * RQ + lane] =
        (lane < RQR) ? pk4(acc) : make_uint4(0, 0, 0, 0);
}

// ---------------- dual MFMA GEMM ----------------

template<bool RELU, bool STATS>
__global__ __launch_bounds__(256) void k_mfma_gemm_dual(
    const short* __restrict__ A,
    const short* __restrict__ BtM, const short* __restrict__ BtL,
    const float* __restrict__ biasM, const float* __restrict__ biasL, int biasN,
    short* __restrict__ Cout, int Cstat, int Cwrite, int Cstride,
    int Astride, int Kloop, int NC,
    int mainLimit, int lgLimit,
    float* __restrict__ statsM, float* __restrict__ statsL) {
  __shared__ __align__(16) short ldsA[2][128 * 32];
  __shared__ __align__(16) short ldsB[2][128 * 32];
  __shared__ float sd[256];

  int bid = blockIdx.x;
  int xcd = bid & 7;
  int t0 = bid >> 3;
  int c = t0 % NC;
  int rr = t0 / NC;
  int rtile = rr * 8 + xcd;
  if (rtile >= NRT) return;

  const int tid = threadIdx.x;
  const int lane = tid & 63, w = tid >> 6;
  const bool isMain = rtile < MAIN_TILES;
  const short* Bt = isMain ? BtM : BtL;
  const float* bias = isMain ? biasM : biasL;
  const int rowLimit = isMain ? mainLimit : lgLimit;
  const int brow = rtile * 128;
  const int bcol = c * 128;
  const int wr = w >> 1, wc = w & 1;

  if (STATS) sd[tid] = 0.f;

  f32x4 acc[4][4] = {};

  const int sr = tid >> 2;
  const int sc = (tid & 3) * 8;

  auto stage = [&](int buf, int k0) {
    char* la = (char*)(&ldsA[buf][0]) + w * 1024;
    char* lb = (char*)(&ldsB[buf][0]) + w * 1024;
    const short* gA0 = A + (size_t)(brow + sr) * Astride + (k0 + sc);
    const short* gB0 = Bt + (size_t)(bcol + sr) * Astride + (k0 + sc);
    gload_lds16(gA0, la);
    gload_lds16(gA0 + (size_t)64 * Astride, la + 4096);
    gload_lds16(gB0, lb);
    gload_lds16(gB0 + (size_t)64 * Astride, lb + 4096);
  };

  const int nt = Kloop / 32;
  stage(0, 0);
  __syncthreads();

  for (int t = 0; t < nt; ++t) {
    int cb = t & 1;
    if (t + 1 < nt) stage(cb ^ 1, (t + 1) * 32);

    const int kq = (lane >> 4) * 16;
    const char* baseA = (const char*)(&ldsA[cb][0]);
    const char* baseB = (const char*)(&ldsB[cb][0]);
    half8 af[4], bf[4];
#pragma unroll
    for (int m = 0; m < 4; ++m) {
      int row = wr * 64 + m * 16 + (lane & 15);
      af[m] = *(const half8*)(baseA + row * 64 + kq);
    }
#pragma unroll
    for (int n = 0; n < 4; ++n) {
      int col = wc * 64 + n * 16 + (lane & 15);
      bf[n] = *(const half8*)(baseB + col * 64 + kq);
    }
#pragma unroll
    for (int m = 0; m < 4; ++m)
#pragma unroll
      for (int n = 0; n < 4; ++n)
        acc[m][n] = __builtin_amdgcn_mfma_f32_16x16x32_f16(af[m], bf[n], acc[m][n], 0, 0, 0);
    __syncthreads();
  }

  const int r0 = brow + wr * 64;
  const int c0 = bcol + wc * 64;
  float ps[4] = {}, pq[4] = {};
#pragma unroll
  for (int m = 0; m < 4; ++m) {
#pragma unroll
    for (int i = 0; i < 4; ++i) {
      int row = r0 + m * 16 + (lane >> 4) * 4 + i;
      bool rv = row < rowLimit;
#pragma unroll
      for (int n = 0; n < 4; ++n) {
        int col = c0 + n * 16 + (lane & 15);
        float bv = (col < biasN) ? bias[col] : 0.f;
        float v = acc[m][n][i] + bv;
        if (RELU) v = fmaxf(v, 0.f);
        if (rv && col < Cwrite) {
          Cout[(size_t)row * Cstride + col] = f2h(v);
          if (STATS && col < Cstat) { ps[n] += v; pq[n] += v * v; }
        }
      }
    }
  }

  if (STATS) {
#pragma unroll
    for (int n = 0; n < 4; ++n) {
      float s = ps[n], q = pq[n];
      s += __shfl_xor(s, 16); q += __shfl_xor(q, 16);
      s += __shfl_xor(s, 32); q += __shfl_xor(q, 32);
      if ((lane >> 4) == 0) {
        int cc = wc * 64 + n * 16 + (lane & 15);
        atomicAdd(&sd[cc], s);
        atomicAdd(&sd[128 + cc], q);
      }
    }
    __syncthreads();
    float* gs = isMain ? statsM : statsL;
    if (tid < 128) {
      int col = bcol + tid;
      if (col < Cstat) {
        atomicAdd(&gs[col], sd[tid]);
        atomicAdd(&gs[320 + col], sd[128 + tid]);
      }
    }
  }
}

// ---------------- final-layer BN apply ----------------

__global__ void k_bn_final(const uint4* __restrict__ pre,
                           const float* __restrict__ stp, const float* __restrict__ gbp,
                           float* __restrict__ outF) {
  int g = blockIdx.x * blockDim.x + threadIdx.x;
  if (g >= NALL * RQR) return;
  int r = g / RQR, q = g - r * RQR;
  bool m = r < kN;
  int pr = m ? r : MP_N + (r - kN);
  float a[8], b[8];
  bn_coef8(stp + (m ? 0 : 640), gbp + (m ? 0 : 640), q,
           m ? (1.f / kN) : (1.f / kNLG), a, b);
  float v[8], y[8];
  unpk8(pre[(size_t)pr * RQ + q], v);
#pragma unroll
  for (int i = 0; i < 8; ++i) y[i] = a[i] * v[i] + b[i];
  float* op = outF + (size_t)r * D + q * 8;
  if (q < 37) {
    *(float4*)op = make_float4(y[0], y[1], y[2], y[3]);
    *(float4*)(op + 4) = make_float4(y[4], y[5], y[6], y[7]);
  } else {
    op = outF + (size_t)r * D + 296;
    *(float4*)op = make_float4(y[0], y[1], y[2], y[3]);
  }
}

}  // namespace

extern "C" void kernel_launch(void* const* d_in, const int* in_sizes, int n_in,
                              void* d_out_v, int out_size, void* d_ws, size_t ws_size,
                              hipStream_t stream) {
  const int*   x            = (const int*)d_in[0];
  const int*   edge_index   = (const int*)d_in[1];
  const int*   edge_attr    = (const int*)d_in[2];
  const int*   lg_x         = (const int*)d_in[3];
  const int*   lg_edge_index= (const int*)d_in[4];
  const int*   lg_map       = (const int*)d_in[5];
  const int*   lg_map2      = (const int*)d_in[6];
  const float* node_emb1    = (const float*)d_in[7];
  const float* node_emb2    = (const float*)d_in[8];
  const float* gnn_e_emb1   = (const float*)d_in[9];
  const float* gnn_e_emb2   = (const float*)d_in[10];
  const float* g_emb1       = (const float*)d_in[11];
  const float* g_emb2       = (const float*)d_in[12];
  const float* g_w1         = (const float*)d_in[13];
  const float* g_b1         = (const float*)d_in[14];
  const float* g_w2         = (const float*)d_in[15];
  const float* g_b2         = (const float*)d_in[16];
  const float* g_gamma      = (const float*)d_in[17];
  const float* g_beta       = (const float*)d_in[18];
  const float* lg_emb1      = (const float*)d_in[19];
  const float* lg_emb2      = (const float*)d_in[20];
  const float* lg_w1        = (const float*)d_in[21];
  const float* lg_b1        = (const float*)d_in[22];
  const float* lg_w2        = (const float*)d_in[23];
  const float* lg_b2        = (const float*)d_in[24];
  const float* lg_gamma     = (const float*)d_in[25];
  const float* lg_beta      = (const float*)d_in[26];

  float* out = (float*)d_out_v;
  char*  ws  = (char*)d_ws;

  size_t off = 0;
  auto alloc = [&](size_t bytes) { void* p = ws + off; off = (off + bytes + 255) & ~(size_t)255; return p; };
  short* ab      = (short*)alloc((size_t)MP_ALL * K1P * 2);
  short* hidden  = (short*)alloc((size_t)MP_ALL * N1P * 2);
  short* pre2    = (short*)alloc((size_t)2 * MP_ALL * PQH * 2);
  short* hist    = (short*)alloc((size_t)NALL * RH * 2);
  short* g_w1t   = (short*)alloc((size_t)kL * N1P * K1P * 2);
  short* g_w2t   = (short*)alloc((size_t)kL * N2P * K2P * 2);
  short* lg_w1t  = (short*)alloc((size_t)kL * N1P * K1P * 2);
  short* lg_w2t  = (short*)alloc((size_t)kL * N2P * K2P * 2);
  float* stats   = (float*)alloc(kL * STL * 4);
  float* gbp     = (float*)alloc(kL * STL * 4);
  float* slv     = (float*)alloc(kL * 640 * 4);
  short* tcm     = (short*)alloc(18 * RH * 2);
  short* tcl     = (short*)alloc(360 * RH * 2);
  int2* r0m    = (int2*)alloc((size_t)kE * 8);
  int2* r0l    = (int2*)alloc((size_t)kELG * 8);
  int2* rLm    = (int2*)alloc((size_t)2 * kNLG * 8);
  int2* rLl    = (int2*)alloc((size_t)kELG * 8);
  int* m0_offs = (int*)alloc((kN + 1) * 4);
  int* m0_cur  = (int*)alloc(kN * 4);
  int* mL_offs = (int*)alloc((kN + 1) * 4);
  int* mL_cur  = (int*)alloc(kN * 4);
  int* lg_offs = (int*)alloc((kNLG + 1) * 4);
  int* lg_cur  = (int*)alloc(kNLG * 4);

  auto hptr = [&](int l) { return out + (size_t)l * 60000 * D; };
  auto prep = [&](int s) { return pre2 + (size_t)s * MP_ALL * PQH; };

  dim3 b(256);

  k_init<<<(kNLG + 255) / 256, b, 0, stream>>>(stats, ab, m0_cur, mL_cur, lg_cur);
  {
    int tot = kE + 2 * kNLG + kELG;
    k_hist_all<<<(tot + 255) / 256, b, 0, stream>>>(edge_index, lg_map, lg_edge_index,
                                                    m0_cur, mL_cur, lg_cur);
    k_scan3<<<3, b, 0, stream>>>(m0_cur, m0_offs, mL_cur, mL_offs, lg_cur, lg_offs);
    k_fill_all<<<(tot + 255) / 256, b, 0, stream>>>(edge_index, lg_map, lg_edge_index,
                                                    edge_attr, lg_map2, x,
                                                    m0_cur, r0m, mL_cur, rLm,
                                                    lg_cur, r0l, rLl);
  }
  {
    int tot = 2 * kL * (N1P * K1P + N2P * K2P) + kL * 640 + 378 * RH + kL * STL;
    k_precomp<<<(tot + 255) / 256, b, 0, stream>>>(g_emb1, g_emb2, lg_emb1, lg_emb2,
                                                   g_w1, g_w2, lg_w1, lg_w2,
                                                   g_gamma, g_beta, lg_gamma, lg_beta,
                                                   slv, tcm, tcl, gbp,
                                                   g_w1t, g_w2t, lg_w1t, lg_w2t);
  }
  k_embed_all<<<(NALL * RQ + 255) / 256, b, 0, stream>>>(x, lg_x, node_emb1, node_emb2,
                                                         gnn_e_emb1, gnn_e_emb2,
                                                         hptr(0), (uint4*)hist);

  int cur = 0;
  for (int l = 0; l < kL; ++l) {
    float* slot = stats + (size_t)l * STL;
    const float* slvM = slv + (size_t)l * 640;
    const float* slvL = slvM + 320;

    if (l == 0)
      k_gather_all0<<<NALL, 64, 0, stream>>>(
          (const uint4*)hist, (const uint4*)(hist + (size_t)kN * RH),
          r0m, r0l, (const uint4*)tcm, (const uint4*)tcl,
          slvM, slvL, m0_offs, lg_offs, (uint4*)ab);
    else
      k_gather_bnL<<<NALL, 64, 0, stream>>>(
          (const uint4*)prep(cur),
          stats + (size_t)(l - 1) * STL, gbp + (size_t)(l - 1) * STL,
          rLm, rLl, slvM, slvL, mL_offs, lg_offs,
          hptr(l), (uint4*)ab);

    k_mfma_gemm_dual<true, false><<<8 * NRP * 5, b, 0, stream>>>(
        ab, g_w1t + (size_t)l * N1P * K1P, lg_w1t + (size_t)l * N1P * K1P,
        g_b1 + (size_t)l * 2 * D, lg_b1 + (size_t)l * 2 * D, 2 * D,
        hidden, 0, 608, N1P, K1P, K1P, 5, MP_ALL, MP_ALL, nullptr, nullptr);

    int nxt = cur ^ 1;
    k_mfma_gemm_dual<false, true><<<8 * NRP * 3, b, 0, stream>>>(
        hidden, g_w2t + (size_t)l * N2P * K2P, lg_w2t + (size_t)l * N2P * K2P,
        g_b2 + (size_t)l * D, lg_b2 + (size_t)l * D, D,
        prep(nxt), D, PQH, PQH, K2P, 608, 3, kN, MP_N + kNLG,
        slot, slot + 640);
    cur = nxt;
  }

  k_bn_final<<<(NALL * RQR + 255) / 256, b, 0, stream>>>(
      (const uint4*)prep(cur),
      stats + (size_t)(kL - 1) * STL, gbp + (size_t)(kL - 1) * STL, hptr(kL));
}